// Round 2
// baseline (1653.473 us; speedup 1.0000x reference)
//
#include <hip/hip_runtime.h>
#include <hip/hip_bf16.h>
#include <cstdint>
#include <cstddef>

using bf16 = __hip_bfloat16;
typedef __attribute__((ext_vector_type(8))) short bf16x8;  // 8 bf16 (4 VGPRs)
typedef __attribute__((ext_vector_type(4))) float f32x4;

static constexpr int B_ = 2, S_ = 1024, D_ = 512, H_ = 8;
static constexpr int M_ = B_ * S_;     // 2048 rows
static constexpr int CHUNKS_ = 32, CLEN_ = 32;  // S = CHUNKS * CLEN
static constexpr float EPS_ = 1e-6f;

__device__ __forceinline__ float sigmoidf_(float x) { return 1.0f / (1.0f + __expf(-x)); }

// ---------------- fused transpose + cast: W [K][N] f32 -> Wt [N][K] bf16 ----------------
struct TJob { const float* src; bf16* dst; int K, N, base; };
struct TTab { TJob j[9]; };

__global__ __launch_bounds__(256) void k_transpose_all(TTab tab) {
  __shared__ float tile[32][33];
  int blk = blockIdx.x;
  int ji = 0;
#pragma unroll
  for (int t = 1; t < 9; ++t) if (tab.j[t].base <= blk) ji = t;
  const float* W = tab.j[ji].src;
  bf16* Wt = tab.j[ji].dst;
  int K = tab.j[ji].K, N = tab.j[ji].N;
  int rel = blk - tab.j[ji].base;
  int nb = N >> 5;
  int n0 = (rel % nb) * 32, k0 = (rel / nb) * 32;
  int tx = threadIdx.x, ty = threadIdx.y;  // 32 x 8
#pragma unroll
  for (int r = ty; r < 32; r += 8) tile[r][tx] = W[(size_t)(k0 + r) * N + n0 + tx];
  __syncthreads();
#pragma unroll
  for (int r = ty; r < 32; r += 8)
    Wt[(size_t)(n0 + r) * K + k0 + tx] = __float2bfloat16(tile[tx][r]);
}

// ---------------- rmsnorm over D=512, optional f32 + bf16 outputs ----------------
__global__ __launch_bounds__(256) void k_rmsnorm(const float* __restrict__ x,
                                                 const float* __restrict__ scale,
                                                 float* __restrict__ outf,
                                                 bf16* __restrict__ outb) {
  int m = blockIdx.x, tid = threadIdx.x;
  const float* row = x + (size_t)m * D_;
  float2 v = *(const float2*)(row + tid * 2);
  float ss = v.x * v.x + v.y * v.y;
#pragma unroll
  for (int o = 1; o < 64; o <<= 1) ss += __shfl_xor(ss, o);
  __shared__ float wsum[4];
  if ((tid & 63) == 0) wsum[tid >> 6] = ss;
  __syncthreads();
  float tot = wsum[0] + wsum[1] + wsum[2] + wsum[3];
  float rs = rsqrtf(tot * (1.0f / (float)D_) + EPS_);
  float2 sc = *(const float2*)(scale + tid * 2);
  float o0 = v.x * rs * sc.x, o1 = v.y * rs * sc.y;
  if (outf) {
    float2 o; o.x = o0; o.y = o1;
    *(float2*)(outf + (size_t)m * D_ + tid * 2) = o;
  }
  if (outb) {
    bf16* p = outb + (size_t)m * D_ + tid * 2;
    p[0] = __float2bfloat16(o0); p[1] = __float2bfloat16(o1);
  }
}

// ---------------- action-embedding gather ----------------
__global__ __launch_bounds__(256) void k_gather(const int* __restrict__ action,
                                                const float* __restrict__ embed,
                                                float* __restrict__ aef, bf16* __restrict__ aeb) {
  int m = blockIdx.x, tid = threadIdx.x;
  int a = action[m];
  float2 v = *(const float2*)(embed + (size_t)a * 512 + tid * 2);
  *(float2*)(aef + (size_t)m * 512 + tid * 2) = v;
  bf16* p = aeb + (size_t)m * 512 + tid * 2;
  p[0] = __float2bfloat16(v.x); p[1] = __float2bfloat16(v.y);
}

// ---------------- [2048,512] @ [512,8] -> sigmoid -> [2048,8] ----------------
__global__ __launch_bounds__(256) void k_dot8_sigmoid(const float* __restrict__ X,
                                                      const float* __restrict__ W8,
                                                      float* __restrict__ out) {
  int m = blockIdx.x, tid = threadIdx.x;
  float x0 = X[(size_t)m * D_ + tid];
  float x1 = X[(size_t)m * D_ + 256 + tid];
  float p[8];
#pragma unroll
  for (int j = 0; j < 8; ++j)
    p[j] = x0 * W8[tid * 8 + j] + x1 * W8[(tid + 256) * 8 + j];
#pragma unroll
  for (int j = 0; j < 8; ++j) {
#pragma unroll
    for (int o = 1; o < 64; o <<= 1) p[j] += __shfl_xor(p[j], o);
  }
  __shared__ float sacc[4][8];
  if ((tid & 63) == 0) {
#pragma unroll
    for (int j = 0; j < 8; ++j) sacc[tid >> 6][j] = p[j];
  }
  __syncthreads();
  if (tid < 8) {
    float s = sacc[0][tid] + sacc[1][tid] + sacc[2][tid] + sacc[3][tid];
    out[(size_t)m * 8 + tid] = sigmoidf_(s);
  }
}

// ---- per (m,h): L2-normalize q,k in place; pack scal8 = {beta, g, kq, kbv, bvq} ----
__global__ __launch_bounds__(64) void k_qknorm_dots(float* __restrict__ qkv,
                                                    const float* __restrict__ buv,
                                                    const float* __restrict__ betaF,
                                                    const float* __restrict__ alphaF,
                                                    const int* __restrict__ mask,
                                                    float* __restrict__ scal8) {
  int blk = blockIdx.x;
  int m = blk >> 3, h = blk & 7, t = threadIdx.x;
  size_t qi = (size_t)m * 1536 + h * 64 + t;
  float q = qkv[qi], k = qkv[qi + 512];
  float bv = buv[(size_t)m * 1024 + 512 + h * 64 + t];
  float qs = q * q, ks = k * k;
#pragma unroll
  for (int o = 1; o < 64; o <<= 1) { qs += __shfl_xor(qs, o); ks += __shfl_xor(ks, o); }
  float qn = q / (sqrtf(qs) + EPS_);
  float kn = k / (sqrtf(ks) + EPS_);
  qkv[qi] = qn; qkv[qi + 512] = kn;
  float d0 = kn * qn, d1 = kn * bv, d2 = bv * qn;
#pragma unroll
  for (int o = 1; o < 64; o <<= 1) {
    d0 += __shfl_xor(d0, o); d1 += __shfl_xor(d1, o); d2 += __shfl_xor(d2, o);
  }
  if (t == 0) {
    int mh = m * 8 + h;
    float4 s4;
    s4.x = betaF[mh];
    s4.y = alphaF[mh] * (1.0f - (float)mask[m]);
    s4.z = d0; s4.w = d1;
    *(float4*)(scal8 + (size_t)mh * 8) = s4;
    scal8[(size_t)mh * 8 + 4] = d2;
  }
}

// ---------------- bf16 MFMA GEMM: C[M,N] = epi(A[M,K] @ Bt[N,K]^T) ----------------
template <int EPI, int WNF>
__global__ __launch_bounds__(256) void k_gemm(const bf16* __restrict__ A,
                                              const bf16* __restrict__ Bt,
                                              float* __restrict__ C, int M, int N, int K,
                                              int actSplit, const float* __restrict__ bias,
                                              const float* __restrict__ res) {
  constexpr int TN = WNF * 32;  // 128 or 64
  __shared__ bf16 As[128][40];
  __shared__ bf16 Bs[TN][40];
  const int tid = threadIdx.x;
  const int wave = tid >> 6, lane = tid & 63;
  const int wm = wave >> 1, wn = wave & 1;
  const int m0 = blockIdx.y * 128, n0 = blockIdx.x * TN;
  const int lrow = lane & 15, lk = (lane >> 4) * 8;

  f32x4 acc[4][WNF];
#pragma unroll
  for (int i = 0; i < 4; ++i)
#pragma unroll
    for (int j = 0; j < WNF; ++j) acc[i][j] = (f32x4){0.f, 0.f, 0.f, 0.f};

  for (int k0 = 0; k0 < K; k0 += 32) {
    int4 areg[2];
    int4 breg[TN / 64];
#pragma unroll
    for (int p = 0; p < 2; ++p) {
      int idx = p * 256 + tid, row = idx >> 2, kg = idx & 3;
      areg[p] = *(const int4*)(A + (size_t)(m0 + row) * K + k0 + kg * 8);
    }
#pragma unroll
    for (int p = 0; p < TN / 64; ++p) {
      int idx = p * 256 + tid, row = idx >> 2, kg = idx & 3;
      breg[p] = *(const int4*)(Bt + (size_t)(n0 + row) * K + k0 + kg * 8);
    }
    __syncthreads();
#pragma unroll
    for (int p = 0; p < 2; ++p) {
      int idx = p * 256 + tid, row = idx >> 2, kg = idx & 3;
      *(int4*)&As[row][kg * 8] = areg[p];
    }
#pragma unroll
    for (int p = 0; p < TN / 64; ++p) {
      int idx = p * 256 + tid, row = idx >> 2, kg = idx & 3;
      *(int4*)&Bs[row][kg * 8] = breg[p];
    }
    __syncthreads();
    bf16x8 af[4], bfr[WNF];
#pragma unroll
    for (int mm = 0; mm < 4; ++mm)
      af[mm] = *(const bf16x8*)&As[wm * 64 + mm * 16 + lrow][lk];
#pragma unroll
    for (int nn = 0; nn < WNF; ++nn)
      bfr[nn] = *(const bf16x8*)&Bs[wn * (WNF * 16) + nn * 16 + lrow][lk];
#pragma unroll
    for (int mm = 0; mm < 4; ++mm)
#pragma unroll
      for (int nn = 0; nn < WNF; ++nn)
        acc[mm][nn] = __builtin_amdgcn_mfma_f32_16x16x32_bf16(af[mm], bfr[nn], acc[mm][nn], 0, 0, 0);
  }
#pragma unroll
  for (int mm = 0; mm < 4; ++mm) {
#pragma unroll
    for (int nn = 0; nn < WNF; ++nn) {
#pragma unroll
      for (int r = 0; r < 4; ++r) {
        int row = m0 + wm * 64 + mm * 16 + (lane >> 4) * 4 + r;
        int col = n0 + wn * (WNF * 16) + nn * 16 + (lane & 15);
        float v = acc[mm][nn][r];
        if constexpr (EPI == 1) {
          if (col < actSplit) v = v * sigmoidf_(v);
        }
        if constexpr (EPI == 2) v += bias[col] + res[(size_t)row * N + col];
        if constexpr (EPI == 3) v += res[(size_t)row * N + col];
        C[(size_t)row * N + col] = v;
      }
    }
  }
}

// ---------------- swiglu: out = bf16(silu(gv[:, :2048]) * gv[:, 2048:]) ----------------
__global__ __launch_bounds__(256) void k_swiglu(const float* __restrict__ gv, bf16* __restrict__ out) {
  size_t idx = (size_t)blockIdx.x * 256 + threadIdx.x;  // over 2048*2048
  int m = (int)(idx >> 11), c = (int)(idx & 2047);
  float g = gv[(size_t)m * 4096 + c];
  float vv = gv[(size_t)m * 4096 + 2048 + c];
  out[idx] = __float2bfloat16(g * sigmoidf_(g) * vv);
}

// ================= chunked recurrence =================
// Per-step transition: hs' = hs @ A_t + U_t,  A_t = g (I - beta k k^T),
// U_t[i][j] = beta v_i k_j + bu_i (bv_j - beta*kbv*k_j).
// Thread layout: tid = 4*i + q4; thread owns cols [q4*16, q4*16+16) of row i.

struct alignas(16) StepC {
  float k[16], bv[16], q[16];
  float v_i, bu_i, beta, g, kq, kbv, bvq;
};

__device__ __forceinline__ void load_stepc(StepC& sd,
    const float* __restrict__ qkv, const float* __restrict__ buv,
    const float* __restrict__ scal8, int m, int h, int i, int j0, bool withq) {
  const float* qb = qkv + (size_t)m * 1536 + h * 64;
  const float* bb = buv + (size_t)m * 1024 + h * 64;
#pragma unroll
  for (int p = 0; p < 4; ++p) *(float4*)&sd.k[p * 4] = *(const float4*)(qb + 512 + j0 + p * 4);
#pragma unroll
  for (int p = 0; p < 4; ++p) *(float4*)&sd.bv[p * 4] = *(const float4*)(bb + 512 + j0 + p * 4);
  if (withq) {
#pragma unroll
    for (int p = 0; p < 4; ++p) *(float4*)&sd.q[p * 4] = *(const float4*)(qb + j0 + p * 4);
  }
  sd.v_i = qb[1024 + i];
  sd.bu_i = bb[i];
  const float* sp = scal8 + (size_t)(m * 8 + h) * 8;
  float4 s4 = *(const float4*)sp;
  sd.beta = s4.x; sd.g = s4.y; sd.kq = s4.z; sd.kbv = s4.w;
  if (withq) sd.bvq = sp[4];
}

// phase-1 step: fold into (P, U)
__device__ __forceinline__ void step_fold(float P[16], float U[16], const StepC& sd) {
  float Pk = 0.f, Uk = 0.f;
#pragma unroll
  for (int jj = 0; jj < 16; ++jj) { Pk += P[jj] * sd.k[jj]; Uk += U[jj] * sd.k[jj]; }
  Pk += __shfl_xor(Pk, 1); Pk += __shfl_xor(Pk, 2);
  Uk += __shfl_xor(Uk, 1); Uk += __shfl_xor(Uk, 2);
  float gb = sd.g * sd.beta;
  float cP = gb * Pk;
  float Ai = sd.beta * sd.v_i - gb * Uk - sd.bu_i * sd.beta * sd.kbv;
#pragma unroll
  for (int jj = 0; jj < 16; ++jj) {
    P[jj] = sd.g * P[jj] - cP * sd.k[jj];
    U[jj] = sd.g * U[jj] + Ai * sd.k[jj] + sd.bu_i * sd.bv[jj];
  }
}

// phase-3 step: advance hs, emit attn
__device__ __forceinline__ void step_apply(float hs[16], const StepC& sd,
                                           float* __restrict__ attn_addr, bool writer) {
  float u = 0.f, w = 0.f;
#pragma unroll
  for (int jj = 0; jj < 16; ++jj) { u += hs[jj] * sd.k[jj]; w += hs[jj] * sd.q[jj]; }
  u += __shfl_xor(u, 1); u += __shfl_xor(u, 2);
  w += __shfl_xor(w, 1); w += __shfl_xor(w, 2);
  float a_i = sd.beta * sd.v_i - sd.g * sd.beta * u;
  float c = sd.beta * sd.kbv;
#pragma unroll
  for (int jj = 0; jj < 16; ++jj) {
    float bvp = sd.bv[jj] - c * sd.k[jj];
    hs[jj] = sd.g * hs[jj] + a_i * sd.k[jj] + sd.bu_i * bvp;
  }
  if (writer) *attn_addr = sd.g * w + a_i * sd.kq + sd.bu_i * (sd.bvq - c * sd.kq);
}

// ---- phase 1: per-chunk (P_c, U_c) ----
__global__ __launch_bounds__(256) void k_scan_chunk(
    const float* __restrict__ qkv, const float* __restrict__ buv,
    const float* __restrict__ scal8, float* __restrict__ Pbuf, float* __restrict__ Ubuf) {
  int blk = blockIdx.x, bh = blk >> 5, c = blk & (CHUNKS_ - 1);
  int b = bh >> 3, h = bh & 7;
  int tid = threadIdx.x, i = tid >> 2, q4 = tid & 3, j0 = q4 * 16;
  alignas(16) float P[16], U[16];
#pragma unroll
  for (int jj = 0; jj < 16; ++jj) { P[jj] = (j0 + jj == i) ? 1.f : 0.f; U[jj] = 0.f; }
  int m0 = b * S_ + c * CLEN_;
  StepC A, Bs;
  load_stepc(A, qkv, buv, scal8, m0, h, i, j0, false);
  load_stepc(Bs, qkv, buv, scal8, m0 + 1, h, i, j0, false);
  for (int s = 0; s < CLEN_; s += 2) {
    step_fold(P, U, A);
    if (s + 2 < CLEN_) load_stepc(A, qkv, buv, scal8, m0 + s + 2, h, i, j0, false);
    step_fold(P, U, Bs);
    if (s + 3 < CLEN_) load_stepc(Bs, qkv, buv, scal8, m0 + s + 3, h, i, j0, false);
  }
  float* pp = Pbuf + ((size_t)bh * CHUNKS_ + c) * 4096 + i * 64 + j0;
  float* up = Ubuf + ((size_t)bh * CHUNKS_ + c) * 4096 + i * 64 + j0;
#pragma unroll
  for (int g = 0; g < 4; ++g) {
    *(float4*)(pp + g * 4) = *(const float4*)&P[g * 4];
    *(float4*)(up + g * 4) = *(const float4*)&U[g * 4];
  }
}

// ---- phase 2: sequential chain over chunks; stores hstart_c and final state ----
__global__ __launch_bounds__(256) void k_chain(
    const float* __restrict__ Pbuf, const float* __restrict__ Ubuf,
    const float* __restrict__ carry, float* __restrict__ Hbuf, float* __restrict__ out_hs) {
  __shared__ float Pl[2][4096];
  int bh = blockIdx.x;
  int tid = threadIdx.x, i = tid >> 2, q4 = tid & 3, j0 = q4 * 16;
  alignas(16) float hs[16];
  const float* cr = carry + (size_t)bh * 4096 + i * 64 + j0;
#pragma unroll
  for (int g = 0; g < 4; ++g) *(float4*)&hs[g * 4] = *(const float4*)(cr + g * 4);

  const float4* Pg0 = (const float4*)(Pbuf + (size_t)bh * CHUNKS_ * 4096);
  const float* Ug0 = Ubuf + (size_t)bh * CHUNKS_ * 4096;

  // prologue: stage P_0 into LDS buf 0
  float4 pn[4], uCur[4], uNext[4];
#pragma unroll
  for (int g = 0; g < 4; ++g) pn[g] = Pg0[g * 256 + tid];
#pragma unroll
  for (int g = 0; g < 4; ++g) uCur[g] = *(const float4*)(Ug0 + i * 64 + j0 + g * 4);
#pragma unroll
  for (int g = 0; g < 4; ++g) ((float4*)&Pl[0][0])[g * 256 + tid] = pn[g];
  __syncthreads();

  for (int c = 0; c < CHUNKS_; ++c) {
    int buf = c & 1;
    if (c + 1 < CHUNKS_) {
#pragma unroll
      for (int g = 0; g < 4; ++g) pn[g] = Pg0[(size_t)(c + 1) * 1024 + g * 256 + tid];
#pragma unroll
      for (int g = 0; g < 4; ++g)
        uNext[g] = *(const float4*)(Ug0 + (size_t)(c + 1) * 4096 + i * 64 + j0 + g * 4);
    }
    // store hstart_c (pre-update hs)
    float* hb = Hbuf + ((size_t)bh * CHUNKS_ + c) * 4096 + i * 64 + j0;
#pragma unroll
    for (int g = 0; g < 4; ++g) *(float4*)(hb + g * 4) = *(const float4*)&hs[g * 4];

    // nout = hs @ P_c + U_c
    alignas(16) float nout[16];
#pragma unroll
    for (int g = 0; g < 4; ++g) {
      nout[g * 4 + 0] = uCur[g].x; nout[g * 4 + 1] = uCur[g].y;
      nout[g * 4 + 2] = uCur[g].z; nout[g * 4 + 3] = uCur[g].w;
    }
#pragma unroll
    for (int l = 0; l < 64; ++l) {
      float hl = __shfl(hs[l & 15], l >> 4, 4);
      const float4* prow = (const float4*)&Pl[buf][l * 64 + j0];
      float4 p0 = prow[0], p1 = prow[1], p2 = prow[2], p3 = prow[3];
      nout[0]  += hl * p0.x; nout[1]  += hl * p0.y; nout[2]  += hl * p0.z; nout[3]  += hl * p0.w;
      nout[4]  += hl * p1.x; nout[5]  += hl * p1.y; nout[6]  += hl * p1.z; nout[7]  += hl * p1.w;
      nout[8]  += hl * p2.x; nout[9]  += hl * p2.y; nout[10] += hl * p2.z; nout[11] += hl * p2.w;
      nout[12] += hl * p3.x; nout[13] += hl * p3.y; nout[14] += hl * p3.z; nout[15] += hl * p3.w;
    }
    // stage P_{c+1} into the other buffer (not read this iter; single barrier keeps
    // waves within one iter, so no wave can still be reading buf^1 from iter c-1)
    if (c + 1 < CHUNKS_) {
#pragma unroll
      for (int g = 0; g < 4; ++g) ((float4*)&Pl[buf ^ 1][0])[g * 256 + tid] = pn[g];
    }
    __syncthreads();
#pragma unroll
    for (int jj = 0; jj < 16; ++jj) hs[jj] = nout[jj];
#pragma unroll
    for (int g = 0; g < 4; ++g) uCur[g] = uNext[g];
  }
  float* ho = out_hs + (size_t)bh * 4096 + i * 64 + j0;
#pragma unroll
  for (int g = 0; g < 4; ++g) *(float4*)(ho + g * 4) = *(const float4*)&hs[g * 4];
}

// ---- phase 3: re-run each chunk from hstart_c, emit attn ----
__global__ __launch_bounds__(256) void k_apply_chunk(
    const float* __restrict__ qkv, const float* __restrict__ buv,
    const float* __restrict__ scal8, const float* __restrict__ Hbuf,
    float* __restrict__ attn) {
  int blk = blockIdx.x, bh = blk >> 5, c = blk & (CHUNKS_ - 1);
  int b = bh >> 3, h = bh & 7;
  int tid = threadIdx.x, i = tid >> 2, q4 = tid & 3, j0 = q4 * 16;
  bool writer = (q4 == 0);
  alignas(16) float hs[16];
  const float* hb = Hbuf + ((size_t)bh * CHUNKS_ + c) * 4096 + i * 64 + j0;
#pragma unroll
  for (int g = 0; g < 4; ++g) *(float4*)&hs[g * 4] = *(const float4*)(hb + g * 4);
  int m0 = b * S_ + c * CLEN_;
  StepC A, Bs;
  load_stepc(A, qkv, buv, scal8, m0, h, i, j0, true);
  load_stepc(Bs, qkv, buv, scal8, m0 + 1, h, i, j0, true);
  for (int s = 0; s < CLEN_; s += 2) {
    step_apply(hs, A, attn + ((size_t)(m0 + s) * 512 + h * 64 + i), writer);
    if (s + 2 < CLEN_) load_stepc(A, qkv, buv, scal8, m0 + s + 2, h, i, j0, true);
    step_apply(hs, Bs, attn + ((size_t)(m0 + s + 1) * 512 + h * 64 + i), writer);
    if (s + 3 < CLEN_) load_stepc(Bs, qkv, buv, scal8, m0 + s + 3, h, i, j0, true);
  }
}

// ---------------- host ----------------
extern "C" void kernel_launch(void* const* d_in, const int* in_sizes, int n_in,
                              void* d_out, int out_size, void* d_ws, size_t ws_size,
                              hipStream_t stream) {
  const float* x      = (const float*)d_in[0];
  const int*   action = (const int*)d_in[1];
  const int*   mask   = (const int*)d_in[2];
  const float* carry  = (const float*)d_in[3];
  const float* n1s    = (const float*)d_in[4];
  const float* wq     = (const float*)d_in[5];
  const float* wk     = (const float*)d_in[6];
  const float* wv     = (const float*)d_in[7];
  const float* wbeta  = (const float*)d_in[8];
  const float* embed  = (const float*)d_in[9];
  const float* walpha = (const float*)d_in[10];
  const float* wbu    = (const float*)d_in[11];
  const float* wbv    = (const float*)d_in[12];
  const float* nas    = (const float*)d_in[13];
  const float* wout   = (const float*)d_in[14];
  const float* bout   = (const float*)d_in[15];
  const float* n2s    = (const float*)d_in[16];
  const float* wgate  = (const float*)d_in[17];
  const float* wval   = (const float*)d_in[18];
  const float* wffn   = (const float*)d_in[19];

  float* out_hs  = (float*)d_out;            // [2,8,64,64]
  float* out_ffn = (float*)d_out + 65536;    // [2,1024,512]

  char* p = (char*)d_ws;
  auto alloc = [&](size_t bytes) -> char* {
    char* r = p; p += (bytes + 255) & ~(size_t)255; return r;
  };
  bf16*  wqkvT = (bf16*)alloc((size_t)1536 * 512 * 2);
  bf16*  wbuvT = (bf16*)alloc((size_t)1024 * 512 * 2);
  bf16*  woutT = (bf16*)alloc((size_t)512 * 512 * 2);
  bf16*  wgvT  = (bf16*)alloc((size_t)4096 * 512 * 2);
  bf16*  wffnT = (bf16*)alloc((size_t)512 * 2048 * 2);
  float* hF    = (float*)alloc((size_t)M_ * 512 * 4);
  bf16*  hB    = (bf16*)alloc((size_t)M_ * 512 * 2);
  float* aeF   = (float*)alloc((size_t)M_ * 512 * 4);
  bf16*  aeB   = (bf16*)alloc((size_t)M_ * 512 * 2);
  float* qkvF  = (float*)alloc((size_t)M_ * 1536 * 4);
  float* buvF  = (float*)alloc((size_t)M_ * 1024 * 4);
  float* betaF = (float*)alloc((size_t)M_ * 8 * 4);
  float* alphaF= (float*)alloc((size_t)M_ * 8 * 4);
  float* scal8 = (float*)alloc((size_t)M_ * 8 * 8 * 4);
  float* attnF = (float*)alloc((size_t)M_ * 512 * 4);
  bf16*  attnB = (bf16*)alloc((size_t)M_ * 512 * 2);
  float* skipF = (float*)alloc((size_t)M_ * 512 * 4);
  bf16*  h2B   = (bf16*)alloc((size_t)M_ * 512 * 2);
  float* gvF   = (float*)alloc((size_t)M_ * 4096 * 4);
  bf16*  ffnB  = (bf16*)alloc((size_t)M_ * 2048 * 2);
  if ((size_t)(p - (char*)d_ws) > ws_size) return;  // workspace too small

  // P/U/H chunk buffers (each 16*32*4096 floats = 8 MB) alias gvF (33.5 MB),
  // which is only written after phase 3 completes.
  float* Pbuf = gvF;
  float* Ubuf = gvF + (size_t)16 * CHUNKS_ * 4096;
  float* Hbuf = gvF + (size_t)32 * CHUNKS_ * 4096;

  // fused weight transposes (9 jobs, 1 dispatch)
  TTab tab;
  tab.j[0] = {wq,    wqkvT,              512,  512,  0};
  tab.j[1] = {wk,    wqkvT + 512 * 512,  512,  512,  256};
  tab.j[2] = {wv,    wqkvT + 1024 * 512, 512,  512,  512};
  tab.j[3] = {wbu,   wbuvT,              512,  512,  768};
  tab.j[4] = {wbv,   wbuvT + 512 * 512,  512,  512,  1024};
  tab.j[5] = {wout,  woutT,              512,  512,  1280};
  tab.j[6] = {wgate, wgvT,               512,  2048, 1536};
  tab.j[7] = {wval,  wgvT + 2048 * 512,  512,  2048, 2560};
  tab.j[8] = {wffn,  wffnT,              2048, 512,  3584};
  k_transpose_all<<<4608, dim3(32, 8), 0, stream>>>(tab);

  k_rmsnorm<<<M_, 256, 0, stream>>>(x, n1s, hF, hB);
  k_gather<<<M_, 256, 0, stream>>>(action, embed, aeF, aeB);

  k_gemm<1, 2><<<dim3(1536 / 64, 16), 256, 0, stream>>>(hB, wqkvT, qkvF, M_, 1536, 512, 1024, nullptr, nullptr);
  k_gemm<0, 2><<<dim3(1024 / 64, 16), 256, 0, stream>>>(aeB, wbuvT, buvF, M_, 1024, 512, 0, nullptr, nullptr);
  k_dot8_sigmoid<<<M_, 256, 0, stream>>>(hF, wbeta, betaF);
  k_dot8_sigmoid<<<M_, 256, 0, stream>>>(aeF, walpha, alphaF);
  k_qknorm_dots<<<M_ * 8, 64, 0, stream>>>(qkvF, buvF, betaF, alphaF, mask, scal8);

  k_scan_chunk<<<16 * CHUNKS_, 256, 0, stream>>>(qkvF, buvF, scal8, Pbuf, Ubuf);
  k_chain<<<16, 256, 0, stream>>>(Pbuf, Ubuf, carry, Hbuf, out_hs);
  k_apply_chunk<<<16 * CHUNKS_, 256, 0, stream>>>(qkvF, buvF, scal8, Hbuf, attnF);

  k_rmsnorm<<<M_, 256, 0, stream>>>(attnF, nas, nullptr, attnB);
  k_gemm<2, 2><<<dim3(512 / 64, 16), 256, 0, stream>>>(attnB, woutT, skipF, M_, 512, 512, 0, bout, x);
  k_rmsnorm<<<M_, 256, 0, stream>>>(skipF, n2s, nullptr, h2B);
  k_gemm<0, 4><<<dim3(4096 / 128, 16), 256, 0, stream>>>(h2B, wgvT, gvF, M_, 4096, 512, 0, nullptr, nullptr);
  k_swiglu<<<(M_ * 2048) / 256, 256, 0, stream>>>(gvF, ffnB);
  k_gemm<3, 2><<<dim3(512 / 64, 16), 256, 0, stream>>>(ffnB, wffnT, out_ffn, M_, 512, 2048, 0, nullptr, skipF);
}

// Round 3
// 361.824 us; speedup vs baseline: 4.5698x; 4.5698x over previous
//
#include <hip/hip_runtime.h>
#include <hip/hip_bf16.h>
#include <cstdint>
#include <cstddef>

using bf16 = __hip_bfloat16;
typedef __attribute__((ext_vector_type(8))) short bf16x8;  // 8 bf16 (4 VGPRs)
typedef __attribute__((ext_vector_type(4))) float f32x4;

static constexpr int B_ = 2, S_ = 1024, D_ = 512, H_ = 8;
static constexpr int M_ = B_ * S_;     // 2048 rows
static constexpr int CHUNKS_ = 32, CLEN_ = 32;  // S = CHUNKS * CLEN
static constexpr float EPS_ = 1e-6f;

__device__ __forceinline__ float sigmoidf_(float x) { return 1.0f / (1.0f + __expf(-x)); }

__device__ __forceinline__ short bf_hi(float v, float& rem) {
  bf16 h = __float2bfloat16(v);
  rem = v - __bfloat162float(h);
  return *(short*)&h;
}
__device__ __forceinline__ short bf_of(float v) {
  bf16 h = __float2bfloat16(v);
  return *(short*)&h;
}

// ---------------- fused transpose + cast: W [K][N] f32 -> Wt [N][K] bf16 ----------------
struct TJob { const float* src; bf16* dst; int K, N, base; };
struct TTab { TJob j[9]; };

__global__ __launch_bounds__(256) void k_transpose_all(TTab tab) {
  __shared__ float tile[32][33];
  int blk = blockIdx.x;
  int ji = 0;
#pragma unroll
  for (int t = 1; t < 9; ++t) if (tab.j[t].base <= blk) ji = t;
  const float* W = tab.j[ji].src;
  bf16* Wt = tab.j[ji].dst;
  int K = tab.j[ji].K, N = tab.j[ji].N;
  int rel = blk - tab.j[ji].base;
  int nb = N >> 5;
  int n0 = (rel % nb) * 32, k0 = (rel / nb) * 32;
  int tx = threadIdx.x, ty = threadIdx.y;  // 32 x 8
#pragma unroll
  for (int r = ty; r < 32; r += 8) tile[r][tx] = W[(size_t)(k0 + r) * N + n0 + tx];
  __syncthreads();
#pragma unroll
  for (int r = ty; r < 32; r += 8)
    Wt[(size_t)(n0 + r) * K + k0 + tx] = __float2bfloat16(tile[tx][r]);
}

// ---------------- rmsnorm over D=512, optional f32 + bf16 outputs ----------------
__global__ __launch_bounds__(256) void k_rmsnorm(const float* __restrict__ x,
                                                 const float* __restrict__ scale,
                                                 float* __restrict__ outf,
                                                 bf16* __restrict__ outb) {
  int m = blockIdx.x, tid = threadIdx.x;
  const float* row = x + (size_t)m * D_;
  float2 v = *(const float2*)(row + tid * 2);
  float ss = v.x * v.x + v.y * v.y;
#pragma unroll
  for (int o = 1; o < 64; o <<= 1) ss += __shfl_xor(ss, o);
  __shared__ float wsum[4];
  if ((tid & 63) == 0) wsum[tid >> 6] = ss;
  __syncthreads();
  float tot = wsum[0] + wsum[1] + wsum[2] + wsum[3];
  float rs = rsqrtf(tot * (1.0f / (float)D_) + EPS_);
  float2 sc = *(const float2*)(scale + tid * 2);
  float o0 = v.x * rs * sc.x, o1 = v.y * rs * sc.y;
  if (outf) {
    float2 o; o.x = o0; o.y = o1;
    *(float2*)(outf + (size_t)m * D_ + tid * 2) = o;
  }
  if (outb) {
    bf16* p = outb + (size_t)m * D_ + tid * 2;
    p[0] = __float2bfloat16(o0); p[1] = __float2bfloat16(o1);
  }
}

// ---------------- action-embedding gather ----------------
__global__ __launch_bounds__(256) void k_gather(const int* __restrict__ action,
                                                const float* __restrict__ embed,
                                                float* __restrict__ aef, bf16* __restrict__ aeb) {
  int m = blockIdx.x, tid = threadIdx.x;
  int a = action[m];
  float2 v = *(const float2*)(embed + (size_t)a * 512 + tid * 2);
  *(float2*)(aef + (size_t)m * 512 + tid * 2) = v;
  bf16* p = aeb + (size_t)m * 512 + tid * 2;
  p[0] = __float2bfloat16(v.x); p[1] = __float2bfloat16(v.y);
}

// ---------------- [2048,512] @ [512,8] -> sigmoid -> [2048,8] ----------------
__global__ __launch_bounds__(256) void k_dot8_sigmoid(const float* __restrict__ X,
                                                      const float* __restrict__ W8,
                                                      float* __restrict__ out) {
  int m = blockIdx.x, tid = threadIdx.x;
  float x0 = X[(size_t)m * D_ + tid];
  float x1 = X[(size_t)m * D_ + 256 + tid];
  float p[8];
#pragma unroll
  for (int j = 0; j < 8; ++j)
    p[j] = x0 * W8[tid * 8 + j] + x1 * W8[(tid + 256) * 8 + j];
#pragma unroll
  for (int j = 0; j < 8; ++j) {
#pragma unroll
    for (int o = 1; o < 64; o <<= 1) p[j] += __shfl_xor(p[j], o);
  }
  __shared__ float sacc[4][8];
  if ((tid & 63) == 0) {
#pragma unroll
    for (int j = 0; j < 8; ++j) sacc[tid >> 6][j] = p[j];
  }
  __syncthreads();
  if (tid < 8) {
    float s = sacc[0][tid] + sacc[1][tid] + sacc[2][tid] + sacc[3][tid];
    out[(size_t)m * 8 + tid] = sigmoidf_(s);
  }
}

// ---- per (m,h): L2-normalize q,k in place; pack scal8 = {beta, g, kq, kbv, bvq} ----
__global__ __launch_bounds__(64) void k_qknorm_dots(float* __restrict__ qkv,
                                                    const float* __restrict__ buv,
                                                    const float* __restrict__ betaF,
                                                    const float* __restrict__ alphaF,
                                                    const int* __restrict__ mask,
                                                    float* __restrict__ scal8) {
  int blk = blockIdx.x;
  int m = blk >> 3, h = blk & 7, t = threadIdx.x;
  size_t qi = (size_t)m * 1536 + h * 64 + t;
  float q = qkv[qi], k = qkv[qi + 512];
  float bv = buv[(size_t)m * 1024 + 512 + h * 64 + t];
  float qs = q * q, ks = k * k;
#pragma unroll
  for (int o = 1; o < 64; o <<= 1) { qs += __shfl_xor(qs, o); ks += __shfl_xor(ks, o); }
  float qn = q / (sqrtf(qs) + EPS_);
  float kn = k / (sqrtf(ks) + EPS_);
  qkv[qi] = qn; qkv[qi + 512] = kn;
  float d0 = kn * qn, d1 = kn * bv, d2 = bv * qn;
#pragma unroll
  for (int o = 1; o < 64; o <<= 1) {
    d0 += __shfl_xor(d0, o); d1 += __shfl_xor(d1, o); d2 += __shfl_xor(d2, o);
  }
  if (t == 0) {
    int mh = m * 8 + h;
    float4 s4;
    s4.x = betaF[mh];
    s4.y = alphaF[mh] * (1.0f - (float)mask[m]);
    s4.z = d0; s4.w = d1;
    *(float4*)(scal8 + (size_t)mh * 8) = s4;
    scal8[(size_t)mh * 8 + 4] = d2;
  }
}

// ---------------- bf16 MFMA GEMM: C[M,N] = epi(A[M,K] @ Bt[N,K]^T) ----------------
template <int EPI, int WNF>
__global__ __launch_bounds__(256) void k_gemm(const bf16* __restrict__ A,
                                              const bf16* __restrict__ Bt,
                                              float* __restrict__ C, int M, int N, int K,
                                              int actSplit, const float* __restrict__ bias,
                                              const float* __restrict__ res) {
  constexpr int TN = WNF * 32;  // 128 or 64
  __shared__ bf16 As[128][40];
  __shared__ bf16 Bs[TN][40];
  const int tid = threadIdx.x;
  const int wave = tid >> 6, lane = tid & 63;
  const int wm = wave >> 1, wn = wave & 1;
  const int m0 = blockIdx.y * 128, n0 = blockIdx.x * TN;
  const int lrow = lane & 15, lk = (lane >> 4) * 8;

  f32x4 acc[4][WNF];
#pragma unroll
  for (int i = 0; i < 4; ++i)
#pragma unroll
    for (int j = 0; j < WNF; ++j) acc[i][j] = (f32x4){0.f, 0.f, 0.f, 0.f};

  for (int k0 = 0; k0 < K; k0 += 32) {
    int4 areg[2];
    int4 breg[TN / 64];
#pragma unroll
    for (int p = 0; p < 2; ++p) {
      int idx = p * 256 + tid, row = idx >> 2, kg = idx & 3;
      areg[p] = *(const int4*)(A + (size_t)(m0 + row) * K + k0 + kg * 8);
    }
#pragma unroll
    for (int p = 0; p < TN / 64; ++p) {
      int idx = p * 256 + tid, row = idx >> 2, kg = idx & 3;
      breg[p] = *(const int4*)(Bt + (size_t)(n0 + row) * K + k0 + kg * 8);
    }
    __syncthreads();
#pragma unroll
    for (int p = 0; p < 2; ++p) {
      int idx = p * 256 + tid, row = idx >> 2, kg = idx & 3;
      *(int4*)&As[row][kg * 8] = areg[p];
    }
#pragma unroll
    for (int p = 0; p < TN / 64; ++p) {
      int idx = p * 256 + tid, row = idx >> 2, kg = idx & 3;
      *(int4*)&Bs[row][kg * 8] = breg[p];
    }
    __syncthreads();
    bf16x8 af[4], bfr[WNF];
#pragma unroll
    for (int mm = 0; mm < 4; ++mm)
      af[mm] = *(const bf16x8*)&As[wm * 64 + mm * 16 + lrow][lk];
#pragma unroll
    for (int nn = 0; nn < WNF; ++nn)
      bfr[nn] = *(const bf16x8*)&Bs[wn * (WNF * 16) + nn * 16 + lrow][lk];
#pragma unroll
    for (int mm = 0; mm < 4; ++mm)
#pragma unroll
      for (int nn = 0; nn < WNF; ++nn)
        acc[mm][nn] = __builtin_amdgcn_mfma_f32_16x16x32_bf16(af[mm], bfr[nn], acc[mm][nn], 0, 0, 0);
  }
#pragma unroll
  for (int mm = 0; mm < 4; ++mm) {
#pragma unroll
    for (int nn = 0; nn < WNF; ++nn) {
#pragma unroll
      for (int r = 0; r < 4; ++r) {
        int row = m0 + wm * 64 + mm * 16 + (lane >> 4) * 4 + r;
        int col = n0 + wn * (WNF * 16) + nn * 16 + (lane & 15);
        float v = acc[mm][nn][r];
        if constexpr (EPI == 1) {
          if (col < actSplit) v = v * sigmoidf_(v);
        }
        if constexpr (EPI == 2) v += bias[col] + res[(size_t)row * N + col];
        if constexpr (EPI == 3) v += res[(size_t)row * N + col];
        C[(size_t)row * N + col] = v;
      }
    }
  }
}

// ---------------- swiglu: out = bf16(silu(gv[:, :2048]) * gv[:, 2048:]) ----------------
__global__ __launch_bounds__(256) void k_swiglu(const float* __restrict__ gv, bf16* __restrict__ out) {
  size_t idx = (size_t)blockIdx.x * 256 + threadIdx.x;  // over 2048*2048
  int m = (int)(idx >> 11), c = (int)(idx & 2047);
  float g = gv[(size_t)m * 4096 + c];
  float vv = gv[(size_t)m * 4096 + 2048 + c];
  out[idx] = __float2bfloat16(g * sigmoidf_(g) * vv);
}

// ================= chunked recurrence =================
// Per-step transition: hs' = hs @ A_t + U_t,  A_t = g (I - beta k k^T),
// U_t[i][j] = beta v_i k_j + bu_i (bv_j - beta*kbv*k_j).
// Thread layout (phases 1,3): tid = 4*i + q4; thread owns cols [q4*16, q4*16+16) of row i.

struct alignas(16) StepC {
  float k[16], bv[16], q[16];
  float v_i, bu_i, beta, g, kq, kbv, bvq;
};

__device__ __forceinline__ void load_stepc(StepC& sd,
    const float* __restrict__ qkv, const float* __restrict__ buv,
    const float* __restrict__ scal8, int m, int h, int i, int j0, bool withq) {
  const float* qb = qkv + (size_t)m * 1536 + h * 64;
  const float* bb = buv + (size_t)m * 1024 + h * 64;
#pragma unroll
  for (int p = 0; p < 4; ++p) *(float4*)&sd.k[p * 4] = *(const float4*)(qb + 512 + j0 + p * 4);
#pragma unroll
  for (int p = 0; p < 4; ++p) *(float4*)&sd.bv[p * 4] = *(const float4*)(bb + 512 + j0 + p * 4);
  if (withq) {
#pragma unroll
    for (int p = 0; p < 4; ++p) *(float4*)&sd.q[p * 4] = *(const float4*)(qb + j0 + p * 4);
  }
  sd.v_i = qb[1024 + i];
  sd.bu_i = bb[i];
  const float* sp = scal8 + (size_t)(m * 8 + h) * 8;
  float4 s4 = *(const float4*)sp;
  sd.beta = s4.x; sd.g = s4.y; sd.kq = s4.z; sd.kbv = s4.w;
  if (withq) sd.bvq = sp[4];
}

// phase-1 step: fold into (P, U)
__device__ __forceinline__ void step_fold(float P[16], float U[16], const StepC& sd) {
  float Pk = 0.f, Uk = 0.f;
#pragma unroll
  for (int jj = 0; jj < 16; ++jj) { Pk += P[jj] * sd.k[jj]; Uk += U[jj] * sd.k[jj]; }
  Pk += __shfl_xor(Pk, 1); Pk += __shfl_xor(Pk, 2);
  Uk += __shfl_xor(Uk, 1); Uk += __shfl_xor(Uk, 2);
  float gb = sd.g * sd.beta;
  float cP = gb * Pk;
  float Ai = sd.beta * sd.v_i - gb * Uk - sd.bu_i * sd.beta * sd.kbv;
#pragma unroll
  for (int jj = 0; jj < 16; ++jj) {
    P[jj] = sd.g * P[jj] - cP * sd.k[jj];
    U[jj] = sd.g * U[jj] + Ai * sd.k[jj] + sd.bu_i * sd.bv[jj];
  }
}

// phase-3 step: advance hs, emit attn
__device__ __forceinline__ void step_apply(float hs[16], const StepC& sd,
                                           float* __restrict__ attn_addr, bool writer) {
  float u = 0.f, w = 0.f;
#pragma unroll
  for (int jj = 0; jj < 16; ++jj) { u += hs[jj] * sd.k[jj]; w += hs[jj] * sd.q[jj]; }
  u += __shfl_xor(u, 1); u += __shfl_xor(u, 2);
  w += __shfl_xor(w, 1); w += __shfl_xor(w, 2);
  float a_i = sd.beta * sd.v_i - sd.g * sd.beta * u;
  float c = sd.beta * sd.kbv;
#pragma unroll
  for (int jj = 0; jj < 16; ++jj) {
    float bvp = sd.bv[jj] - c * sd.k[jj];
    hs[jj] = sd.g * hs[jj] + a_i * sd.k[jj] + sd.bu_i * bvp;
  }
  if (writer) *attn_addr = sd.g * w + a_i * sd.kq + sd.bu_i * (sd.bvq - c * sd.kq);
}

// ---- phase 1: per-chunk transition, emitted as P^T (bf16 hi/lo) + U^T (f32) ----
// PtHi/PtLo[(bh,c)][r][k] = P[k][r] (bf16 pair); Ut[(bh,c)][r][k] = U[k][r] (f32).
__global__ __launch_bounds__(256) void k_scan_chunk(
    const float* __restrict__ qkv, const float* __restrict__ buv,
    const float* __restrict__ scal8, bf16* __restrict__ PtHi,
    bf16* __restrict__ PtLo, float* __restrict__ Ut) {
  int blk = blockIdx.x, bh = blk >> 5, c = blk & (CHUNKS_ - 1);
  int b = bh >> 3, h = bh & 7;
  int tid = threadIdx.x, i = tid >> 2, q4 = tid & 3, j0 = q4 * 16;
  alignas(16) float P[16], U[16];
#pragma unroll
  for (int jj = 0; jj < 16; ++jj) { P[jj] = (j0 + jj == i) ? 1.f : 0.f; U[jj] = 0.f; }
  int m0 = b * S_ + c * CLEN_;
  StepC A, Bs;
  load_stepc(A, qkv, buv, scal8, m0, h, i, j0, false);
  load_stepc(Bs, qkv, buv, scal8, m0 + 1, h, i, j0, false);
  for (int s = 0; s < CLEN_; s += 2) {
    step_fold(P, U, A);
    if (s + 2 < CLEN_) load_stepc(A, qkv, buv, scal8, m0 + s + 2, h, i, j0, false);
    step_fold(P, U, Bs);
    if (s + 3 < CLEN_) load_stepc(Bs, qkv, buv, scal8, m0 + s + 3, h, i, j0, false);
  }
  const size_t base = ((size_t)bh * CHUNKS_ + c) * 4096;
#pragma unroll
  for (int jj = 0; jj < 16; ++jj) {
    int j = j0 + jj;
    float pv = P[jj];
    float rem;
    short ph = bf_hi(pv, rem);
    short pl = bf_of(rem);
    ((short*)PtHi)[base + (size_t)j * 64 + i] = ph;
    ((short*)PtLo)[base + (size_t)j * 64 + i] = pl;
    Ut[base + (size_t)j * 64 + i] = U[jj];
  }
}

// ---- phase 2: MFMA chain. One block (4 waves) per bh; hs state f32 in LDS.
// hs_new^T = P^T @ hs^T + U^T; wave w computes D' rows [16w,16w+16), all 4 col-tiles.
__global__ __launch_bounds__(256) void k_chain2(
    const bf16* __restrict__ PtHi, const bf16* __restrict__ PtLo,
    const float* __restrict__ Ut, const float* __restrict__ carry,
    float* __restrict__ Hbuf, float* __restrict__ out_hs) {
  constexpr int PITCH = 68;  // f32 pitch: 16B-aligned rows, bank-stride 4 -> 2-way (free)
  __shared__ float hsL[64 * PITCH];
  const int bh = blockIdx.x, tid = threadIdx.x;
  const int wave = tid >> 6, lane = tid & 63;
  const int lr = lane & 15, lg = lane >> 4;
  const int srow = tid >> 2, sc0 = (tid & 3) * 16;  // staging map (row, col-block)

  // carry -> LDS
  {
    const float* src = carry + (size_t)bh * 4096 + srow * 64 + sc0;
#pragma unroll
    for (int g = 0; g < 4; ++g)
      *(float4*)&hsL[srow * PITCH + sc0 + 4 * g] = *(const float4*)(src + 4 * g);
  }
  __syncthreads();

  const short* PH = (const short*)PtHi + (size_t)bh * CHUNKS_ * 4096;
  const short* PL = (const short*)PtLo + (size_t)bh * CHUNKS_ * 4096;
  const float* UB = Ut + (size_t)bh * CHUNKS_ * 4096;
  float* HB = Hbuf + (size_t)bh * CHUNKS_ * 4096;

  const int arow = wave * 16 + lr;  // A-fragment row for this lane

  bf16x8 aH[2], aL[2];
  float uC[4][4];
  // prologue: prefetch chunk 0 A (P^T hi/lo) and U^T
#pragma unroll
  for (int ks = 0; ks < 2; ++ks) {
    size_t off = (size_t)arow * 64 + ks * 32 + lg * 8;
    aH[ks] = *(const bf16x8*)(PH + off);
    aL[ks] = *(const bf16x8*)(PL + off);
  }
#pragma unroll
  for (int nt = 0; nt < 4; ++nt)
#pragma unroll
    for (int r = 0; r < 4; ++r)
      uC[nt][r] = UB[(size_t)(wave * 16 + lg * 4 + r) * 64 + nt * 16 + lr];

  for (int c = 0; c < CHUNKS_; ++c) {
    // store hstart_c (current hs) for phase 3
    {
      float* dst = HB + (size_t)c * 4096 + srow * 64 + sc0;
#pragma unroll
      for (int g = 0; g < 4; ++g)
        *(float4*)(dst + 4 * g) = *(const float4*)&hsL[srow * PITCH + sc0 + 4 * g];
    }
    // B fragments: B[k][col] = hs[col][k]; cast f32 -> bf16 hi/lo
    bf16x8 bH[4][2], bL[4][2];
#pragma unroll
    for (int nt = 0; nt < 4; ++nt) {
#pragma unroll
      for (int ks = 0; ks < 2; ++ks) {
        const float* sp = &hsL[(nt * 16 + lr) * PITCH + ks * 32 + lg * 8];
        float4 f0 = *(const float4*)sp;
        float4 f1 = *(const float4*)(sp + 4);
        float fv[8] = {f0.x, f0.y, f0.z, f0.w, f1.x, f1.y, f1.z, f1.w};
        bf16x8 hi, lo;
#pragma unroll
        for (int e = 0; e < 8; ++e) {
          float rem;
          hi[e] = bf_hi(fv[e], rem);
          lo[e] = bf_of(rem);
        }
        bH[nt][ks] = hi; bL[nt][ks] = lo;
      }
    }
    // prefetch next chunk A/U (in flight across the MFMAs + barrier)
    bf16x8 aHn[2] = {}, aLn[2] = {};
    float uN[4][4];
    if (c + 1 < CHUNKS_) {
#pragma unroll
      for (int ks = 0; ks < 2; ++ks) {
        size_t off = (size_t)(c + 1) * 4096 + (size_t)arow * 64 + ks * 32 + lg * 8;
        aHn[ks] = *(const bf16x8*)(PH + off);
        aLn[ks] = *(const bf16x8*)(PL + off);
      }
#pragma unroll
      for (int nt = 0; nt < 4; ++nt)
#pragma unroll
        for (int r = 0; r < 4; ++r)
          uN[nt][r] = UB[(size_t)(c + 1) * 4096 +
                         (size_t)(wave * 16 + lg * 4 + r) * 64 + nt * 16 + lr];
    }
    // MFMAs: hi*hi + hi*lo + lo*hi (lo*lo ~ 2^-16, skipped)
    f32x4 acc[4];
#pragma unroll
    for (int nt = 0; nt < 4; ++nt) {
      f32x4 a = (f32x4){0.f, 0.f, 0.f, 0.f};
#pragma unroll
      for (int ks = 0; ks < 2; ++ks) {
        a = __builtin_amdgcn_mfma_f32_16x16x32_bf16(aH[ks], bH[nt][ks], a, 0, 0, 0);
        a = __builtin_amdgcn_mfma_f32_16x16x32_bf16(aH[ks], bL[nt][ks], a, 0, 0, 0);
        a = __builtin_amdgcn_mfma_f32_16x16x32_bf16(aL[ks], bH[nt][ks], a, 0, 0, 0);
      }
      acc[nt] = a;
    }
    __syncthreads();  // all reads of hsL complete (B-frags + Hbuf staging)
    // D'[16w+lg*4+r][16nt+lr] = hs_new[16nt+lr][16w+lg*4+r]; add U^T; write back
#pragma unroll
    for (int nt = 0; nt < 4; ++nt) {
      f32x4 v = acc[nt];
#pragma unroll
      for (int r = 0; r < 4; ++r) v[r] += uC[nt][r];
      *(f32x4*)&hsL[(nt * 16 + lr) * PITCH + wave * 16 + lg * 4] = v;
    }
    __syncthreads();
    if (c + 1 < CHUNKS_) {
#pragma unroll
      for (int ks = 0; ks < 2; ++ks) { aH[ks] = aHn[ks]; aL[ks] = aLn[ks]; }
#pragma unroll
      for (int nt = 0; nt < 4; ++nt)
#pragma unroll
        for (int r = 0; r < 4; ++r) uC[nt][r] = uN[nt][r];
    }
  }
  // final state
  {
    float* dst = out_hs + (size_t)bh * 4096 + srow * 64 + sc0;
#pragma unroll
    for (int g = 0; g < 4; ++g)
      *(float4*)(dst + 4 * g) = *(const float4*)&hsL[srow * PITCH + sc0 + 4 * g];
  }
}

// ---- phase 3: re-run each chunk from hstart_c, emit attn ----
__global__ __launch_bounds__(256) void k_apply_chunk(
    const float* __restrict__ qkv, const float* __restrict__ buv,
    const float* __restrict__ scal8, const float* __restrict__ Hbuf,
    float* __restrict__ attn) {
  int blk = blockIdx.x, bh = blk >> 5, c = blk & (CHUNKS_ - 1);
  int b = bh >> 3, h = bh & 7;
  int tid = threadIdx.x, i = tid >> 2, q4 = tid & 3, j0 = q4 * 16;
  bool writer = (q4 == 0);
  alignas(16) float hs[16];
  const float* hb = Hbuf + ((size_t)bh * CHUNKS_ + c) * 4096 + i * 64 + j0;
#pragma unroll
  for (int g = 0; g < 4; ++g) *(float4*)&hs[g * 4] = *(const float4*)(hb + g * 4);
  int m0 = b * S_ + c * CLEN_;
  StepC A, Bs;
  load_stepc(A, qkv, buv, scal8, m0, h, i, j0, true);
  load_stepc(Bs, qkv, buv, scal8, m0 + 1, h, i, j0, true);
  for (int s = 0; s < CLEN_; s += 2) {
    step_apply(hs, A, attn + ((size_t)(m0 + s) * 512 + h * 64 + i), writer);
    if (s + 2 < CLEN_) load_stepc(A, qkv, buv, scal8, m0 + s + 2, h, i, j0, true);
    step_apply(hs, Bs, attn + ((size_t)(m0 + s + 1) * 512 + h * 64 + i), writer);
    if (s + 3 < CLEN_) load_stepc(Bs, qkv, buv, scal8, m0 + s + 3, h, i, j0, true);
  }
}

// ---------------- host ----------------
extern "C" void kernel_launch(void* const* d_in, const int* in_sizes, int n_in,
                              void* d_out, int out_size, void* d_ws, size_t ws_size,
                              hipStream_t stream) {
  const float* x      = (const float*)d_in[0];
  const int*   action = (const int*)d_in[1];
  const int*   mask   = (const int*)d_in[2];
  const float* carry  = (const float*)d_in[3];
  const float* n1s    = (const float*)d_in[4];
  const float* wq     = (const float*)d_in[5];
  const float* wk     = (const float*)d_in[6];
  const float* wv     = (const float*)d_in[7];
  const float* wbeta  = (const float*)d_in[8];
  const float* embed  = (const float*)d_in[9];
  const float* walpha = (const float*)d_in[10];
  const float* wbu    = (const float*)d_in[11];
  const float* wbv    = (const float*)d_in[12];
  const float* nas    = (const float*)d_in[13];
  const float* wout   = (const float*)d_in[14];
  const float* bout   = (const float*)d_in[15];
  const float* n2s    = (const float*)d_in[16];
  const float* wgate  = (const float*)d_in[17];
  const float* wval   = (const float*)d_in[18];
  const float* wffn   = (const float*)d_in[19];

  float* out_hs  = (float*)d_out;            // [2,8,64,64]
  float* out_ffn = (float*)d_out + 65536;    // [2,1024,512]

  char* p = (char*)d_ws;
  auto alloc = [&](size_t bytes) -> char* {
    char* r = p; p += (bytes + 255) & ~(size_t)255; return r;
  };
  bf16*  wqkvT = (bf16*)alloc((size_t)1536 * 512 * 2);
  bf16*  wbuvT = (bf16*)alloc((size_t)1024 * 512 * 2);
  bf16*  woutT = (bf16*)alloc((size_t)512 * 512 * 2);
  bf16*  wgvT  = (bf16*)alloc((size_t)4096 * 512 * 2);
  bf16*  wffnT = (bf16*)alloc((size_t)512 * 2048 * 2);
  float* hF    = (float*)alloc((size_t)M_ * 512 * 4);
  bf16*  hB    = (bf16*)alloc((size_t)M_ * 512 * 2);
  float* aeF   = (float*)alloc((size_t)M_ * 512 * 4);
  bf16*  aeB   = (bf16*)alloc((size_t)M_ * 512 * 2);
  float* qkvF  = (float*)alloc((size_t)M_ * 1536 * 4);
  float* buvF  = (float*)alloc((size_t)M_ * 1024 * 4);
  float* betaF = (float*)alloc((size_t)M_ * 8 * 4);
  float* alphaF= (float*)alloc((size_t)M_ * 8 * 4);
  float* scal8 = (float*)alloc((size_t)M_ * 8 * 8 * 4);
  float* attnF = (float*)alloc((size_t)M_ * 512 * 4);
  bf16*  attnB = (bf16*)alloc((size_t)M_ * 512 * 2);
  float* skipF = (float*)alloc((size_t)M_ * 512 * 4);
  bf16*  h2B   = (bf16*)alloc((size_t)M_ * 512 * 2);
  float* gvF   = (float*)alloc((size_t)M_ * 4096 * 4);
  bf16*  ffnB  = (bf16*)alloc((size_t)M_ * 2048 * 2);
  if ((size_t)(p - (char*)d_ws) > ws_size) return;  // workspace too small

  // chunk buffers alias gvF (33.5 MB), which is written only after phase 3.
  // PtHi 4MB | PtLo 4MB | Ut 8MB | Hbuf 8MB
  constexpr size_t CELEMS = (size_t)16 * CHUNKS_ * 4096;
  bf16*  PtHi = (bf16*)gvF;
  bf16*  PtLo = (bf16*)gvF + CELEMS;
  float* UtB  = gvF + CELEMS;            // floats: skips the 8MB of PtHi+PtLo
  float* Hbuf = gvF + CELEMS * 3;        // skips PtHi+PtLo (2MB-f32 each... in f32 units)
  // NOTE: gvF is float*; CELEMS bf16 = CELEMS/2 floats. Compute carefully in bytes:
  {
    char* base = (char*)gvF;
    PtHi = (bf16*)(base);
    PtLo = (bf16*)(base + CELEMS * 2);
    UtB  = (float*)(base + CELEMS * 4);
    Hbuf = (float*)(base + CELEMS * 4 + CELEMS * 4);
  }

  // fused weight transposes (9 jobs, 1 dispatch)
  TTab tab;
  tab.j[0] = {wq,    wqkvT,              512,  512,  0};
  tab.j[1] = {wk,    wqkvT + 512 * 512,  512,  512,  256};
  tab.j[2] = {wv,    wqkvT + 1024 * 512, 512,  512,  512};
  tab.j[3] = {wbu,   wbuvT,              512,  512,  768};
  tab.j[4] = {wbv,   wbuvT + 512 * 512,  512,  512,  1024};
  tab.j[5] = {wout,  woutT,              512,  512,  1280};
  tab.j[6] = {wgate, wgvT,               512,  2048, 1536};
  tab.j[7] = {wval,  wgvT + 2048 * 512,  512,  2048, 2560};
  tab.j[8] = {wffn,  wffnT,              2048, 512,  3584};
  k_transpose_all<<<4608, dim3(32, 8), 0, stream>>>(tab);

  k_rmsnorm<<<M_, 256, 0, stream>>>(x, n1s, hF, hB);
  k_gather<<<M_, 256, 0, stream>>>(action, embed, aeF, aeB);

  k_gemm<1, 2><<<dim3(1536 / 64, 16), 256, 0, stream>>>(hB, wqkvT, qkvF, M_, 1536, 512, 1024, nullptr, nullptr);
  k_gemm<0, 2><<<dim3(1024 / 64, 16), 256, 0, stream>>>(aeB, wbuvT, buvF, M_, 1024, 512, 0, nullptr, nullptr);
  k_dot8_sigmoid<<<M_, 256, 0, stream>>>(hF, wbeta, betaF);
  k_dot8_sigmoid<<<M_, 256, 0, stream>>>(aeF, walpha, alphaF);
  k_qknorm_dots<<<M_ * 8, 64, 0, stream>>>(qkvF, buvF, betaF, alphaF, mask, scal8);

  k_scan_chunk<<<16 * CHUNKS_, 256, 0, stream>>>(qkvF, buvF, scal8, PtHi, PtLo, UtB);
  k_chain2<<<16, 256, 0, stream>>>(PtHi, PtLo, UtB, carry, Hbuf, out_hs);
  k_apply_chunk<<<16 * CHUNKS_, 256, 0, stream>>>(qkvF, buvF, scal8, Hbuf, attnF);

  k_rmsnorm<<<M_, 256, 0, stream>>>(attnF, nas, nullptr, attnB);
  k_gemm<2, 2><<<dim3(512 / 64, 16), 256, 0, stream>>>(attnB, woutT, skipF, M_, 512, 512, 0, bout, x);
  k_rmsnorm<<<M_, 256, 0, stream>>>(skipF, n2s, nullptr, h2B);
  k_gemm<0, 4><<<dim3(4096 / 128, 16), 256, 0, stream>>>(h2B, wgvT, gvF, M_, 4096, 512, 0, nullptr, nullptr);
  k_swiglu<<<(M_ * 2048) / 256, 256, 0, stream>>>(gvF, ffnB);
  k_gemm<3, 2><<<dim3(512 / 64, 16), 256, 0, stream>>>(ffnB, wffnT, out_ffn, M_, 512, 2048, 0, nullptr, skipF);
}

// Round 4
// 245.798 us; speedup vs baseline: 6.7270x; 1.4720x over previous
//
#include <hip/hip_runtime.h>
#include <hip/hip_bf16.h>
#include <cstdint>
#include <cstddef>

using bf16 = __hip_bfloat16;
typedef __attribute__((ext_vector_type(8))) short bf16x8;  // 8 bf16 (4 VGPRs)
typedef __attribute__((ext_vector_type(4))) float f32x4;

static constexpr int B_ = 2, S_ = 1024, D_ = 512, H_ = 8;
static constexpr int M_ = B_ * S_;     // 2048 rows
static constexpr int CHUNKS_ = 32, CLEN_ = 32;  // S = CHUNKS * CLEN
static constexpr float EPS_ = 1e-6f;

__device__ __forceinline__ float sigmoidf_(float x) { return 1.0f / (1.0f + __expf(-x)); }

__device__ __forceinline__ short bf_hi(float v, float& rem) {
  bf16 h = __float2bfloat16(v);
  rem = v - __bfloat162float(h);
  return *(short*)&h;
}
__device__ __forceinline__ short bf_of(float v) {
  bf16 h = __float2bfloat16(v);
  return *(short*)&h;
}

// -------- fused transpose + cast: W [K][N] f32 -> Wt [dstRow(n)][K] bf16 --------
// xf: 0 linear; 1 gate-interleave (row = (n>>5)*64 + (n&31)); 2 val (+32)
struct TJob { const float* src; bf16* dst; int K, N, base, xf; };
struct TTab { TJob j[9]; };

__global__ __launch_bounds__(256) void k_transpose_all(TTab tab) {
  __shared__ float tile[32][33];
  int blk = blockIdx.x;
  int ji = 0;
#pragma unroll
  for (int t = 1; t < 9; ++t) if (tab.j[t].base <= blk) ji = t;
  const float* W = tab.j[ji].src;
  bf16* Wt = tab.j[ji].dst;
  int K = tab.j[ji].K, N = tab.j[ji].N, xf = tab.j[ji].xf;
  int rel = blk - tab.j[ji].base;
  int nb = N >> 5;
  int n0 = (rel % nb) * 32, k0 = (rel / nb) * 32;
  int tx = threadIdx.x, ty = threadIdx.y;  // 32 x 8
#pragma unroll
  for (int r = ty; r < 32; r += 8) tile[r][tx] = W[(size_t)(k0 + r) * N + n0 + tx];
  __syncthreads();
#pragma unroll
  for (int r = ty; r < 32; r += 8) {
    int n = n0 + r;
    int drow = n;
    if (xf == 1) drow = ((n >> 5) << 6) + (n & 31);
    else if (xf == 2) drow = ((n >> 5) << 6) + (n & 31) + 32;
    Wt[(size_t)drow * K + k0 + tx] = __float2bfloat16(tile[tx][r]);
  }
}

// ---------------- rmsnorm over D=512, optional f32 + bf16 outputs ----------------
__global__ __launch_bounds__(256) void k_rmsnorm(const float* __restrict__ x,
                                                 const float* __restrict__ scale,
                                                 float* __restrict__ outf,
                                                 bf16* __restrict__ outb) {
  int m = blockIdx.x, tid = threadIdx.x;
  const float* row = x + (size_t)m * D_;
  float2 v = *(const float2*)(row + tid * 2);
  float ss = v.x * v.x + v.y * v.y;
#pragma unroll
  for (int o = 1; o < 64; o <<= 1) ss += __shfl_xor(ss, o);
  __shared__ float wsum[4];
  if ((tid & 63) == 0) wsum[tid >> 6] = ss;
  __syncthreads();
  float tot = wsum[0] + wsum[1] + wsum[2] + wsum[3];
  float rs = rsqrtf(tot * (1.0f / (float)D_) + EPS_);
  float2 sc = *(const float2*)(scale + tid * 2);
  float o0 = v.x * rs * sc.x, o1 = v.y * rs * sc.y;
  if (outf) {
    float2 o; o.x = o0; o.y = o1;
    *(float2*)(outf + (size_t)m * D_ + tid * 2) = o;
  }
  if (outb) {
    bf16* p = outb + (size_t)m * D_ + tid * 2;
    p[0] = __float2bfloat16(o0); p[1] = __float2bfloat16(o1);
  }
}

// ---------------- action-embedding gather ----------------
__global__ __launch_bounds__(256) void k_gather(const int* __restrict__ action,
                                                const float* __restrict__ embed,
                                                float* __restrict__ aef, bf16* __restrict__ aeb) {
  int m = blockIdx.x, tid = threadIdx.x;
  int a = action[m];
  float2 v = *(const float2*)(embed + (size_t)a * 512 + tid * 2);
  *(float2*)(aef + (size_t)m * 512 + tid * 2) = v;
  bf16* p = aeb + (size_t)m * 512 + tid * 2;
  p[0] = __float2bfloat16(v.x); p[1] = __float2bfloat16(v.y);
}

// ---- beta = sigmoid(hF@wbeta), alpha = sigmoid(aeF@walpha) in one dispatch ----
__global__ __launch_bounds__(256) void k_dot8x2(const float* __restrict__ hF,
                                                const float* __restrict__ aeF,
                                                const float* __restrict__ W1,
                                                const float* __restrict__ W2,
                                                float* __restrict__ o1,
                                                float* __restrict__ o2) {
  int m = blockIdx.x, tid = threadIdx.x;
  float x0 = hF[(size_t)m * D_ + tid], x1 = hF[(size_t)m * D_ + 256 + tid];
  float y0 = aeF[(size_t)m * D_ + tid], y1 = aeF[(size_t)m * D_ + 256 + tid];
  float p[8], q[8];
#pragma unroll
  for (int j = 0; j < 8; ++j) {
    p[j] = x0 * W1[tid * 8 + j] + x1 * W1[(tid + 256) * 8 + j];
    q[j] = y0 * W2[tid * 8 + j] + y1 * W2[(tid + 256) * 8 + j];
  }
#pragma unroll
  for (int j = 0; j < 8; ++j) {
#pragma unroll
    for (int o = 1; o < 64; o <<= 1) {
      p[j] += __shfl_xor(p[j], o);
      q[j] += __shfl_xor(q[j], o);
    }
  }
  __shared__ float sacc[4][16];
  if ((tid & 63) == 0) {
#pragma unroll
    for (int j = 0; j < 8; ++j) { sacc[tid >> 6][j] = p[j]; sacc[tid >> 6][8 + j] = q[j]; }
  }
  __syncthreads();
  if (tid < 8) {
    float s = sacc[0][tid] + sacc[1][tid] + sacc[2][tid] + sacc[3][tid];
    o1[(size_t)m * 8 + tid] = sigmoidf_(s);
  } else if (tid < 16) {
    int j = tid - 8;
    float s = sacc[0][8 + j] + sacc[1][8 + j] + sacc[2][8 + j] + sacc[3][8 + j];
    o2[(size_t)m * 8 + j] = sigmoidf_(s);
  }
}

// ---- per (m,h): L2-normalize q,k in place; pack scal8 = {beta, g, kq, kbv, bvq} ----
// 4 (m,h) wave-jobs per 256-thread block.
__global__ __launch_bounds__(256) void k_qknorm_dots(float* __restrict__ qkv,
                                                     const float* __restrict__ buv,
                                                     const float* __restrict__ betaF,
                                                     const float* __restrict__ alphaF,
                                                     const int* __restrict__ mask,
                                                     float* __restrict__ scal8) {
  int blk = blockIdx.x * 4 + (threadIdx.x >> 6);
  int m = blk >> 3, h = blk & 7, t = threadIdx.x & 63;
  size_t qi = (size_t)m * 1536 + h * 64 + t;
  float q = qkv[qi], k = qkv[qi + 512];
  float bv = buv[(size_t)m * 1024 + 512 + h * 64 + t];
  float qs = q * q, ks = k * k;
#pragma unroll
  for (int o = 1; o < 64; o <<= 1) { qs += __shfl_xor(qs, o); ks += __shfl_xor(ks, o); }
  float qn = q / (sqrtf(qs) + EPS_);
  float kn = k / (sqrtf(ks) + EPS_);
  qkv[qi] = qn; qkv[qi + 512] = kn;
  float d0 = kn * qn, d1 = kn * bv, d2 = bv * qn;
#pragma unroll
  for (int o = 1; o < 64; o <<= 1) {
    d0 += __shfl_xor(d0, o); d1 += __shfl_xor(d1, o); d2 += __shfl_xor(d2, o);
  }
  if (t == 0) {
    int mh = m * 8 + h;
    float4 s4;
    s4.x = betaF[mh];
    s4.y = alphaF[mh] * (1.0f - (float)mask[m]);
    s4.z = d0; s4.w = d1;
    *(float4*)(scal8 + (size_t)mh * 8) = s4;
    scal8[(size_t)mh * 8 + 4] = d2;
  }
}

// ======== pipelined bf16 MFMA GEMM: C = epi(A[M,K] @ Bt[N,K]^T), 64x64 tile ========
// EPI: 0 none; 1 silu if col<actSplit; 2 +bias[col]+res; 3 +res;
//      4 swiglu-combine (Bt is gate/val row-interleaved in 64-row groups; C is bf16
//        [M][2048], out cols [32*bx, 32*bx+32))
template <int EPI>
__global__ __launch_bounds__(256) void k_gemm2(const bf16* __restrict__ A,
                                               const bf16* __restrict__ Bt,
                                               void* __restrict__ Cv, int M, int N, int K,
                                               int actSplit, const float* __restrict__ bias,
                                               const float* __restrict__ res) {
  __shared__ bf16 As[2][64 * 32];
  __shared__ bf16 Bs[2][64 * 32];
  const int tid = threadIdx.x;
  const int wave = tid >> 6, lane = tid & 63;
  const int wm = wave >> 1, wn = wave & 1;
  const int m0 = blockIdx.y * 64, n0 = blockIdx.x * 64;
  const int lr = lane & 15, lg = lane >> 4;
  // staging: lane -> (row = 16*wave + (lane>>2), k-chunk = (lane&3)*8); LDS dest tid*8
  const int srow = (wave << 4) | (lane >> 2);
  const int skb = (lane & 3) << 3;
  const bf16* ga = A + (size_t)(m0 + srow) * K + skb;
  const bf16* gb = Bt + (size_t)(n0 + srow) * K + skb;

  f32x4 acc[2][2];
#pragma unroll
  for (int i = 0; i < 2; ++i)
#pragma unroll
    for (int j = 0; j < 2; ++j) acc[i][j] = (f32x4){0.f, 0.f, 0.f, 0.f};

  const int nk = K >> 5;
  int4 ar = *(const int4*)ga;
  int4 br = *(const int4*)gb;
  for (int t = 0; t < nk; ++t) {
    bf16* asb = &As[t & 1][0];
    bf16* bsb = &Bs[t & 1][0];
    *(int4*)(asb + tid * 8) = ar;   // waits on this tile's loads only
    *(int4*)(bsb + tid * 8) = br;
    __syncthreads();
    if (t + 1 < nk) {               // issue next tile; in flight across compute
      ar = *(const int4*)(ga + ((size_t)(t + 1) << 5));
      br = *(const int4*)(gb + ((size_t)(t + 1) << 5));
    }
    bf16x8 af[2], bfr[2];
#pragma unroll
    for (int mm = 0; mm < 2; ++mm)
      af[mm] = *(const bf16x8*)(asb + (wm * 32 + mm * 16 + lr) * 32 + lg * 8);
#pragma unroll
    for (int nn = 0; nn < 2; ++nn)
      bfr[nn] = *(const bf16x8*)(bsb + (wn * 32 + nn * 16 + lr) * 32 + lg * 8);
#pragma unroll
    for (int mm = 0; mm < 2; ++mm)
#pragma unroll
      for (int nn = 0; nn < 2; ++nn)
        acc[mm][nn] = __builtin_amdgcn_mfma_f32_16x16x32_bf16(af[mm], bfr[nn], acc[mm][nn], 0, 0, 0);
  }

  if constexpr (EPI == 4) {
    __syncthreads();  // done with LDS tiles; reuse as f32 scratch
    float* gateL = (float*)&As[0][0];  // [64][32] f32
    float* valL = (float*)&Bs[0][0];   // [64][32] f32
    float* dstL = wn ? valL : gateL;
#pragma unroll
    for (int mm = 0; mm < 2; ++mm)
#pragma unroll
      for (int nn = 0; nn < 2; ++nn)
#pragma unroll
        for (int r = 0; r < 4; ++r)
          dstL[(wm * 32 + mm * 16 + lg * 4 + r) * 32 + nn * 16 + lr] = acc[mm][nn][r];
    __syncthreads();
    bf16* Cb = (bf16*)Cv;
    int row = tid >> 2, c0 = (tid & 3) * 8;
    bf16x8 o;
#pragma unroll
    for (int e = 0; e < 8; ++e) {
      float g = gateL[row * 32 + c0 + e];
      float v = valL[row * 32 + c0 + e];
      o[e] = bf_of(g * sigmoidf_(g) * v);
    }
    *(int4*)(Cb + (size_t)(m0 + row) * 2048 + blockIdx.x * 32 + c0) = *(int4*)&o;
  } else {
    float* C = (float*)Cv;
#pragma unroll
    for (int mm = 0; mm < 2; ++mm) {
#pragma unroll
      for (int nn = 0; nn < 2; ++nn) {
#pragma unroll
        for (int r = 0; r < 4; ++r) {
          int row = m0 + wm * 32 + mm * 16 + lg * 4 + r;
          int col = n0 + wn * 32 + nn * 16 + lr;
          float v = acc[mm][nn][r];
          if constexpr (EPI == 1) {
            if (col < actSplit) v = v * sigmoidf_(v);
          }
          if constexpr (EPI == 2) v += bias[col] + res[(size_t)row * N + col];
          if constexpr (EPI == 3) v += res[(size_t)row * N + col];
          C[(size_t)row * N + col] = v;
        }
      }
    }
  }
}

// ================= chunked recurrence =================
struct alignas(16) StepC {
  float k[16], bv[16], q[16];
  float v_i, bu_i, beta, g, kq, kbv, bvq;
};

__device__ __forceinline__ void load_stepc(StepC& sd,
    const float* __restrict__ qkv, const float* __restrict__ buv,
    const float* __restrict__ scal8, int m, int h, int i, int j0, bool withq) {
  const float* qb = qkv + (size_t)m * 1536 + h * 64;
  const float* bb = buv + (size_t)m * 1024 + h * 64;
#pragma unroll
  for (int p = 0; p < 4; ++p) *(float4*)&sd.k[p * 4] = *(const float4*)(qb + 512 + j0 + p * 4);
#pragma unroll
  for (int p = 0; p < 4; ++p) *(float4*)&sd.bv[p * 4] = *(const float4*)(bb + 512 + j0 + p * 4);
  if (withq) {
#pragma unroll
    for (int p = 0; p < 4; ++p) *(float4*)&sd.q[p * 4] = *(const float4*)(qb + j0 + p * 4);
  }
  sd.v_i = qb[1024 + i];
  sd.bu_i = bb[i];
  const float* sp = scal8 + (size_t)(m * 8 + h) * 8;
  float4 s4 = *(const float4*)sp;
  sd.beta = s4.x; sd.g = s4.y; sd.kq = s4.z; sd.kbv = s4.w;
  if (withq) sd.bvq = sp[4];
}

__device__ __forceinline__ void step_fold(float P[16], float U[16], const StepC& sd) {
  float Pk = 0.f, Uk = 0.f;
#pragma unroll
  for (int jj = 0; jj < 16; ++jj) { Pk += P[jj] * sd.k[jj]; Uk += U[jj] * sd.k[jj]; }
  Pk += __shfl_xor(Pk, 1); Pk += __shfl_xor(Pk, 2);
  Uk += __shfl_xor(Uk, 1); Uk += __shfl_xor(Uk, 2);
  float gb = sd.g * sd.beta;
  float cP = gb * Pk;
  float Ai = sd.beta * sd.v_i - gb * Uk - sd.bu_i * sd.beta * sd.kbv;
#pragma unroll
  for (int jj = 0; jj < 16; ++jj) {
    P[jj] = sd.g * P[jj] - cP * sd.k[jj];
    U[jj] = sd.g * U[jj] + Ai * sd.k[jj] + sd.bu_i * sd.bv[jj];
  }
}

__device__ __forceinline__ void step_apply(float hs[16], const StepC& sd,
                                           float* __restrict__ attn_addr, bool writer) {
  float u = 0.f, w = 0.f;
#pragma unroll
  for (int jj = 0; jj < 16; ++jj) { u += hs[jj] * sd.k[jj]; w += hs[jj] * sd.q[jj]; }
  u += __shfl_xor(u, 1); u += __shfl_xor(u, 2);
  w += __shfl_xor(w, 1); w += __shfl_xor(w, 2);
  float a_i = sd.beta * sd.v_i - sd.g * sd.beta * u;
  float c = sd.beta * sd.kbv;
#pragma unroll
  for (int jj = 0; jj < 16; ++jj) {
    float bvp = sd.bv[jj] - c * sd.k[jj];
    hs[jj] = sd.g * hs[jj] + a_i * sd.k[jj] + sd.bu_i * bvp;
  }
  if (writer) *attn_addr = sd.g * w + a_i * sd.kq + sd.bu_i * (sd.bvq - c * sd.kq);
}

// ---- phase 1: per-chunk transition, emitted as P^T (bf16 hi/lo) + U^T (f32) ----
__global__ __launch_bounds__(256) void k_scan_chunk(
    const float* __restrict__ qkv, const float* __restrict__ buv,
    const float* __restrict__ scal8, bf16* __restrict__ PtHi,
    bf16* __restrict__ PtLo, float* __restrict__ Ut) {
  int blk = blockIdx.x, bh = blk >> 5, c = blk & (CHUNKS_ - 1);
  int b = bh >> 3, h = bh & 7;
  int tid = threadIdx.x, i = tid >> 2, q4 = tid & 3, j0 = q4 * 16;
  alignas(16) float P[16], U[16];
#pragma unroll
  for (int jj = 0; jj < 16; ++jj) { P[jj] = (j0 + jj == i) ? 1.f : 0.f; U[jj] = 0.f; }
  int m0 = b * S_ + c * CLEN_;
  StepC A, Bs;
  load_stepc(A, qkv, buv, scal8, m0, h, i, j0, false);
  load_stepc(Bs, qkv, buv, scal8, m0 + 1, h, i, j0, false);
  for (int s = 0; s < CLEN_; s += 2) {
    step_fold(P, U, A);
    if (s + 2 < CLEN_) load_stepc(A, qkv, buv, scal8, m0 + s + 2, h, i, j0, false);
    step_fold(P, U, Bs);
    if (s + 3 < CLEN_) load_stepc(Bs, qkv, buv, scal8, m0 + s + 3, h, i, j0, false);
  }
  const size_t base = ((size_t)bh * CHUNKS_ + c) * 4096;
#pragma unroll
  for (int jj = 0; jj < 16; ++jj) {
    int j = j0 + jj;
    float pv = P[jj];
    float rem;
    short ph = bf_hi(pv, rem);
    short pl = bf_of(rem);
    ((short*)PtHi)[base + (size_t)j * 64 + i] = ph;
    ((short*)PtLo)[base + (size_t)j * 64 + i] = pl;
    Ut[base + (size_t)j * 64 + i] = U[jj];
  }
}

// ---- phase 2: MFMA chain (split-precision bf16), one block per bh ----
__global__ __launch_bounds__(256) void k_chain2(
    const bf16* __restrict__ PtHi, const bf16* __restrict__ PtLo,
    const float* __restrict__ Ut, const float* __restrict__ carry,
    float* __restrict__ Hbuf, float* __restrict__ out_hs) {
  constexpr int PITCH = 68;
  __shared__ float hsL[64 * PITCH];
  const int bh = blockIdx.x, tid = threadIdx.x;
  const int wave = tid >> 6, lane = tid & 63;
  const int lr = lane & 15, lg = lane >> 4;
  const int srow = tid >> 2, sc0 = (tid & 3) * 16;

  {
    const float* src = carry + (size_t)bh * 4096 + srow * 64 + sc0;
#pragma unroll
    for (int g = 0; g < 4; ++g)
      *(float4*)&hsL[srow * PITCH + sc0 + 4 * g] = *(const float4*)(src + 4 * g);
  }
  __syncthreads();

  const short* PH = (const short*)PtHi + (size_t)bh * CHUNKS_ * 4096;
  const short* PL = (const short*)PtLo + (size_t)bh * CHUNKS_ * 4096;
  const float* UB = Ut + (size_t)bh * CHUNKS_ * 4096;
  float* HB = Hbuf + (size_t)bh * CHUNKS_ * 4096;

  const int arow = wave * 16 + lr;

  bf16x8 aH[2], aL[2];
  float uC[4][4];
#pragma unroll
  for (int ks = 0; ks < 2; ++ks) {
    size_t off = (size_t)arow * 64 + ks * 32 + lg * 8;
    aH[ks] = *(const bf16x8*)(PH + off);
    aL[ks] = *(const bf16x8*)(PL + off);
  }
#pragma unroll
  for (int nt = 0; nt < 4; ++nt)
#pragma unroll
    for (int r = 0; r < 4; ++r)
      uC[nt][r] = UB[(size_t)(wave * 16 + lg * 4 + r) * 64 + nt * 16 + lr];

  for (int c = 0; c < CHUNKS_; ++c) {
    {
      float* dst = HB + (size_t)c * 4096 + srow * 64 + sc0;
#pragma unroll
      for (int g = 0; g < 4; ++g)
        *(float4*)(dst + 4 * g) = *(const float4*)&hsL[srow * PITCH + sc0 + 4 * g];
    }
    bf16x8 bH[4][2], bL[4][2];
#pragma unroll
    for (int nt = 0; nt < 4; ++nt) {
#pragma unroll
      for (int ks = 0; ks < 2; ++ks) {
        const float* sp = &hsL[(nt * 16 + lr) * PITCH + ks * 32 + lg * 8];
        float4 f0 = *(const float4*)sp;
        float4 f1 = *(const float4*)(sp + 4);
        float fv[8] = {f0.x, f0.y, f0.z, f0.w, f1.x, f1.y, f1.z, f1.w};
        bf16x8 hi, lo;
#pragma unroll
        for (int e = 0; e < 8; ++e) {
          float rem;
          hi[e] = bf_hi(fv[e], rem);
          lo[e] = bf_of(rem);
        }
        bH[nt][ks] = hi; bL[nt][ks] = lo;
      }
    }
    bf16x8 aHn[2] = {}, aLn[2] = {};
    float uN[4][4];
    if (c + 1 < CHUNKS_) {
#pragma unroll
      for (int ks = 0; ks < 2; ++ks) {
        size_t off = (size_t)(c + 1) * 4096 + (size_t)arow * 64 + ks * 32 + lg * 8;
        aHn[ks] = *(const bf16x8*)(PH + off);
        aLn[ks] = *(const bf16x8*)(PL + off);
      }
#pragma unroll
      for (int nt = 0; nt < 4; ++nt)
#pragma unroll
        for (int r = 0; r < 4; ++r)
          uN[nt][r] = UB[(size_t)(c + 1) * 4096 +
                         (size_t)(wave * 16 + lg * 4 + r) * 64 + nt * 16 + lr];
    }
    f32x4 acc[4];
#pragma unroll
    for (int nt = 0; nt < 4; ++nt) {
      f32x4 a = (f32x4){0.f, 0.f, 0.f, 0.f};
#pragma unroll
      for (int ks = 0; ks < 2; ++ks) {
        a = __builtin_amdgcn_mfma_f32_16x16x32_bf16(aH[ks], bH[nt][ks], a, 0, 0, 0);
        a = __builtin_amdgcn_mfma_f32_16x16x32_bf16(aH[ks], bL[nt][ks], a, 0, 0, 0);
        a = __builtin_amdgcn_mfma_f32_16x16x32_bf16(aL[ks], bH[nt][ks], a, 0, 0, 0);
      }
      acc[nt] = a;
    }
    __syncthreads();
#pragma unroll
    for (int nt = 0; nt < 4; ++nt) {
      f32x4 v = acc[nt];
#pragma unroll
      for (int r = 0; r < 4; ++r) v[r] += uC[nt][r];
      *(f32x4*)&hsL[(nt * 16 + lr) * PITCH + wave * 16 + lg * 4] = v;
    }
    __syncthreads();
    if (c + 1 < CHUNKS_) {
#pragma unroll
      for (int ks = 0; ks < 2; ++ks) { aH[ks] = aHn[ks]; aL[ks] = aLn[ks]; }
#pragma unroll
      for (int nt = 0; nt < 4; ++nt)
#pragma unroll
        for (int r = 0; r < 4; ++r) uC[nt][r] = uN[nt][r];
    }
  }
  {
    float* dst = out_hs + (size_t)bh * 4096 + srow * 64 + sc0;
#pragma unroll
    for (int g = 0; g < 4; ++g)
      *(float4*)(dst + 4 * g) = *(const float4*)&hsL[srow * PITCH + sc0 + 4 * g];
  }
}

// ---- phase 3: re-run each chunk from hstart_c, emit attn ----
__global__ __launch_bounds__(256) void k_apply_chunk(
    const float* __restrict__ qkv, const float* __restrict__ buv,
    const float* __restrict__ scal8, const float* __restrict__ Hbuf,
    float* __restrict__ attn) {
  int blk = blockIdx.x, bh = blk >> 5, c = blk & (CHUNKS_ - 1);
  int b = bh >> 3, h = bh & 7;
  int tid = threadIdx.x, i = tid >> 2, q4 = tid & 3, j0 = q4 * 16;
  bool writer = (q4 == 0);
  alignas(16) float hs[16];
  const float* hb = Hbuf + ((size_t)bh * CHUNKS_ + c) * 4096 + i * 64 + j0;
#pragma unroll
  for (int g = 0; g < 4; ++g) *(float4*)&hs[g * 4] = *(const float4*)(hb + g * 4);
  int m0 = b * S_ + c * CLEN_;
  StepC A, Bs;
  load_stepc(A, qkv, buv, scal8, m0, h, i, j0, true);
  load_stepc(Bs, qkv, buv, scal8, m0 + 1, h, i, j0, true);
  for (int s = 0; s < CLEN_; s += 2) {
    step_apply(hs, A, attn + ((size_t)(m0 + s) * 512 + h * 64 + i), writer);
    if (s + 2 < CLEN_) load_stepc(A, qkv, buv, scal8, m0 + s + 2, h, i, j0, true);
    step_apply(hs, Bs, attn + ((size_t)(m0 + s + 1) * 512 + h * 64 + i), writer);
    if (s + 3 < CLEN_) load_stepc(Bs, qkv, buv, scal8, m0 + s + 3, h, i, j0, true);
  }
}

// ---------------- host ----------------
extern "C" void kernel_launch(void* const* d_in, const int* in_sizes, int n_in,
                              void* d_out, int out_size, void* d_ws, size_t ws_size,
                              hipStream_t stream) {
  const float* x      = (const float*)d_in[0];
  const int*   action = (const int*)d_in[1];
  const int*   mask   = (const int*)d_in[2];
  const float* carry  = (const float*)d_in[3];
  const float* n1s    = (const float*)d_in[4];
  const float* wq     = (const float*)d_in[5];
  const float* wk     = (const float*)d_in[6];
  const float* wv     = (const float*)d_in[7];
  const float* wbeta  = (const float*)d_in[8];
  const float* embed  = (const float*)d_in[9];
  const float* walpha = (const float*)d_in[10];
  const float* wbu    = (const float*)d_in[11];
  const float* wbv    = (const float*)d_in[12];
  const float* nas    = (const float*)d_in[13];
  const float* wout   = (const float*)d_in[14];
  const float* bout   = (const float*)d_in[15];
  const float* n2s    = (const float*)d_in[16];
  const float* wgate  = (const float*)d_in[17];
  const float* wval   = (const float*)d_in[18];
  const float* wffn   = (const float*)d_in[19];

  float* out_hs  = (float*)d_out;            // [2,8,64,64]
  float* out_ffn = (float*)d_out + 65536;    // [2,1024,512]

  char* p = (char*)d_ws;
  auto alloc = [&](size_t bytes) -> char* {
    char* r = p; p += (bytes + 255) & ~(size_t)255; return r;
  };
  bf16*  wqkvT = (bf16*)alloc((size_t)1536 * 512 * 2);
  bf16*  wbuvT = (bf16*)alloc((size_t)1024 * 512 * 2);
  bf16*  woutT = (bf16*)alloc((size_t)512 * 512 * 2);
  bf16*  wgvT  = (bf16*)alloc((size_t)4096 * 512 * 2);   // gate/val row-interleaved
  bf16*  wffnT = (bf16*)alloc((size_t)512 * 2048 * 2);
  float* hF    = (float*)alloc((size_t)M_ * 512 * 4);
  bf16*  hB    = (bf16*)alloc((size_t)M_ * 512 * 2);
  float* aeF   = (float*)alloc((size_t)M_ * 512 * 4);
  bf16*  aeB   = (bf16*)alloc((size_t)M_ * 512 * 2);
  float* qkvF  = (float*)alloc((size_t)M_ * 1536 * 4);
  float* buvF  = (float*)alloc((size_t)M_ * 1024 * 4);
  float* betaF = (float*)alloc((size_t)M_ * 8 * 4);
  float* alphaF= (float*)alloc((size_t)M_ * 8 * 4);
  float* scal8 = (float*)alloc((size_t)M_ * 8 * 8 * 4);
  float* attnF = (float*)alloc((size_t)M_ * 512 * 4);
  bf16*  attnB = (bf16*)alloc((size_t)M_ * 512 * 2);
  float* skipF = (float*)alloc((size_t)M_ * 512 * 4);
  bf16*  h2B   = (bf16*)alloc((size_t)M_ * 512 * 2);
  bf16*  ffnB  = (bf16*)alloc((size_t)M_ * 2048 * 2);
  char*  chunkWS = alloc((size_t)24 * 1024 * 1024);      // Pt/Ut/H chunk buffers
  if ((size_t)(p - (char*)d_ws) > ws_size) return;  // workspace too small

  constexpr size_t CELEMS = (size_t)16 * CHUNKS_ * 4096;
  bf16*  PtHi = (bf16*)(chunkWS);
  bf16*  PtLo = (bf16*)(chunkWS + CELEMS * 2);
  float* UtB  = (float*)(chunkWS + CELEMS * 4);
  float* Hbuf = (float*)(chunkWS + CELEMS * 8);

  // fused weight transposes (9 jobs, 1 dispatch); wgate/wval interleave into wgvT
  TTab tab;
  tab.j[0] = {wq,    wqkvT,              512,  512,  0,    0};
  tab.j[1] = {wk,    wqkvT + 512 * 512,  512,  512,  256,  0};
  tab.j[2] = {wv,    wqkvT + 1024 * 512, 512,  512,  512,  0};
  tab.j[3] = {wbu,   wbuvT,              512,  512,  768,  0};
  tab.j[4] = {wbv,   wbuvT + 512 * 512,  512,  512,  1024, 0};
  tab.j[5] = {wout,  woutT,              512,  512,  1280, 0};
  tab.j[6] = {wgate, wgvT,               512,  2048, 1536, 1};
  tab.j[7] = {wval,  wgvT,               512,  2048, 2560, 2};
  tab.j[8] = {wffn,  wffnT,              2048, 512,  3584, 0};
  k_transpose_all<<<4608, dim3(32, 8), 0, stream>>>(tab);

  k_rmsnorm<<<M_, 256, 0, stream>>>(x, n1s, hF, hB);
  k_gather<<<M_, 256, 0, stream>>>(action, embed, aeF, aeB);

  k_gemm2<1><<<dim3(1536 / 64, M_ / 64), 256, 0, stream>>>(hB, wqkvT, qkvF, M_, 1536, 512, 1024, nullptr, nullptr);
  k_gemm2<0><<<dim3(1024 / 64, M_ / 64), 256, 0, stream>>>(aeB, wbuvT, buvF, M_, 1024, 512, 0, nullptr, nullptr);
  k_dot8x2<<<M_, 256, 0, stream>>>(hF, aeF, wbeta, walpha, betaF, alphaF);
  k_qknorm_dots<<<M_ * 2, 256, 0, stream>>>(qkvF, buvF, betaF, alphaF, mask, scal8);

  k_scan_chunk<<<16 * CHUNKS_, 256, 0, stream>>>(qkvF, buvF, scal8, PtHi, PtLo, UtB);
  k_chain2<<<16, 256, 0, stream>>>(PtHi, PtLo, UtB, carry, Hbuf, out_hs);
  k_apply_chunk<<<16 * CHUNKS_, 256, 0, stream>>>(qkvF, buvF, scal8, Hbuf, attnF);

  k_rmsnorm<<<M_, 256, 0, stream>>>(attnF, nas, nullptr, attnB);
  k_gemm2<2><<<dim3(512 / 64, M_ / 64), 256, 0, stream>>>(attnB, woutT, skipF, M_, 512, 512, 0, bout, x);
  k_rmsnorm<<<M_, 256, 0, stream>>>(skipF, n2s, nullptr, h2B);
  k_gemm2<4><<<dim3(4096 / 64, M_ / 64), 256, 0, stream>>>(h2B, wgvT, ffnB, M_, 4096, 512, 0, nullptr, nullptr);
  k_gemm2<3><<<dim3(512 / 64, M_ / 64), 256, 0, stream>>>(ffnB, wffnT, out_ffn, M_, 512, 2048, 0, nullptr, skipF);
}

// Round 5
// 227.559 us; speedup vs baseline: 7.2661x; 1.0801x over previous
//
#include <hip/hip_runtime.h>
#include <hip/hip_bf16.h>
#include <cstdint>
#include <cstddef>

using bf16 = __hip_bfloat16;
typedef __attribute__((ext_vector_type(8))) short bf16x8;  // 8 bf16 (4 VGPRs)
typedef __attribute__((ext_vector_type(4))) float f32x4;

static constexpr int B_ = 2, S_ = 1024, D_ = 512, H_ = 8;
static constexpr int M_ = B_ * S_;     // 2048 rows
static constexpr int CHUNKS_ = 32, CLEN_ = 32;  // S = CHUNKS * CLEN
static constexpr float EPS_ = 1e-6f;

__device__ __forceinline__ float sigmoidf_(float x) { return 1.0f / (1.0f + __expf(-x)); }

__device__ __forceinline__ short bf_hi(float v, float& rem) {
  bf16 h = __float2bfloat16(v);
  rem = v - __bfloat162float(h);
  return *(short*)&h;
}
__device__ __forceinline__ short bf_of(float v) {
  bf16 h = __float2bfloat16(v);
  return *(short*)&h;
}

// -------- fused transpose + cast: W [K][N] f32 -> Wt [dstRow(n)][K] bf16 --------
// xf: 0 linear; 1 gate-interleave (row = (n>>5)*64 + (n&31)); 2 val (+32)
struct TJob { const float* src; bf16* dst; int K, N, base, xf; };
struct TTab { TJob j[9]; };

__global__ __launch_bounds__(256) void k_transpose_all(TTab tab) {
  __shared__ float tile[32][33];
  int blk = blockIdx.x;
  int ji = 0;
#pragma unroll
  for (int t = 1; t < 9; ++t) if (tab.j[t].base <= blk) ji = t;
  const float* W = tab.j[ji].src;
  bf16* Wt = tab.j[ji].dst;
  int K = tab.j[ji].K, N = tab.j[ji].N, xf = tab.j[ji].xf;
  int rel = blk - tab.j[ji].base;
  int nb = N >> 5;
  int n0 = (rel % nb) * 32, k0 = (rel / nb) * 32;
  int tx = threadIdx.x, ty = threadIdx.y;  // 32 x 8
#pragma unroll
  for (int r = ty; r < 32; r += 8) tile[r][tx] = W[(size_t)(k0 + r) * N + n0 + tx];
  __syncthreads();
#pragma unroll
  for (int r = ty; r < 32; r += 8) {
    int n = n0 + r;
    int drow = n;
    if (xf == 1) drow = ((n >> 5) << 6) + (n & 31);
    else if (xf == 2) drow = ((n >> 5) << 6) + (n & 31) + 32;
    Wt[(size_t)drow * K + k0 + tx] = __float2bfloat16(tile[tx][r]);
  }
}

// ---------------- rmsnorm over D=512, optional f32 + bf16 outputs ----------------
__global__ __launch_bounds__(256) void k_rmsnorm(const float* __restrict__ x,
                                                 const float* __restrict__ scale,
                                                 float* __restrict__ outf,
                                                 bf16* __restrict__ outb) {
  int m = blockIdx.x, tid = threadIdx.x;
  const float* row = x + (size_t)m * D_;
  float2 v = *(const float2*)(row + tid * 2);
  float ss = v.x * v.x + v.y * v.y;
#pragma unroll
  for (int o = 1; o < 64; o <<= 1) ss += __shfl_xor(ss, o);
  __shared__ float wsum[4];
  if ((tid & 63) == 0) wsum[tid >> 6] = ss;
  __syncthreads();
  float tot = wsum[0] + wsum[1] + wsum[2] + wsum[3];
  float rs = rsqrtf(tot * (1.0f / (float)D_) + EPS_);
  float2 sc = *(const float2*)(scale + tid * 2);
  float o0 = v.x * rs * sc.x, o1 = v.y * rs * sc.y;
  if (outf) {
    float2 o; o.x = o0; o.y = o1;
    *(float2*)(outf + (size_t)m * D_ + tid * 2) = o;
  }
  if (outb) {
    bf16* p = outb + (size_t)m * D_ + tid * 2;
    p[0] = __float2bfloat16(o0); p[1] = __float2bfloat16(o1);
  }
}

// ---------------- action-embedding gather ----------------
__global__ __launch_bounds__(256) void k_gather(const int* __restrict__ action,
                                                const float* __restrict__ embed,
                                                float* __restrict__ aef, bf16* __restrict__ aeb) {
  int m = blockIdx.x, tid = threadIdx.x;
  int a = action[m];
  float2 v = *(const float2*)(embed + (size_t)a * 512 + tid * 2);
  *(float2*)(aef + (size_t)m * 512 + tid * 2) = v;
  bf16* p = aeb + (size_t)m * 512 + tid * 2;
  p[0] = __float2bfloat16(v.x); p[1] = __float2bfloat16(v.y);
}

// ---- beta = sigmoid(hF@wbeta), alpha = sigmoid(aeF@walpha) in one dispatch ----
__global__ __launch_bounds__(256) void k_dot8x2(const float* __restrict__ hF,
                                                const float* __restrict__ aeF,
                                                const float* __restrict__ W1,
                                                const float* __restrict__ W2,
                                                float* __restrict__ o1,
                                                float* __restrict__ o2) {
  int m = blockIdx.x, tid = threadIdx.x;
  float x0 = hF[(size_t)m * D_ + tid], x1 = hF[(size_t)m * D_ + 256 + tid];
  float y0 = aeF[(size_t)m * D_ + tid], y1 = aeF[(size_t)m * D_ + 256 + tid];
  float p[8], q[8];
#pragma unroll
  for (int j = 0; j < 8; ++j) {
    p[j] = x0 * W1[tid * 8 + j] + x1 * W1[(tid + 256) * 8 + j];
    q[j] = y0 * W2[tid * 8 + j] + y1 * W2[(tid + 256) * 8 + j];
  }
#pragma unroll
  for (int j = 0; j < 8; ++j) {
#pragma unroll
    for (int o = 1; o < 64; o <<= 1) {
      p[j] += __shfl_xor(p[j], o);
      q[j] += __shfl_xor(q[j], o);
    }
  }
  __shared__ float sacc[4][16];
  if ((tid & 63) == 0) {
#pragma unroll
    for (int j = 0; j < 8; ++j) { sacc[tid >> 6][j] = p[j]; sacc[tid >> 6][8 + j] = q[j]; }
  }
  __syncthreads();
  if (tid < 8) {
    float s = sacc[0][tid] + sacc[1][tid] + sacc[2][tid] + sacc[3][tid];
    o1[(size_t)m * 8 + tid] = sigmoidf_(s);
  } else if (tid < 16) {
    int j = tid - 8;
    float s = sacc[0][8 + j] + sacc[1][8 + j] + sacc[2][8 + j] + sacc[3][8 + j];
    o2[(size_t)m * 8 + j] = sigmoidf_(s);
  }
}

// ---- per (m,h): L2-normalize q,k in place; pack scal8 = {beta, g, kq, kbv, bvq} ----
__global__ __launch_bounds__(256) void k_qknorm_dots(float* __restrict__ qkv,
                                                     const float* __restrict__ buv,
                                                     const float* __restrict__ betaF,
                                                     const float* __restrict__ alphaF,
                                                     const int* __restrict__ mask,
                                                     float* __restrict__ scal8) {
  int blk = blockIdx.x * 4 + (threadIdx.x >> 6);
  int m = blk >> 3, h = blk & 7, t = threadIdx.x & 63;
  size_t qi = (size_t)m * 1536 + h * 64 + t;
  float q = qkv[qi], k = qkv[qi + 512];
  float bv = buv[(size_t)m * 1024 + 512 + h * 64 + t];
  float qs = q * q, ks = k * k;
#pragma unroll
  for (int o = 1; o < 64; o <<= 1) { qs += __shfl_xor(qs, o); ks += __shfl_xor(ks, o); }
  float qn = q / (sqrtf(qs) + EPS_);
  float kn = k / (sqrtf(ks) + EPS_);
  qkv[qi] = qn; qkv[qi + 512] = kn;
  float d0 = kn * qn, d1 = kn * bv, d2 = bv * qn;
#pragma unroll
  for (int o = 1; o < 64; o <<= 1) {
    d0 += __shfl_xor(d0, o); d1 += __shfl_xor(d1, o); d2 += __shfl_xor(d2, o);
  }
  if (t == 0) {
    int mh = m * 8 + h;
    float4 s4;
    s4.x = betaF[mh];
    s4.y = alphaF[mh] * (1.0f - (float)mask[m]);
    s4.z = d0; s4.w = d1;
    *(float4*)(scal8 + (size_t)mh * 8) = s4;
    scal8[(size_t)mh * 8 + 4] = d2;
  }
}

// ======== pipelined bf16 MFMA GEMM: C = epi(A[M,K] @ Bt[N,K]^T), 64x64 tile ========
template <int EPI>
__global__ __launch_bounds__(256) void k_gemm2(const bf16* __restrict__ A,
                                               const bf16* __restrict__ Bt,
                                               void* __restrict__ Cv, int M, int N, int K,
                                               int actSplit, const float* __restrict__ bias,
                                               const float* __restrict__ res) {
  __shared__ bf16 As[2][64 * 32];
  __shared__ bf16 Bs[2][64 * 32];
  const int tid = threadIdx.x;
  const int wave = tid >> 6, lane = tid & 63;
  const int wm = wave >> 1, wn = wave & 1;
  const int m0 = blockIdx.y * 64, n0 = blockIdx.x * 64;
  const int lr = lane & 15, lg = lane >> 4;
  const int srow = (wave << 4) | (lane >> 2);
  const int skb = (lane & 3) << 3;
  const bf16* ga = A + (size_t)(m0 + srow) * K + skb;
  const bf16* gb = Bt + (size_t)(n0 + srow) * K + skb;

  f32x4 acc[2][2];
#pragma unroll
  for (int i = 0; i < 2; ++i)
#pragma unroll
    for (int j = 0; j < 2; ++j) acc[i][j] = (f32x4){0.f, 0.f, 0.f, 0.f};

  const int nk = K >> 5;
  int4 ar = *(const int4*)ga;
  int4 br = *(const int4*)gb;
  for (int t = 0; t < nk; ++t) {
    bf16* asb = &As[t & 1][0];
    bf16* bsb = &Bs[t & 1][0];
    *(int4*)(asb + tid * 8) = ar;
    *(int4*)(bsb + tid * 8) = br;
    __syncthreads();
    if (t + 1 < nk) {
      ar = *(const int4*)(ga + ((size_t)(t + 1) << 5));
      br = *(const int4*)(gb + ((size_t)(t + 1) << 5));
    }
    bf16x8 af[2], bfr[2];
#pragma unroll
    for (int mm = 0; mm < 2; ++mm)
      af[mm] = *(const bf16x8*)(asb + (wm * 32 + mm * 16 + lr) * 32 + lg * 8);
#pragma unroll
    for (int nn = 0; nn < 2; ++nn)
      bfr[nn] = *(const bf16x8*)(bsb + (wn * 32 + nn * 16 + lr) * 32 + lg * 8);
#pragma unroll
    for (int mm = 0; mm < 2; ++mm)
#pragma unroll
      for (int nn = 0; nn < 2; ++nn)
        acc[mm][nn] = __builtin_amdgcn_mfma_f32_16x16x32_bf16(af[mm], bfr[nn], acc[mm][nn], 0, 0, 0);
  }

  if constexpr (EPI == 4) {
    __syncthreads();
    float* gateL = (float*)&As[0][0];
    float* valL = (float*)&Bs[0][0];
    float* dstL = wn ? valL : gateL;
#pragma unroll
    for (int mm = 0; mm < 2; ++mm)
#pragma unroll
      for (int nn = 0; nn < 2; ++nn)
#pragma unroll
        for (int r = 0; r < 4; ++r)
          dstL[(wm * 32 + mm * 16 + lg * 4 + r) * 32 + nn * 16 + lr] = acc[mm][nn][r];
    __syncthreads();
    bf16* Cb = (bf16*)Cv;
    int row = tid >> 2, c0 = (tid & 3) * 8;
    bf16x8 o;
#pragma unroll
    for (int e = 0; e < 8; ++e) {
      float g = gateL[row * 32 + c0 + e];
      float v = valL[row * 32 + c0 + e];
      o[e] = bf_of(g * sigmoidf_(g) * v);
    }
    *(int4*)(Cb + (size_t)(m0 + row) * 2048 + blockIdx.x * 32 + c0) = *(int4*)&o;
  } else {
    float* C = (float*)Cv;
#pragma unroll
    for (int mm = 0; mm < 2; ++mm) {
#pragma unroll
      for (int nn = 0; nn < 2; ++nn) {
#pragma unroll
        for (int r = 0; r < 4; ++r) {
          int row = m0 + wm * 32 + mm * 16 + lg * 4 + r;
          int col = n0 + wn * 32 + nn * 16 + lr;
          float v = acc[mm][nn][r];
          if constexpr (EPI == 1) {
            if (col < actSplit) v = v * sigmoidf_(v);
          }
          if constexpr (EPI == 2) v += bias[col] + res[(size_t)row * N + col];
          if constexpr (EPI == 3) v += res[(size_t)row * N + col];
          C[(size_t)row * N + col] = v;
        }
      }
    }
  }
}

// ================= chunked recurrence =================
struct alignas(16) StepC {
  float k[16], bv[16], q[16];
  float v_i, bu_i, beta, g, kq, kbv, bvq;
};

__device__ __forceinline__ void load_stepc(StepC& sd,
    const float* __restrict__ qkv, const float* __restrict__ buv,
    const float* __restrict__ scal8, int m, int h, int i, int j0, bool withq) {
  const float* qb = qkv + (size_t)m * 1536 + h * 64;
  const float* bb = buv + (size_t)m * 1024 + h * 64;
#pragma unroll
  for (int p = 0; p < 4; ++p) *(float4*)&sd.k[p * 4] = *(const float4*)(qb + 512 + j0 + p * 4);
#pragma unroll
  for (int p = 0; p < 4; ++p) *(float4*)&sd.bv[p * 4] = *(const float4*)(bb + 512 + j0 + p * 4);
  if (withq) {
#pragma unroll
    for (int p = 0; p < 4; ++p) *(float4*)&sd.q[p * 4] = *(const float4*)(qb + j0 + p * 4);
  }
  sd.v_i = qb[1024 + i];
  sd.bu_i = bb[i];
  const float* sp = scal8 + (size_t)(m * 8 + h) * 8;
  float4 s4 = *(const float4*)sp;
  sd.beta = s4.x; sd.g = s4.y; sd.kq = s4.z; sd.kbv = s4.w;
  if (withq) sd.bvq = sp[4];
}

__device__ __forceinline__ void step_fold(float P[16], float U[16], const StepC& sd) {
  float Pk = 0.f, Uk = 0.f;
#pragma unroll
  for (int jj = 0; jj < 16; ++jj) { Pk += P[jj] * sd.k[jj]; Uk += U[jj] * sd.k[jj]; }
  Pk += __shfl_xor(Pk, 1); Pk += __shfl_xor(Pk, 2);
  Uk += __shfl_xor(Uk, 1); Uk += __shfl_xor(Uk, 2);
  float gb = sd.g * sd.beta;
  float cP = gb * Pk;
  float Ai = sd.beta * sd.v_i - gb * Uk - sd.bu_i * sd.beta * sd.kbv;
#pragma unroll
  for (int jj = 0; jj < 16; ++jj) {
    P[jj] = sd.g * P[jj] - cP * sd.k[jj];
    U[jj] = sd.g * U[jj] + Ai * sd.k[jj] + sd.bu_i * sd.bv[jj];
  }
}

__device__ __forceinline__ void step_apply(float hs[16], const StepC& sd,
                                           float* __restrict__ attn_addr, bool writer) {
  float u = 0.f, w = 0.f;
#pragma unroll
  for (int jj = 0; jj < 16; ++jj) { u += hs[jj] * sd.k[jj]; w += hs[jj] * sd.q[jj]; }
  u += __shfl_xor(u, 1); u += __shfl_xor(u, 2);
  w += __shfl_xor(w, 1); w += __shfl_xor(w, 2);
  float a_i = sd.beta * sd.v_i - sd.g * sd.beta * u;
  float c = sd.beta * sd.kbv;
#pragma unroll
  for (int jj = 0; jj < 16; ++jj) {
    float bvp = sd.bv[jj] - c * sd.k[jj];
    hs[jj] = sd.g * hs[jj] + a_i * sd.k[jj] + sd.bu_i * bvp;
  }
  if (writer) *attn_addr = sd.g * w + a_i * sd.kq + sd.bu_i * (sd.bvq - c * sd.kq);
}

// ---- phase 1: per-chunk transition, emitted as P^T (bf16 hi/lo) + U^T (f32) ----
__global__ __launch_bounds__(256) void k_scan_chunk(
    const float* __restrict__ qkv, const float* __restrict__ buv,
    const float* __restrict__ scal8, bf16* __restrict__ PtHi,
    bf16* __restrict__ PtLo, float* __restrict__ Ut) {
  int blk = blockIdx.x, bh = blk >> 5, c = blk & (CHUNKS_ - 1);
  int b = bh >> 3, h = bh & 7;
  int tid = threadIdx.x, i = tid >> 2, q4 = tid & 3, j0 = q4 * 16;
  alignas(16) float P[16], U[16];
#pragma unroll
  for (int jj = 0; jj < 16; ++jj) { P[jj] = (j0 + jj == i) ? 1.f : 0.f; U[jj] = 0.f; }
  int m0 = b * S_ + c * CLEN_;
  StepC A, Bs;
  load_stepc(A, qkv, buv, scal8, m0, h, i, j0, false);
  load_stepc(Bs, qkv, buv, scal8, m0 + 1, h, i, j0, false);
  for (int s = 0; s < CLEN_; s += 2) {
    step_fold(P, U, A);
    if (s + 2 < CLEN_) load_stepc(A, qkv, buv, scal8, m0 + s + 2, h, i, j0, false);
    step_fold(P, U, Bs);
    if (s + 3 < CLEN_) load_stepc(Bs, qkv, buv, scal8, m0 + s + 3, h, i, j0, false);
  }
  const size_t base = ((size_t)bh * CHUNKS_ + c) * 4096;
#pragma unroll
  for (int jj = 0; jj < 16; ++jj) {
    int j = j0 + jj;
    float pv = P[jj];
    float rem;
    short ph = bf_hi(pv, rem);
    short pl = bf_of(rem);
    ((short*)PtHi)[base + (size_t)j * 64 + i] = ph;
    ((short*)PtLo)[base + (size_t)j * 64 + i] = pl;
    Ut[base + (size_t)j * 64 + i] = U[jj];
  }
}

// ---- phase 2: barrier-free register-resident MFMA chain ----
// One WAVE per (bh, 16-column strip of hs^T). State lives in D-fragments:
// st[mt][r] = hs^T[16mt+4lg+r][col0+lr]. Next B-frag rebuilt via lane shuffles.
#define PREFETCH_(SET, CIDX)                                                     \
  {                                                                              \
    const size_t cbo_ = (size_t)(CIDX) * 4096;                                   \
    _Pragma("unroll") for (int mt = 0; mt < 4; ++mt) {                           \
      _Pragma("unroll") for (int ks = 0; ks < 2; ++ks) {                         \
        size_t off_ = cbo_ + (size_t)(16 * mt + lr) * 64 + ks * 32 + lg * 8;     \
        aH[SET][mt][ks] = *(const bf16x8*)(PH + off_);                           \
        aL[SET][mt][ks] = *(const bf16x8*)(PL + off_);                           \
      }                                                                          \
      _Pragma("unroll") for (int r = 0; r < 4; ++r)                              \
        u[SET][mt][r] = UB[cbo_ + (size_t)(16 * mt + 4 * lg + r) * 64 + col0 + lr]; \
    }                                                                            \
  }

#define CHAINSTEP_(SET, NSET, CIDX)                                              \
  {                                                                              \
    if ((CIDX) + 1 < CHUNKS_) PREFETCH_(NSET, (CIDX) + 1);                       \
    _Pragma("unroll") for (int mt = 0; mt < 4; ++mt)                             \
      _Pragma("unroll") for (int r = 0; r < 4; ++r)                              \
        HB[(size_t)(CIDX) * 4096 + (size_t)(16 * mt + 4 * lg + r) * 64 + col0 + lr] = st[mt][r]; \
    bf16x8 bH[2], bL[2];                                                         \
    _Pragma("unroll") for (int ks = 0; ks < 2; ++ks) {                           \
      _Pragma("unroll") for (int e = 0; e < 8; ++e) {                            \
        int src_ = (2 * (lg & 1) + (e >> 2)) * 16 + lr;                          \
        float va_ = __shfl(st[2 * ks][e & 3], src_);                             \
        float vb_ = __shfl(st[2 * ks + 1][e & 3], src_);                         \
        float bv_ = (lg & 2) ? vb_ : va_;                                        \
        float rem_;                                                              \
        bH[ks][e] = bf_hi(bv_, rem_);                                            \
        bL[ks][e] = bf_of(rem_);                                                 \
      }                                                                          \
    }                                                                            \
    f32x4 stn[4];                                                                \
    _Pragma("unroll") for (int mt = 0; mt < 4; ++mt) {                           \
      f32x4 a_ = u[SET][mt];                                                     \
      _Pragma("unroll") for (int ks = 0; ks < 2; ++ks) {                         \
        a_ = __builtin_amdgcn_mfma_f32_16x16x32_bf16(aH[SET][mt][ks], bH[ks], a_, 0, 0, 0); \
        a_ = __builtin_amdgcn_mfma_f32_16x16x32_bf16(aH[SET][mt][ks], bL[ks], a_, 0, 0, 0); \
        a_ = __builtin_amdgcn_mfma_f32_16x16x32_bf16(aL[SET][mt][ks], bH[ks], a_, 0, 0, 0); \
      }                                                                          \
      stn[mt] = a_;                                                              \
    }                                                                            \
    _Pragma("unroll") for (int mt = 0; mt < 4; ++mt) st[mt] = stn[mt];           \
  }

__global__ __launch_bounds__(64, 1) void k_chain3(
    const bf16* __restrict__ PtHi, const bf16* __restrict__ PtLo,
    const float* __restrict__ Ut, const float* __restrict__ carry,
    float* __restrict__ Hbuf, float* __restrict__ out_hs) {
  const int bh = blockIdx.x >> 2, cb = blockIdx.x & 3, col0 = cb * 16;
  const int lane = threadIdx.x & 63, lr = lane & 15, lg = lane >> 4;
  const short* PH = (const short*)PtHi + (size_t)bh * CHUNKS_ * 4096;
  const short* PL = (const short*)PtLo + (size_t)bh * CHUNKS_ * 4096;
  const float* UB = Ut + (size_t)bh * CHUNKS_ * 4096;
  float* HB = Hbuf + (size_t)bh * CHUNKS_ * 4096;

  f32x4 st[4];
#pragma unroll
  for (int mt = 0; mt < 4; ++mt)
    st[mt] = *(const f32x4*)(carry + ((size_t)bh * 64 + col0 + lr) * 64 + 16 * mt + 4 * lg);

  bf16x8 aH[2][4][2], aL[2][4][2];
  f32x4 u[2][4];
  PREFETCH_(0, 0);
  for (int c = 0; c < CHUNKS_; c += 2) {
    CHAINSTEP_(0, 1, c);
    CHAINSTEP_(1, 0, c + 1);
  }
#pragma unroll
  for (int mt = 0; mt < 4; ++mt)
    *(f32x4*)(out_hs + ((size_t)bh * 64 + col0 + lr) * 64 + 16 * mt + 4 * lg) = st[mt];
}

// ---- phase 3: re-run each chunk from hstart_c (stored as hs^T), emit attn ----
__global__ __launch_bounds__(256) void k_apply_chunk(
    const float* __restrict__ qkv, const float* __restrict__ buv,
    const float* __restrict__ scal8, const float* __restrict__ Hbuf,
    float* __restrict__ attn) {
  int blk = blockIdx.x, bh = blk >> 5, c = blk & (CHUNKS_ - 1);
  int b = bh >> 3, h = bh & 7;
  int tid = threadIdx.x, i = tid >> 2, q4 = tid & 3, j0 = q4 * 16;
  bool writer = (q4 == 0);
  alignas(16) float hs[16];
  const float* hb = Hbuf + ((size_t)bh * CHUNKS_ + c) * 4096;
#pragma unroll
  for (int jj = 0; jj < 16; ++jj) hs[jj] = hb[(size_t)(j0 + jj) * 64 + i];  // hs^T[j][i]
  int m0 = b * S_ + c * CLEN_;
  StepC A, Bs;
  load_stepc(A, qkv, buv, scal8, m0, h, i, j0, true);
  load_stepc(Bs, qkv, buv, scal8, m0 + 1, h, i, j0, true);
  for (int s = 0; s < CLEN_; s += 2) {
    step_apply(hs, A, attn + ((size_t)(m0 + s) * 512 + h * 64 + i), writer);
    if (s + 2 < CLEN_) load_stepc(A, qkv, buv, scal8, m0 + s + 2, h, i, j0, true);
    step_apply(hs, Bs, attn + ((size_t)(m0 + s + 1) * 512 + h * 64 + i), writer);
    if (s + 3 < CLEN_) load_stepc(Bs, qkv, buv, scal8, m0 + s + 3, h, i, j0, true);
  }
}

// ---------------- host ----------------
extern "C" void kernel_launch(void* const* d_in, const int* in_sizes, int n_in,
                              void* d_out, int out_size, void* d_ws, size_t ws_size,
                              hipStream_t stream) {
  const float* x      = (const float*)d_in[0];
  const int*   action = (const int*)d_in[1];
  const int*   mask   = (const int*)d_in[2];
  const float* carry  = (const float*)d_in[3];
  const float* n1s    = (const float*)d_in[4];
  const float* wq     = (const float*)d_in[5];
  const float* wk     = (const float*)d_in[6];
  const float* wv     = (const float*)d_in[7];
  const float* wbeta  = (const float*)d_in[8];
  const float* embed  = (const float*)d_in[9];
  const float* walpha = (const float*)d_in[10];
  const float* wbu    = (const float*)d_in[11];
  const float* wbv    = (const float*)d_in[12];
  const float* nas    = (const float*)d_in[13];
  const float* wout   = (const float*)d_in[14];
  const float* bout   = (const float*)d_in[15];
  const float* n2s    = (const float*)d_in[16];
  const float* wgate  = (const float*)d_in[17];
  const float* wval   = (const float*)d_in[18];
  const float* wffn   = (const float*)d_in[19];

  float* out_hs  = (float*)d_out;            // [2,8,64,64]
  float* out_ffn = (float*)d_out + 65536;    // [2,1024,512]

  char* p = (char*)d_ws;
  auto alloc = [&](size_t bytes) -> char* {
    char* r = p; p += (bytes + 255) & ~(size_t)255; return r;
  };
  bf16*  wqkvT = (bf16*)alloc((size_t)1536 * 512 * 2);
  bf16*  wbuvT = (bf16*)alloc((size_t)1024 * 512 * 2);
  bf16*  woutT = (bf16*)alloc((size_t)512 * 512 * 2);
  bf16*  wgvT  = (bf16*)alloc((size_t)4096 * 512 * 2);   // gate/val row-interleaved
  bf16*  wffnT = (bf16*)alloc((size_t)512 * 2048 * 2);
  float* hF    = (float*)alloc((size_t)M_ * 512 * 4);
  bf16*  hB    = (bf16*)alloc((size_t)M_ * 512 * 2);
  float* aeF   = (float*)alloc((size_t)M_ * 512 * 4);
  bf16*  aeB   = (bf16*)alloc((size_t)M_ * 512 * 2);
  float* qkvF  = (float*)alloc((size_t)M_ * 1536 * 4);
  float* buvF  = (float*)alloc((size_t)M_ * 1024 * 4);
  float* betaF = (float*)alloc((size_t)M_ * 8 * 4);
  float* alphaF= (float*)alloc((size_t)M_ * 8 * 4);
  float* scal8 = (float*)alloc((size_t)M_ * 8 * 8 * 4);
  float* attnF = (float*)alloc((size_t)M_ * 512 * 4);
  bf16*  attnB = (bf16*)alloc((size_t)M_ * 512 * 2);
  float* skipF = (float*)alloc((size_t)M_ * 512 * 4);
  bf16*  h2B   = (bf16*)alloc((size_t)M_ * 512 * 2);
  bf16*  ffnB  = (bf16*)alloc((size_t)M_ * 2048 * 2);
  char*  chunkWS = alloc((size_t)24 * 1024 * 1024);      // Pt/Ut/H chunk buffers
  if ((size_t)(p - (char*)d_ws) > ws_size) return;  // workspace too small

  constexpr size_t CELEMS = (size_t)16 * CHUNKS_ * 4096;
  bf16*  PtHi = (bf16*)(chunkWS);
  bf16*  PtLo = (bf16*)(chunkWS + CELEMS * 2);
  float* UtB  = (float*)(chunkWS + CELEMS * 4);
  float* Hbuf = (float*)(chunkWS + CELEMS * 8);

  TTab tab;
  tab.j[0] = {wq,    wqkvT,              512,  512,  0,    0};
  tab.j[1] = {wk,    wqkvT + 512 * 512,  512,  512,  256,  0};
  tab.j[2] = {wv,    wqkvT + 1024 * 512, 512,  512,  512,  0};
  tab.j[3] = {wbu,   wbuvT,              512,  512,  768,  0};
  tab.j[4] = {wbv,   wbuvT + 512 * 512,  512,  512,  1024, 0};
  tab.j[5] = {wout,  woutT,              512,  512,  1280, 0};
  tab.j[6] = {wgate, wgvT,               512,  2048, 1536, 1};
  tab.j[7] = {wval,  wgvT,               512,  2048, 2560, 2};
  tab.j[8] = {wffn,  wffnT,              2048, 512,  3584, 0};
  k_transpose_all<<<4608, dim3(32, 8), 0, stream>>>(tab);

  k_rmsnorm<<<M_, 256, 0, stream>>>(x, n1s, hF, hB);
  k_gather<<<M_, 256, 0, stream>>>(action, embed, aeF, aeB);

  k_gemm2<1><<<dim3(1536 / 64, M_ / 64), 256, 0, stream>>>(hB, wqkvT, qkvF, M_, 1536, 512, 1024, nullptr, nullptr);
  k_gemm2<0><<<dim3(1024 / 64, M_ / 64), 256, 0, stream>>>(aeB, wbuvT, buvF, M_, 1024, 512, 0, nullptr, nullptr);
  k_dot8x2<<<M_, 256, 0, stream>>>(hF, aeF, wbeta, walpha, betaF, alphaF);
  k_qknorm_dots<<<M_ * 2, 256, 0, stream>>>(qkvF, buvF, betaF, alphaF, mask, scal8);

  k_scan_chunk<<<16 * CHUNKS_, 256, 0, stream>>>(qkvF, buvF, scal8, PtHi, PtLo, UtB);
  k_chain3<<<64, 64, 0, stream>>>(PtHi, PtLo, UtB, carry, Hbuf, out_hs);
  k_apply_chunk<<<16 * CHUNKS_, 256, 0, stream>>>(qkvF, buvF, scal8, Hbuf, attnF);

  k_rmsnorm<<<M_, 256, 0, stream>>>(attnF, nas, nullptr, attnB);
  k_gemm2<2><<<dim3(512 / 64, M_ / 64), 256, 0, stream>>>(attnB, woutT, skipF, M_, 512, 512, 0, bout, x);
  k_rmsnorm<<<M_, 256, 0, stream>>>(skipF, n2s, nullptr, h2B);
  k_gemm2<4><<<dim3(4096 / 64, M_ / 64), 256, 0, stream>>>(h2B, wgvT, ffnB, M_, 4096, 512, 0, nullptr, nullptr);
  k_gemm2<3><<<dim3(512 / 64, M_ / 64), 256, 0, stream>>>(ffnB, wffnT, out_ffn, M_, 512, 2048, 0, nullptr, skipF);
}

// Round 6
// 201.205 us; speedup vs baseline: 8.2178x; 1.1310x over previous
//
#include <hip/hip_runtime.h>
#include <hip/hip_bf16.h>
#include <cstdint>
#include <cstddef>

using bf16 = __hip_bfloat16;
typedef __attribute__((ext_vector_type(8))) short bf16x8;  // 8 bf16 (4 VGPRs)
typedef __attribute__((ext_vector_type(4))) float f32x4;

static constexpr int B_ = 2, S_ = 1024, D_ = 512, H_ = 8;
static constexpr int M_ = B_ * S_;     // 2048 rows
static constexpr int CHUNKS_ = 32, CLEN_ = 32;  // S = CHUNKS * CLEN
static constexpr float EPS_ = 1e-6f;

__device__ __forceinline__ float sigmoidf_(float x) { return 1.0f / (1.0f + __expf(-x)); }

__device__ __forceinline__ short bf_hi(float v, float& rem) {
  bf16 h = __float2bfloat16(v);
  rem = v - __bfloat162float(h);
  return *(short*)&h;
}
__device__ __forceinline__ short bf_of(float v) {
  bf16 h = __float2bfloat16(v);
  return *(short*)&h;
}

// -------- fused transpose + cast: W [K][N] f32 -> Wt [dstRow(n)][K] bf16 --------
// xf: 0 linear; 1 gate-interleave (row = (n>>5)*64 + (n&31)); 2 val (+32)
struct TJob { const float* src; bf16* dst; int K, N, base, xf; };
struct TTab { TJob j[9]; };

__global__ __launch_bounds__(256) void k_transpose_all(TTab tab) {
  __shared__ float tile[32][33];
  int blk = blockIdx.x;
  int ji = 0;
#pragma unroll
  for (int t = 1; t < 9; ++t) if (tab.j[t].base <= blk) ji = t;
  const float* W = tab.j[ji].src;
  bf16* Wt = tab.j[ji].dst;
  int K = tab.j[ji].K, N = tab.j[ji].N, xf = tab.j[ji].xf;
  int rel = blk - tab.j[ji].base;
  int nb = N >> 5;
  int n0 = (rel % nb) * 32, k0 = (rel / nb) * 32;
  int tx = threadIdx.x, ty = threadIdx.y;  // 32 x 8
#pragma unroll
  for (int r = ty; r < 32; r += 8) tile[r][tx] = W[(size_t)(k0 + r) * N + n0 + tx];
  __syncthreads();
#pragma unroll
  for (int r = ty; r < 32; r += 8) {
    int n = n0 + r;
    int drow = n;
    if (xf == 1) drow = ((n >> 5) << 6) + (n & 31);
    else if (xf == 2) drow = ((n >> 5) << 6) + (n & 31) + 32;
    Wt[(size_t)drow * K + k0 + tx] = __float2bfloat16(tile[tx][r]);
  }
}

// ---------------- rmsnorm over D=512, optional f32 + bf16 outputs ----------------
__global__ __launch_bounds__(256) void k_rmsnorm(const float* __restrict__ x,
                                                 const float* __restrict__ scale,
                                                 float* __restrict__ outf,
                                                 bf16* __restrict__ outb) {
  int m = blockIdx.x, tid = threadIdx.x;
  const float* row = x + (size_t)m * D_;
  float2 v = *(const float2*)(row + tid * 2);
  float ss = v.x * v.x + v.y * v.y;
#pragma unroll
  for (int o = 1; o < 64; o <<= 1) ss += __shfl_xor(ss, o);
  __shared__ float wsum[4];
  if ((tid & 63) == 0) wsum[tid >> 6] = ss;
  __syncthreads();
  float tot = wsum[0] + wsum[1] + wsum[2] + wsum[3];
  float rs = rsqrtf(tot * (1.0f / (float)D_) + EPS_);
  float2 sc = *(const float2*)(scale + tid * 2);
  float o0 = v.x * rs * sc.x, o1 = v.y * rs * sc.y;
  if (outf) {
    float2 o; o.x = o0; o.y = o1;
    *(float2*)(outf + (size_t)m * D_ + tid * 2) = o;
  }
  if (outb) {
    bf16* p = outb + (size_t)m * D_ + tid * 2;
    p[0] = __float2bfloat16(o0); p[1] = __float2bfloat16(o1);
  }
}

// ---------------- action-embedding gather ----------------
__global__ __launch_bounds__(256) void k_gather(const int* __restrict__ action,
                                                const float* __restrict__ embed,
                                                float* __restrict__ aef, bf16* __restrict__ aeb) {
  int m = blockIdx.x, tid = threadIdx.x;
  int a = action[m];
  float2 v = *(const float2*)(embed + (size_t)a * 512 + tid * 2);
  *(float2*)(aef + (size_t)m * 512 + tid * 2) = v;
  bf16* p = aeb + (size_t)m * 512 + tid * 2;
  p[0] = __float2bfloat16(v.x); p[1] = __float2bfloat16(v.y);
}

// ---- beta = sigmoid(hF@wbeta), alpha = sigmoid(aeF@walpha) in one dispatch ----
__global__ __launch_bounds__(256) void k_dot8x2(const float* __restrict__ hF,
                                                const float* __restrict__ aeF,
                                                const float* __restrict__ W1,
                                                const float* __restrict__ W2,
                                                float* __restrict__ o1,
                                                float* __restrict__ o2) {
  int m = blockIdx.x, tid = threadIdx.x;
  float x0 = hF[(size_t)m * D_ + tid], x1 = hF[(size_t)m * D_ + 256 + tid];
  float y0 = aeF[(size_t)m * D_ + tid], y1 = aeF[(size_t)m * D_ + 256 + tid];
  float p[8], q[8];
#pragma unroll
  for (int j = 0; j < 8; ++j) {
    p[j] = x0 * W1[tid * 8 + j] + x1 * W1[(tid + 256) * 8 + j];
    q[j] = y0 * W2[tid * 8 + j] + y1 * W2[(tid + 256) * 8 + j];
  }
#pragma unroll
  for (int j = 0; j < 8; ++j) {
#pragma unroll
    for (int o = 1; o < 64; o <<= 1) {
      p[j] += __shfl_xor(p[j], o);
      q[j] += __shfl_xor(q[j], o);
    }
  }
  __shared__ float sacc[4][16];
  if ((tid & 63) == 0) {
#pragma unroll
    for (int j = 0; j < 8; ++j) { sacc[tid >> 6][j] = p[j]; sacc[tid >> 6][8 + j] = q[j]; }
  }
  __syncthreads();
  if (tid < 8) {
    float s = sacc[0][tid] + sacc[1][tid] + sacc[2][tid] + sacc[3][tid];
    o1[(size_t)m * 8 + tid] = sigmoidf_(s);
  } else if (tid < 16) {
    int j = tid - 8;
    float s = sacc[0][8 + j] + sacc[1][8 + j] + sacc[2][8 + j] + sacc[3][8 + j];
    o2[(size_t)m * 8 + j] = sigmoidf_(s);
  }
}

// ---- per (m,h): L2-normalize q,k in place; pack scal8 = {beta, g, kq, kbv, bvq} ----
__global__ __launch_bounds__(256) void k_qknorm_dots(float* __restrict__ qkv,
                                                     const float* __restrict__ buv,
                                                     const float* __restrict__ betaF,
                                                     const float* __restrict__ alphaF,
                                                     const int* __restrict__ mask,
                                                     float* __restrict__ scal8) {
  int blk = blockIdx.x * 4 + (threadIdx.x >> 6);
  int m = blk >> 3, h = blk & 7, t = threadIdx.x & 63;
  size_t qi = (size_t)m * 1536 + h * 64 + t;
  float q = qkv[qi], k = qkv[qi + 512];
  float bv = buv[(size_t)m * 1024 + 512 + h * 64 + t];
  float qs = q * q, ks = k * k;
#pragma unroll
  for (int o = 1; o < 64; o <<= 1) { qs += __shfl_xor(qs, o); ks += __shfl_xor(ks, o); }
  float qn = q / (sqrtf(qs) + EPS_);
  float kn = k / (sqrtf(ks) + EPS_);
  qkv[qi] = qn; qkv[qi + 512] = kn;
  float d0 = kn * qn, d1 = kn * bv, d2 = bv * qn;
#pragma unroll
  for (int o = 1; o < 64; o <<= 1) {
    d0 += __shfl_xor(d0, o); d1 += __shfl_xor(d1, o); d2 += __shfl_xor(d2, o);
  }
  if (t == 0) {
    int mh = m * 8 + h;
    float4 s4;
    s4.x = betaF[mh];
    s4.y = alphaF[mh] * (1.0f - (float)mask[m]);
    s4.z = d0; s4.w = d1;
    *(float4*)(scal8 + (size_t)mh * 8) = s4;
    scal8[(size_t)mh * 8 + 4] = d2;
  }
}

// ======== pipelined bf16 MFMA GEMM: C = epi(A[M,K] @ Bt[N,K]^T), 64x64 tile ========
template <int EPI>
__global__ __launch_bounds__(256) void k_gemm2(const bf16* __restrict__ A,
                                               const bf16* __restrict__ Bt,
                                               void* __restrict__ Cv, int M, int N, int K,
                                               int actSplit, const float* __restrict__ bias,
                                               const float* __restrict__ res) {
  __shared__ bf16 As[2][64 * 32];
  __shared__ bf16 Bs[2][64 * 32];
  const int tid = threadIdx.x;
  const int wave = tid >> 6, lane = tid & 63;
  const int wm = wave >> 1, wn = wave & 1;
  const int m0 = blockIdx.y * 64, n0 = blockIdx.x * 64;
  const int lr = lane & 15, lg = lane >> 4;
  const int srow = (wave << 4) | (lane >> 2);
  const int skb = (lane & 3) << 3;
  const bf16* ga = A + (size_t)(m0 + srow) * K + skb;
  const bf16* gb = Bt + (size_t)(n0 + srow) * K + skb;

  f32x4 acc[2][2];
#pragma unroll
  for (int i = 0; i < 2; ++i)
#pragma unroll
    for (int j = 0; j < 2; ++j) acc[i][j] = (f32x4){0.f, 0.f, 0.f, 0.f};

  const int nk = K >> 5;
  int4 ar = *(const int4*)ga;
  int4 br = *(const int4*)gb;
  for (int t = 0; t < nk; ++t) {
    bf16* asb = &As[t & 1][0];
    bf16* bsb = &Bs[t & 1][0];
    *(int4*)(asb + tid * 8) = ar;
    *(int4*)(bsb + tid * 8) = br;
    __syncthreads();
    if (t + 1 < nk) {
      ar = *(const int4*)(ga + ((size_t)(t + 1) << 5));
      br = *(const int4*)(gb + ((size_t)(t + 1) << 5));
    }
    bf16x8 af[2], bfr[2];
#pragma unroll
    for (int mm = 0; mm < 2; ++mm)
      af[mm] = *(const bf16x8*)(asb + (wm * 32 + mm * 16 + lr) * 32 + lg * 8);
#pragma unroll
    for (int nn = 0; nn < 2; ++nn)
      bfr[nn] = *(const bf16x8*)(bsb + (wn * 32 + nn * 16 + lr) * 32 + lg * 8);
#pragma unroll
    for (int mm = 0; mm < 2; ++mm)
#pragma unroll
      for (int nn = 0; nn < 2; ++nn)
        acc[mm][nn] = __builtin_amdgcn_mfma_f32_16x16x32_bf16(af[mm], bfr[nn], acc[mm][nn], 0, 0, 0);
  }

  if constexpr (EPI == 4) {
    __syncthreads();
    float* gateL = (float*)&As[0][0];
    float* valL = (float*)&Bs[0][0];
    float* dstL = wn ? valL : gateL;
#pragma unroll
    for (int mm = 0; mm < 2; ++mm)
#pragma unroll
      for (int nn = 0; nn < 2; ++nn)
#pragma unroll
        for (int r = 0; r < 4; ++r)
          dstL[(wm * 32 + mm * 16 + lg * 4 + r) * 32 + nn * 16 + lr] = acc[mm][nn][r];
    __syncthreads();
    bf16* Cb = (bf16*)Cv;
    int row = tid >> 2, c0 = (tid & 3) * 8;
    bf16x8 o;
#pragma unroll
    for (int e = 0; e < 8; ++e) {
      float g = gateL[row * 32 + c0 + e];
      float v = valL[row * 32 + c0 + e];
      o[e] = bf_of(g * sigmoidf_(g) * v);
    }
    *(int4*)(Cb + (size_t)(m0 + row) * 2048 + blockIdx.x * 32 + c0) = *(int4*)&o;
  } else {
    float* C = (float*)Cv;
#pragma unroll
    for (int mm = 0; mm < 2; ++mm) {
#pragma unroll
      for (int nn = 0; nn < 2; ++nn) {
#pragma unroll
        for (int r = 0; r < 4; ++r) {
          int row = m0 + wm * 32 + mm * 16 + lg * 4 + r;
          int col = n0 + wn * 32 + nn * 16 + lr;
          float v = acc[mm][nn][r];
          if constexpr (EPI == 1) {
            if (col < actSplit) v = v * sigmoidf_(v);
          }
          if constexpr (EPI == 2) v += bias[col] + res[(size_t)row * N + col];
          if constexpr (EPI == 3) v += res[(size_t)row * N + col];
          C[(size_t)row * N + col] = v;
        }
      }
    }
  }
}

// ================= chunked recurrence =================
// Per-step transition: hs' = hs @ A_t + U_t,  A_t = g (I - beta k k^T),
// U_t[i][j] = beta v_i k_j + bu_i (bv_j - beta*kbv*k_j).
// Scan thread layout: tid = 4*i + q4; thread owns cols [q4*16, q4*16+16) of row i.

struct alignas(16) StepC {
  float k[16], bv[16], q[16];
  float v_i, bu_i, beta, g, kbv;
};

__device__ __forceinline__ void load_stepc(StepC& sd,
    const float* __restrict__ qkv, const float* __restrict__ buv,
    const float* __restrict__ scal8, int m, int h, int i, int j0) {
  const float* qb = qkv + (size_t)m * 1536 + h * 64;
  const float* bb = buv + (size_t)m * 1024 + h * 64;
#pragma unroll
  for (int p = 0; p < 4; ++p) *(float4*)&sd.k[p * 4] = *(const float4*)(qb + 512 + j0 + p * 4);
#pragma unroll
  for (int p = 0; p < 4; ++p) *(float4*)&sd.bv[p * 4] = *(const float4*)(bb + 512 + j0 + p * 4);
#pragma unroll
  for (int p = 0; p < 4; ++p) *(float4*)&sd.q[p * 4] = *(const float4*)(qb + j0 + p * 4);
  sd.v_i = qb[1024 + i];
  sd.bu_i = bb[i];
  const float* sp = scal8 + (size_t)(m * 8 + h) * 8;
  float4 s4 = *(const float4*)sp;
  sd.beta = s4.x; sd.g = s4.y; sd.kbv = s4.w;
}

// fold A_s into (P,U) (P,U become Pcum_s, Ucum_s), then emit
// qtilde_s[i] = (P q_s)[i], utilde_s[i] = (U q_s)[i] via 4-lane reduce.
__device__ __forceinline__ void step_fold_q(float P[16], float U[16], const StepC& sd,
                                            float* __restrict__ qt_addr,
                                            float* __restrict__ vt_addr, bool writer) {
  float Pk = 0.f, Uk = 0.f;
#pragma unroll
  for (int jj = 0; jj < 16; ++jj) { Pk += P[jj] * sd.k[jj]; Uk += U[jj] * sd.k[jj]; }
  Pk += __shfl_xor(Pk, 1); Pk += __shfl_xor(Pk, 2);
  Uk += __shfl_xor(Uk, 1); Uk += __shfl_xor(Uk, 2);
  float gb = sd.g * sd.beta;
  float cP = gb * Pk;
  float Ai = sd.beta * sd.v_i - gb * Uk - sd.bu_i * sd.beta * sd.kbv;
  float pq = 0.f, uq = 0.f;
#pragma unroll
  for (int jj = 0; jj < 16; ++jj) {
    P[jj] = sd.g * P[jj] - cP * sd.k[jj];
    U[jj] = sd.g * U[jj] + Ai * sd.k[jj] + sd.bu_i * sd.bv[jj];
    pq += P[jj] * sd.q[jj];
    uq += U[jj] * sd.q[jj];
  }
  pq += __shfl_xor(pq, 1); pq += __shfl_xor(pq, 2);
  uq += __shfl_xor(uq, 1); uq += __shfl_xor(uq, 2);
  if (writer) { *qt_addr = pq; *vt_addr = uq; }
}

// ---- phase 1: per-chunk transition (P^T bf16 hi/lo + U^T f32) + qtilde/utilde ----
__global__ __launch_bounds__(256) void k_scan_chunk(
    const float* __restrict__ qkv, const float* __restrict__ buv,
    const float* __restrict__ scal8, bf16* __restrict__ PtHi,
    bf16* __restrict__ PtLo, float* __restrict__ Ut,
    float* __restrict__ Qtb, float* __restrict__ Vtb) {
  int blk = blockIdx.x, bh = blk >> 5, c = blk & (CHUNKS_ - 1);
  int b = bh >> 3, h = bh & 7;
  int tid = threadIdx.x, i = tid >> 2, q4 = tid & 3, j0 = q4 * 16;
  bool writer = (q4 == 0);
  alignas(16) float P[16], U[16];
#pragma unroll
  for (int jj = 0; jj < 16; ++jj) { P[jj] = (j0 + jj == i) ? 1.f : 0.f; U[jj] = 0.f; }
  int m0 = b * S_ + c * CLEN_;
  float* QT = Qtb + ((size_t)bh * CHUNKS_ + c) * (CLEN_ * 64);
  float* VT = Vtb + ((size_t)bh * CHUNKS_ + c) * (CLEN_ * 64);
  StepC A, Bs;
  load_stepc(A, qkv, buv, scal8, m0, h, i, j0);
  load_stepc(Bs, qkv, buv, scal8, m0 + 1, h, i, j0);
  for (int s = 0; s < CLEN_; s += 2) {
    step_fold_q(P, U, A, QT + s * 64 + i, VT + s * 64 + i, writer);
    if (s + 2 < CLEN_) load_stepc(A, qkv, buv, scal8, m0 + s + 2, h, i, j0);
    step_fold_q(P, U, Bs, QT + (s + 1) * 64 + i, VT + (s + 1) * 64 + i, writer);
    if (s + 3 < CLEN_) load_stepc(Bs, qkv, buv, scal8, m0 + s + 3, h, i, j0);
  }
  const size_t base = ((size_t)bh * CHUNKS_ + c) * 4096;
#pragma unroll
  for (int jj = 0; jj < 16; ++jj) {
    int j = j0 + jj;
    float pv = P[jj];
    float rem;
    short ph = bf_hi(pv, rem);
    short pl = bf_of(rem);
    ((short*)PtHi)[base + (size_t)j * 64 + i] = ph;
    ((short*)PtLo)[base + (size_t)j * 64 + i] = pl;
    Ut[base + (size_t)j * 64 + i] = U[jj];
  }
}

// ---- phase 2: barrier-free register-resident MFMA chain ----
// One WAVE per (bh, 16-column strip of hs^T). State lives in D-fragments:
// st[mt][r] = hs^T[16mt+4lg+r][col0+lr]. Next B-frag rebuilt via lane shuffles.
#define PREFETCH_(SET, CIDX)                                                     \
  {                                                                              \
    const size_t cbo_ = (size_t)(CIDX) * 4096;                                   \
    _Pragma("unroll") for (int mt = 0; mt < 4; ++mt) {                           \
      _Pragma("unroll") for (int ks = 0; ks < 2; ++ks) {                         \
        size_t off_ = cbo_ + (size_t)(16 * mt + lr) * 64 + ks * 32 + lg * 8;     \
        aH[SET][mt][ks] = *(const bf16x8*)(PH + off_);                           \
        aL[SET][mt][ks] = *(const bf16x8*)(PL + off_);                           \
      }                                                                          \
      _Pragma("unroll") for (int r = 0; r < 4; ++r)                              \
        u[SET][mt][r] = UB[cbo_ + (size_t)(16 * mt + 4 * lg + r) * 64 + col0 + lr]; \
    }                                                                            \
  }

#define CHAINSTEP_(SET, NSET, CIDX)                                              \
  {                                                                              \
    if ((CIDX) + 1 < CHUNKS_) PREFETCH_(NSET, (CIDX) + 1);                       \
    _Pragma("unroll") for (int mt = 0; mt < 4; ++mt)                             \
      _Pragma("unroll") for (int r = 0; r < 4; ++r)                              \
        HB[(size_t)(CIDX) * 4096 + (size_t)(16 * mt + 4 * lg + r) * 64 + col0 + lr] = st[mt][r]; \
    bf16x8 bH[2], bL[2];                                                         \
    _Pragma("unroll") for (int ks = 0; ks < 2; ++ks) {                           \
      _Pragma("unroll") for (int e = 0; e < 8; ++e) {                            \
        int src_ = (2 * (lg & 1) + (e >> 2)) * 16 + lr;                          \
        float va_ = __shfl(st[2 * ks][e & 3], src_);                             \
        float vb_ = __shfl(st[2 * ks + 1][e & 3], src_);                         \
        float bv_ = (lg & 2) ? vb_ : va_;                                        \
        float rem_;                                                              \
        bH[ks][e] = bf_hi(bv_, rem_);                                            \
        bL[ks][e] = bf_of(rem_);                                                 \
      }                                                                          \
    }                                                                            \
    f32x4 stn[4];                                                                \
    _Pragma("unroll") for (int mt = 0; mt < 4; ++mt) {                           \
      f32x4 a_ = u[SET][mt];                                                     \
      _Pragma("unroll") for (int ks = 0; ks < 2; ++ks) {                         \
        a_ = __builtin_amdgcn_mfma_f32_16x16x32_bf16(aH[SET][mt][ks], bH[ks], a_, 0, 0, 0); \
        a_ = __builtin_amdgcn_mfma_f32_16x16x32_bf16(aH[SET][mt][ks], bL[ks], a_, 0, 0, 0); \
        a_ = __builtin_amdgcn_mfma_f32_16x16x32_bf16(aL[SET][mt][ks], bH[ks], a_, 0, 0, 0); \
      }                                                                          \
      stn[mt] = a_;                                                              \
    }                                                                            \
    _Pragma("unroll") for (int mt = 0; mt < 4; ++mt) st[mt] = stn[mt];           \
  }

__global__ __launch_bounds__(64, 1) void k_chain3(
    const bf16* __restrict__ PtHi, const bf16* __restrict__ PtLo,
    const float* __restrict__ Ut, const float* __restrict__ carry,
    float* __restrict__ Hbuf, float* __restrict__ out_hs) {
  const int bh = blockIdx.x >> 2, cb = blockIdx.x & 3, col0 = cb * 16;
  const int lane = threadIdx.x & 63, lr = lane & 15, lg = lane >> 4;
  const short* PH = (const short*)PtHi + (size_t)bh * CHUNKS_ * 4096;
  const short* PL = (const short*)PtLo + (size_t)bh * CHUNKS_ * 4096;
  const float* UB = Ut + (size_t)bh * CHUNKS_ * 4096;
  float* HB = Hbuf + (size_t)bh * CHUNKS_ * 4096;

  f32x4 st[4];
#pragma unroll
  for (int mt = 0; mt < 4; ++mt)
    st[mt] = *(const f32x4*)(carry + ((size_t)bh * 64 + col0 + lr) * 64 + 16 * mt + 4 * lg);

  bf16x8 aH[2][4][2], aL[2][4][2];
  f32x4 u[2][4];
  PREFETCH_(0, 0);
  for (int c = 0; c < CHUNKS_; c += 2) {
    CHAINSTEP_(0, 1, c);
    CHAINSTEP_(1, 0, c + 1);
  }
#pragma unroll
  for (int mt = 0; mt < 4; ++mt)
    *(f32x4*)(out_hs + ((size_t)bh * 64 + col0 + lr) * 64 + 16 * mt + 4 * lg) = st[mt];
}

// ---- phase 3: Attn[64x32] = H0 @ Qt^T + Vt per (bh, c), via hi/lo MFMA ----
// Hbuf layout: HB[c][j*64 + i] = hs[i][j] (j = H0 col index l). Qt[s][l], Vt[s][i].
__global__ __launch_bounds__(256) void k_attn_gemm(
    const float* __restrict__ Hbuf, const float* __restrict__ Qtb,
    const float* __restrict__ Vtb, float* __restrict__ attn) {
  const int blk = blockIdx.x, bh = blk >> 5, c = blk & (CHUNKS_ - 1);
  const int b = bh >> 3, h = bh & 7;
  const int tid = threadIdx.x, wave = tid >> 6, lane = tid & 63;
  const int lr = lane & 15, lg = lane >> 4;
  const float* H0 = Hbuf + ((size_t)bh * CHUNKS_ + c) * 4096;
  const float* QT = Qtb + ((size_t)bh * CHUNKS_ + c) * (CLEN_ * 64);
  const float* VT = Vtb + ((size_t)bh * CHUNKS_ + c) * (CLEN_ * 64);

  // A-frag: rows i = wave*16 + lr, k = l = ks*32 + lg*8 + e; H0[i][l] at H0[l*64+i]
  bf16x8 aH[2], aL[2];
#pragma unroll
  for (int ks = 0; ks < 2; ++ks) {
#pragma unroll
    for (int e = 0; e < 8; ++e) {
      float v = H0[(size_t)(ks * 32 + lg * 8 + e) * 64 + wave * 16 + lr];
      float rem;
      aH[ks][e] = bf_hi(v, rem);
      aL[ks][e] = bf_of(rem);
    }
  }
  f32x4 acc[2];
#pragma unroll
  for (int nt = 0; nt < 2; ++nt) {
    f32x4 a = (f32x4){0.f, 0.f, 0.f, 0.f};
#pragma unroll
    for (int ks = 0; ks < 2; ++ks) {
      const float* qp = QT + (size_t)(nt * 16 + lr) * 64 + ks * 32 + lg * 8;
      bf16x8 bH, bL;
#pragma unroll
      for (int e = 0; e < 8; ++e) {
        float rem;
        bH[e] = bf_hi(qp[e], rem);
        bL[e] = bf_of(rem);
      }
      a = __builtin_amdgcn_mfma_f32_16x16x32_bf16(aH[ks], bH, a, 0, 0, 0);
      a = __builtin_amdgcn_mfma_f32_16x16x32_bf16(aH[ks], bL, a, 0, 0, 0);
      a = __builtin_amdgcn_mfma_f32_16x16x32_bf16(aL[ks], bH, a, 0, 0, 0);
    }
    acc[nt] = a;
  }
  const int m0 = b * S_ + c * CLEN_;
#pragma unroll
  for (int nt = 0; nt < 2; ++nt) {
    int s = nt * 16 + lr;
    f32x4 vt = *(const f32x4*)(VT + (size_t)s * 64 + wave * 16 + lg * 4);
    f32x4 o = acc[nt];
#pragma unroll
    for (int r = 0; r < 4; ++r) o[r] += vt[r];
    *(f32x4*)(attn + (size_t)(m0 + s) * 512 + h * 64 + wave * 16 + lg * 4) = o;
  }
}

// ---------------- host ----------------
extern "C" void kernel_launch(void* const* d_in, const int* in_sizes, int n_in,
                              void* d_out, int out_size, void* d_ws, size_t ws_size,
                              hipStream_t stream) {
  const float* x      = (const float*)d_in[0];
  const int*   action = (const int*)d_in[1];
  const int*   mask   = (const int*)d_in[2];
  const float* carry  = (const float*)d_in[3];
  const float* n1s    = (const float*)d_in[4];
  const float* wq     = (const float*)d_in[5];
  const float* wk     = (const float*)d_in[6];
  const float* wv     = (const float*)d_in[7];
  const float* wbeta  = (const float*)d_in[8];
  const float* embed  = (const float*)d_in[9];
  const float* walpha = (const float*)d_in[10];
  const float* wbu    = (const float*)d_in[11];
  const float* wbv    = (const float*)d_in[12];
  const float* nas    = (const float*)d_in[13];
  const float* wout   = (const float*)d_in[14];
  const float* bout   = (const float*)d_in[15];
  const float* n2s    = (const float*)d_in[16];
  const float* wgate  = (const float*)d_in[17];
  const float* wval   = (const float*)d_in[18];
  const float* wffn   = (const float*)d_in[19];

  float* out_hs  = (float*)d_out;            // [2,8,64,64]
  float* out_ffn = (float*)d_out + 65536;    // [2,1024,512]

  char* p = (char*)d_ws;
  auto alloc = [&](size_t bytes) -> char* {
    char* r = p; p += (bytes + 255) & ~(size_t)255; return r;
  };
  bf16*  wqkvT = (bf16*)alloc((size_t)1536 * 512 * 2);
  bf16*  wbuvT = (bf16*)alloc((size_t)1024 * 512 * 2);
  bf16*  woutT = (bf16*)alloc((size_t)512 * 512 * 2);
  bf16*  wgvT  = (bf16*)alloc((size_t)4096 * 512 * 2);   // gate/val row-interleaved
  bf16*  wffnT = (bf16*)alloc((size_t)512 * 2048 * 2);
  float* qkvF  = (float*)alloc((size_t)M_ * 1536 * 4);
  float* buvF  = (float*)alloc((size_t)M_ * 1024 * 4);
  float* betaF = (float*)alloc((size_t)M_ * 8 * 4);
  float* alphaF= (float*)alloc((size_t)M_ * 8 * 4);
  float* scal8 = (float*)alloc((size_t)M_ * 8 * 8 * 4);
  float* attnF = (float*)alloc((size_t)M_ * 512 * 4);
  bf16*  attnB = (bf16*)alloc((size_t)M_ * 512 * 2);
  float* skipF = (float*)alloc((size_t)M_ * 512 * 4);
  bf16*  h2B   = (bf16*)alloc((size_t)M_ * 512 * 2);
  bf16*  ffnB  = (bf16*)alloc((size_t)M_ * 2048 * 2);
  // 32 MiB shared tail: early-phase hF/hB/aeF/aeB, later the chunk buffers
  // (hF/hB/aeF/aeB are dead before k_scan_chunk writes the chunk buffers).
  char*  tail  = alloc((size_t)32 * 1024 * 1024);
  if ((size_t)(p - (char*)d_ws) > ws_size) return;  // workspace too small

  float* hF  = (float*)tail;                               // 4 MiB
  bf16*  hB  = (bf16*)(tail + ((size_t)4 << 20));          // 2 MiB
  float* aeF = (float*)(tail + ((size_t)6 << 20));         // 4 MiB
  bf16*  aeB = (bf16*)(tail + ((size_t)10 << 20));         // 2 MiB

  bf16*  PtHi = (bf16*)tail;                               // 4 MiB
  bf16*  PtLo = (bf16*)(tail + ((size_t)4 << 20));         // 4 MiB
  float* UtB  = (float*)(tail + ((size_t)8 << 20));        // 8 MiB
  float* Hbuf = (float*)(tail + ((size_t)16 << 20));       // 8 MiB
  float* Qtb  = (float*)(tail + ((size_t)24 << 20));       // 4 MiB
  float* Vtb  = (float*)(tail + ((size_t)28 << 20));       // 4 MiB

  TTab tab;
  tab.j[0] = {wq,    wqkvT,              512,  512,  0,    0};
  tab.j[1] = {wk,    wqkvT + 512 * 512,  512,  512,  256,  0};
  tab.j[2] = {wv,    wqkvT + 1024 * 512, 512,  512,  512,  0};
  tab.j[3] = {wbu,   wbuvT,              512,  512,  768,  0};
  tab.j[4] = {wbv,   wbuvT + 512 * 512,  512,  512,  1024, 0};
  tab.j[5] = {wout,  woutT,              512,  512,  1280, 0};
  tab.j[6] = {wgate, wgvT,               512,  2048, 1536, 1};
  tab.j[7] = {wval,  wgvT,               512,  2048, 2560, 2};
  tab.j[8] = {wffn,  wffnT,              2048, 512,  3584, 0};
  k_transpose_all<<<4608, dim3(32, 8), 0, stream>>>(tab);

  k_rmsnorm<<<M_, 256, 0, stream>>>(x, n1s, hF, hB);
  k_gather<<<M_, 256, 0, stream>>>(action, embed, aeF, aeB);

  k_gemm2<1><<<dim3(1536 / 64, M_ / 64), 256, 0, stream>>>(hB, wqkvT, qkvF, M_, 1536, 512, 1024, nullptr, nullptr);
  k_gemm2<0><<<dim3(1024 / 64, M_ / 64), 256, 0, stream>>>(aeB, wbuvT, buvF, M_, 1024, 512, 0, nullptr, nullptr);
  k_dot8x2<<<M_, 256, 0, stream>>>(hF, aeF, wbeta, walpha, betaF, alphaF);
  k_qknorm_dots<<<M_ * 2, 256, 0, stream>>>(qkvF, buvF, betaF, alphaF, mask, scal8);
  // hF/hB/aeF/aeB dead from here; tail region is reused by the chunk buffers.

  k_scan_chunk<<<16 * CHUNKS_, 256, 0, stream>>>(qkvF, buvF, scal8, PtHi, PtLo, UtB, Qtb, Vtb);
  k_chain3<<<64, 64, 0, stream>>>(PtHi, PtLo, UtB, carry, Hbuf, out_hs);
  k_attn_gemm<<<16 * CHUNKS_, 256, 0, stream>>>(Hbuf, Qtb, Vtb, attnF);

  k_rmsnorm<<<M_, 256, 0, stream>>>(attnF, nas, nullptr, attnB);
  k_gemm2<2><<<dim3(512 / 64, M_ / 64), 256, 0, stream>>>(attnB, woutT, skipF, M_, 512, 512, 0, bout, x);
  k_rmsnorm<<<M_, 256, 0, stream>>>(skipF, n2s, nullptr, h2B);
  k_gemm2<4><<<dim3(4096 / 64, M_ / 64), 256, 0, stream>>>(h2B, wgvT, ffnB, M_, 4096, 512, 0, nullptr, nullptr);
  k_gemm2<3><<<dim3(512 / 64, M_ / 64), 256, 0, stream>>>(ffnB, wffnT, out_ffn, M_, 512, 2048, 0, nullptr, skipF);
}

// Round 7
// 190.184 us; speedup vs baseline: 8.6941x; 1.0579x over previous
//
#include <hip/hip_runtime.h>
#include <hip/hip_bf16.h>
#include <cstdint>
#include <cstddef>

using bf16 = __hip_bfloat16;
typedef __attribute__((ext_vector_type(8))) short bf16x8;  // 8 bf16 (4 VGPRs)
typedef __attribute__((ext_vector_type(4))) float f32x4;

static constexpr int B_ = 2, S_ = 1024, D_ = 512, H_ = 8;
static constexpr int M_ = B_ * S_;     // 2048 rows
static constexpr int CHUNKS_ = 32, CLEN_ = 32;  // S = CHUNKS * CLEN
static constexpr float EPS_ = 1e-6f;

__device__ __forceinline__ float sigmoidf_(float x) { return 1.0f / (1.0f + __expf(-x)); }

__device__ __forceinline__ short bf_hi(float v, float& rem) {
  bf16 h = __float2bfloat16(v);
  rem = v - __bfloat162float(h);
  return *(short*)&h;
}
__device__ __forceinline__ short bf_of(float v) {
  bf16 h = __float2bfloat16(v);
  return *(short*)&h;
}

// -------- fused transpose + cast: W [K][N] f32 -> Wt [dstRow(n)][K] bf16 --------
// xf: 0 linear; 1 gate-interleave (row = (n>>5)*64 + (n&31)); 2 val (+32)
struct TJob { const float* src; bf16* dst; int K, N, base, xf; };
struct TTab { TJob j[9]; };

__global__ __launch_bounds__(256) void k_transpose_all(TTab tab) {
  __shared__ float tile[32][33];
  int blk = blockIdx.x;
  int ji = 0;
#pragma unroll
  for (int t = 1; t < 9; ++t) if (tab.j[t].base <= blk) ji = t;
  const float* W = tab.j[ji].src;
  bf16* Wt = tab.j[ji].dst;
  int K = tab.j[ji].K, N = tab.j[ji].N, xf = tab.j[ji].xf;
  int rel = blk - tab.j[ji].base;
  int nb = N >> 5;
  int n0 = (rel % nb) * 32, k0 = (rel / nb) * 32;
  int tx = threadIdx.x, ty = threadIdx.y;  // 32 x 8
#pragma unroll
  for (int r = ty; r < 32; r += 8) tile[r][tx] = W[(size_t)(k0 + r) * N + n0 + tx];
  __syncthreads();
#pragma unroll
  for (int r = ty; r < 32; r += 8) {
    int n = n0 + r;
    int drow = n;
    if (xf == 1) drow = ((n >> 5) << 6) + (n & 31);
    else if (xf == 2) drow = ((n >> 5) << 6) + (n & 31) + 32;
    Wt[(size_t)drow * K + k0 + tx] = __float2bfloat16(tile[tx][r]);
  }
}

// ---------------- rmsnorm over D=512, optional f32 + bf16 outputs ----------------
__global__ __launch_bounds__(256) void k_rmsnorm(const float* __restrict__ x,
                                                 const float* __restrict__ scale,
                                                 float* __restrict__ outf,
                                                 bf16* __restrict__ outb) {
  int m = blockIdx.x, tid = threadIdx.x;
  const float* row = x + (size_t)m * D_;
  float2 v = *(const float2*)(row + tid * 2);
  float ss = v.x * v.x + v.y * v.y;
#pragma unroll
  for (int o = 1; o < 64; o <<= 1) ss += __shfl_xor(ss, o);
  __shared__ float wsum[4];
  if ((tid & 63) == 0) wsum[tid >> 6] = ss;
  __syncthreads();
  float tot = wsum[0] + wsum[1] + wsum[2] + wsum[3];
  float rs = rsqrtf(tot * (1.0f / (float)D_) + EPS_);
  float2 sc = *(const float2*)(scale + tid * 2);
  float o0 = v.x * rs * sc.x, o1 = v.y * rs * sc.y;
  if (outf) {
    float2 o; o.x = o0; o.y = o1;
    *(float2*)(outf + (size_t)m * D_ + tid * 2) = o;
  }
  if (outb) {
    bf16* p = outb + (size_t)m * D_ + tid * 2;
    p[0] = __float2bfloat16(o0); p[1] = __float2bfloat16(o1);
  }
}

// ---------------- action-embedding gather ----------------
__global__ __launch_bounds__(256) void k_gather(const int* __restrict__ action,
                                                const float* __restrict__ embed,
                                                float* __restrict__ aef, bf16* __restrict__ aeb) {
  int m = blockIdx.x, tid = threadIdx.x;
  int a = action[m];
  float2 v = *(const float2*)(embed + (size_t)a * 512 + tid * 2);
  *(float2*)(aef + (size_t)m * 512 + tid * 2) = v;
  bf16* p = aeb + (size_t)m * 512 + tid * 2;
  p[0] = __float2bfloat16(v.x); p[1] = __float2bfloat16(v.y);
}

// ---- beta = sigmoid(hF@wbeta), alpha = sigmoid(aeF@walpha) in one dispatch ----
__global__ __launch_bounds__(256) void k_dot8x2(const float* __restrict__ hF,
                                                const float* __restrict__ aeF,
                                                const float* __restrict__ W1,
                                                const float* __restrict__ W2,
                                                float* __restrict__ o1,
                                                float* __restrict__ o2) {
  int m = blockIdx.x, tid = threadIdx.x;
  float x0 = hF[(size_t)m * D_ + tid], x1 = hF[(size_t)m * D_ + 256 + tid];
  float y0 = aeF[(size_t)m * D_ + tid], y1 = aeF[(size_t)m * D_ + 256 + tid];
  float p[8], q[8];
#pragma unroll
  for (int j = 0; j < 8; ++j) {
    p[j] = x0 * W1[tid * 8 + j] + x1 * W1[(tid + 256) * 8 + j];
    q[j] = y0 * W2[tid * 8 + j] + y1 * W2[(tid + 256) * 8 + j];
  }
#pragma unroll
  for (int j = 0; j < 8; ++j) {
#pragma unroll
    for (int o = 1; o < 64; o <<= 1) {
      p[j] += __shfl_xor(p[j], o);
      q[j] += __shfl_xor(q[j], o);
    }
  }
  __shared__ float sacc[4][16];
  if ((tid & 63) == 0) {
#pragma unroll
    for (int j = 0; j < 8; ++j) { sacc[tid >> 6][j] = p[j]; sacc[tid >> 6][8 + j] = q[j]; }
  }
  __syncthreads();
  if (tid < 8) {
    float s = sacc[0][tid] + sacc[1][tid] + sacc[2][tid] + sacc[3][tid];
    o1[(size_t)m * 8 + tid] = sigmoidf_(s);
  } else if (tid < 16) {
    int j = tid - 8;
    float s = sacc[0][8 + j] + sacc[1][8 + j] + sacc[2][8 + j] + sacc[3][8 + j];
    o2[(size_t)m * 8 + j] = sigmoidf_(s);
  }
}

// ---- per (m,h): L2-normalize q,k in place; pack scal8 = {beta, g, kq, kbv, bvq} ----
__global__ __launch_bounds__(256) void k_qknorm_dots(float* __restrict__ qkv,
                                                     const float* __restrict__ buv,
                                                     const float* __restrict__ betaF,
                                                     const float* __restrict__ alphaF,
                                                     const int* __restrict__ mask,
                                                     float* __restrict__ scal8) {
  int blk = blockIdx.x * 4 + (threadIdx.x >> 6);
  int m = blk >> 3, h = blk & 7, t = threadIdx.x & 63;
  size_t qi = (size_t)m * 1536 + h * 64 + t;
  float q = qkv[qi], k = qkv[qi + 512];
  float bv = buv[(size_t)m * 1024 + 512 + h * 64 + t];
  float qs = q * q, ks = k * k;
#pragma unroll
  for (int o = 1; o < 64; o <<= 1) { qs += __shfl_xor(qs, o); ks += __shfl_xor(ks, o); }
  float qn = q / (sqrtf(qs) + EPS_);
  float kn = k / (sqrtf(ks) + EPS_);
  qkv[qi] = qn; qkv[qi + 512] = kn;
  float d0 = kn * qn, d1 = kn * bv, d2 = bv * qn;
#pragma unroll
  for (int o = 1; o < 64; o <<= 1) {
    d0 += __shfl_xor(d0, o); d1 += __shfl_xor(d1, o); d2 += __shfl_xor(d2, o);
  }
  if (t == 0) {
    int mh = m * 8 + h;
    float4 s4;
    s4.x = betaF[mh];
    s4.y = alphaF[mh] * (1.0f - (float)mask[m]);
    s4.z = d0; s4.w = d1;
    *(float4*)(scal8 + (size_t)mh * 8) = s4;
    scal8[(size_t)mh * 8 + 4] = d2;
  }
}

// ======== pipelined bf16 MFMA GEMM: C = epi(A[M,K] @ Bt[N,K]^T), 64x64 tile ========
template <int EPI>
__global__ __launch_bounds__(256) void k_gemm2(const bf16* __restrict__ A,
                                               const bf16* __restrict__ Bt,
                                               void* __restrict__ Cv, int M, int N, int K,
                                               int actSplit, const float* __restrict__ bias,
                                               const float* __restrict__ res) {
  __shared__ bf16 As[2][64 * 32];
  __shared__ bf16 Bs[2][64 * 32];
  const int tid = threadIdx.x;
  const int wave = tid >> 6, lane = tid & 63;
  const int wm = wave >> 1, wn = wave & 1;
  const int m0 = blockIdx.y * 64, n0 = blockIdx.x * 64;
  const int lr = lane & 15, lg = lane >> 4;
  const int srow = (wave << 4) | (lane >> 2);
  const int skb = (lane & 3) << 3;
  const bf16* ga = A + (size_t)(m0 + srow) * K + skb;
  const bf16* gb = Bt + (size_t)(n0 + srow) * K + skb;

  f32x4 acc[2][2];
#pragma unroll
  for (int i = 0; i < 2; ++i)
#pragma unroll
    for (int j = 0; j < 2; ++j) acc[i][j] = (f32x4){0.f, 0.f, 0.f, 0.f};

  const int nk = K >> 5;
  int4 ar = *(const int4*)ga;
  int4 br = *(const int4*)gb;
  for (int t = 0; t < nk; ++t) {
    bf16* asb = &As[t & 1][0];
    bf16* bsb = &Bs[t & 1][0];
    *(int4*)(asb + tid * 8) = ar;
    *(int4*)(bsb + tid * 8) = br;
    __syncthreads();
    if (t + 1 < nk) {
      ar = *(const int4*)(ga + ((size_t)(t + 1) << 5));
      br = *(const int4*)(gb + ((size_t)(t + 1) << 5));
    }
    bf16x8 af[2], bfr[2];
#pragma unroll
    for (int mm = 0; mm < 2; ++mm)
      af[mm] = *(const bf16x8*)(asb + (wm * 32 + mm * 16 + lr) * 32 + lg * 8);
#pragma unroll
    for (int nn = 0; nn < 2; ++nn)
      bfr[nn] = *(const bf16x8*)(bsb + (wn * 32 + nn * 16 + lr) * 32 + lg * 8);
#pragma unroll
    for (int mm = 0; mm < 2; ++mm)
#pragma unroll
      for (int nn = 0; nn < 2; ++nn)
        acc[mm][nn] = __builtin_amdgcn_mfma_f32_16x16x32_bf16(af[mm], bfr[nn], acc[mm][nn], 0, 0, 0);
  }

  if constexpr (EPI == 4) {
    __syncthreads();
    float* gateL = (float*)&As[0][0];
    float* valL = (float*)&Bs[0][0];
    float* dstL = wn ? valL : gateL;
#pragma unroll
    for (int mm = 0; mm < 2; ++mm)
#pragma unroll
      for (int nn = 0; nn < 2; ++nn)
#pragma unroll
        for (int r = 0; r < 4; ++r)
          dstL[(wm * 32 + mm * 16 + lg * 4 + r) * 32 + nn * 16 + lr] = acc[mm][nn][r];
    __syncthreads();
    bf16* Cb = (bf16*)Cv;
    int row = tid >> 2, c0 = (tid & 3) * 8;
    bf16x8 o;
#pragma unroll
    for (int e = 0; e < 8; ++e) {
      float g = gateL[row * 32 + c0 + e];
      float v = valL[row * 32 + c0 + e];
      o[e] = bf_of(g * sigmoidf_(g) * v);
    }
    *(int4*)(Cb + (size_t)(m0 + row) * 2048 + blockIdx.x * 32 + c0) = *(int4*)&o;
  } else {
    float* C = (float*)Cv;
#pragma unroll
    for (int mm = 0; mm < 2; ++mm) {
#pragma unroll
      for (int nn = 0; nn < 2; ++nn) {
#pragma unroll
        for (int r = 0; r < 4; ++r) {
          int row = m0 + wm * 32 + mm * 16 + lg * 4 + r;
          int col = n0 + wn * 32 + nn * 16 + lr;
          float v = acc[mm][nn][r];
          if constexpr (EPI == 1) {
            if (col < actSplit) v = v * sigmoidf_(v);
          }
          if constexpr (EPI == 2) v += bias[col] + res[(size_t)row * N + col];
          if constexpr (EPI == 3) v += res[(size_t)row * N + col];
          C[(size_t)row * N + col] = v;
        }
      }
    }
  }
}

// ================= chunked recurrence =================
// Per-step transition: hs' = hs @ A_t + U_t,  A_t = g (I - beta k k^T),
// U_t[i][j] = beta v_i k_j + bu_i (bv_j - beta*kbv*k_j).
// Scan thread layout: tid = 8*i + q8; thread owns cols [q8*8, q8*8+8) of row i.

struct alignas(16) StepC8 {
  float k[8], bv[8], q[8];
  float v_i, bu_i, beta, g, kbv;
};

__device__ __forceinline__ void load_stepc8(StepC8& sd,
    const float* __restrict__ qkv, const float* __restrict__ buv,
    const float* __restrict__ scal8, int m, int h, int i, int j0) {
  const float* qb = qkv + (size_t)m * 1536 + h * 64;
  const float* bb = buv + (size_t)m * 1024 + h * 64;
  *(float4*)&sd.k[0] = *(const float4*)(qb + 512 + j0);
  *(float4*)&sd.k[4] = *(const float4*)(qb + 512 + j0 + 4);
  *(float4*)&sd.bv[0] = *(const float4*)(bb + 512 + j0);
  *(float4*)&sd.bv[4] = *(const float4*)(bb + 512 + j0 + 4);
  *(float4*)&sd.q[0] = *(const float4*)(qb + j0);
  *(float4*)&sd.q[4] = *(const float4*)(qb + j0 + 4);
  sd.v_i = qb[1024 + i];
  sd.bu_i = bb[i];
  const float* sp = scal8 + (size_t)(m * 8 + h) * 8;
  float4 s4 = *(const float4*)sp;
  sd.beta = s4.x; sd.g = s4.y; sd.kbv = s4.w;
}

// fold A_s into (P,U) (P,U become Pcum_s, Ucum_s), then emit
// qtilde_s[i] = (P q_s)[i], utilde_s[i] = (U q_s)[i] via 8-lane reduce.
__device__ __forceinline__ void step_fold_q8(float P[8], float U[8], const StepC8& sd,
                                             float* __restrict__ qt_addr,
                                             float* __restrict__ vt_addr, bool writer) {
  float Pk = 0.f, Uk = 0.f;
#pragma unroll
  for (int jj = 0; jj < 8; ++jj) { Pk += P[jj] * sd.k[jj]; Uk += U[jj] * sd.k[jj]; }
  Pk += __shfl_xor(Pk, 1); Pk += __shfl_xor(Pk, 2); Pk += __shfl_xor(Pk, 4);
  Uk += __shfl_xor(Uk, 1); Uk += __shfl_xor(Uk, 2); Uk += __shfl_xor(Uk, 4);
  float gb = sd.g * sd.beta;
  float cP = gb * Pk;
  float Ai = sd.beta * sd.v_i - gb * Uk - sd.bu_i * sd.beta * sd.kbv;
  float pq = 0.f, uq = 0.f;
#pragma unroll
  for (int jj = 0; jj < 8; ++jj) {
    P[jj] = sd.g * P[jj] - cP * sd.k[jj];
    U[jj] = sd.g * U[jj] + Ai * sd.k[jj] + sd.bu_i * sd.bv[jj];
    pq += P[jj] * sd.q[jj];
    uq += U[jj] * sd.q[jj];
  }
  pq += __shfl_xor(pq, 1); pq += __shfl_xor(pq, 2); pq += __shfl_xor(pq, 4);
  uq += __shfl_xor(uq, 1); uq += __shfl_xor(uq, 2); uq += __shfl_xor(uq, 4);
  if (writer) { *qt_addr = pq; *vt_addr = uq; }
}

// ---- phase 1: per-chunk transition (P^T bf16 hi/lo + U^T f32) + qtilde/utilde ----
// 512 threads: tid = 8*i + q8 -> 8 waves/block, 4 waves/SIMD at 512-block grid.
__global__ __launch_bounds__(512) void k_scan_chunk(
    const float* __restrict__ qkv, const float* __restrict__ buv,
    const float* __restrict__ scal8, bf16* __restrict__ PtHi,
    bf16* __restrict__ PtLo, float* __restrict__ Ut,
    float* __restrict__ Qtb, float* __restrict__ Vtb) {
  int blk = blockIdx.x, bh = blk >> 5, c = blk & (CHUNKS_ - 1);
  int b = bh >> 3, h = bh & 7;
  int tid = threadIdx.x, i = tid >> 3, q8 = tid & 7, j0 = q8 * 8;
  bool writer = (q8 == 0);
  alignas(16) float P[8], U[8];
#pragma unroll
  for (int jj = 0; jj < 8; ++jj) { P[jj] = (j0 + jj == i) ? 1.f : 0.f; U[jj] = 0.f; }
  int m0 = b * S_ + c * CLEN_;
  float* QT = Qtb + ((size_t)bh * CHUNKS_ + c) * (CLEN_ * 64);
  float* VT = Vtb + ((size_t)bh * CHUNKS_ + c) * (CLEN_ * 64);
  StepC8 A, Bs;
  load_stepc8(A, qkv, buv, scal8, m0, h, i, j0);
  load_stepc8(Bs, qkv, buv, scal8, m0 + 1, h, i, j0);
  for (int s = 0; s < CLEN_; s += 2) {
    step_fold_q8(P, U, A, QT + s * 64 + i, VT + s * 64 + i, writer);
    if (s + 2 < CLEN_) load_stepc8(A, qkv, buv, scal8, m0 + s + 2, h, i, j0);
    step_fold_q8(P, U, Bs, QT + (s + 1) * 64 + i, VT + (s + 1) * 64 + i, writer);
    if (s + 3 < CLEN_) load_stepc8(Bs, qkv, buv, scal8, m0 + s + 3, h, i, j0);
  }
  const size_t base = ((size_t)bh * CHUNKS_ + c) * 4096;
#pragma unroll
  for (int jj = 0; jj < 8; ++jj) {
    int j = j0 + jj;
    float pv = P[jj];
    float rem;
    short ph = bf_hi(pv, rem);
    short pl = bf_of(rem);
    ((short*)PtHi)[base + (size_t)j * 64 + i] = ph;
    ((short*)PtLo)[base + (size_t)j * 64 + i] = pl;
    Ut[base + (size_t)j * 64 + i] = U[jj];
  }
}

// ---- phase 2: barrier-free register-resident MFMA chain ----
// One WAVE per (bh, 16-column strip of hs^T). State lives in D-fragments:
// st[mt][r] = hs^T[16mt+4lg+r][col0+lr]. Next B-frag rebuilt via lane shuffles.
#define PREFETCH_(SET, CIDX)                                                     \
  {                                                                              \
    const size_t cbo_ = (size_t)(CIDX) * 4096;                                   \
    _Pragma("unroll") for (int mt = 0; mt < 4; ++mt) {                           \
      _Pragma("unroll") for (int ks = 0; ks < 2; ++ks) {                         \
        size_t off_ = cbo_ + (size_t)(16 * mt + lr) * 64 + ks * 32 + lg * 8;     \
        aH[SET][mt][ks] = *(const bf16x8*)(PH + off_);                           \
        aL[SET][mt][ks] = *(const bf16x8*)(PL + off_);                           \
      }                                                                          \
      _Pragma("unroll") for (int r = 0; r < 4; ++r)                              \
        u[SET][mt][r] = UB[cbo_ + (size_t)(16 * mt + 4 * lg + r) * 64 + col0 + lr]; \
    }                                                                            \
  }

#define CHAINSTEP_(SET, NSET, CIDX)                                              \
  {                                                                              \
    if ((CIDX) + 1 < CHUNKS_) PREFETCH_(NSET, (CIDX) + 1);                       \
    _Pragma("unroll") for (int mt = 0; mt < 4; ++mt)                             \
      _Pragma("unroll") for (int r = 0; r < 4; ++r)                              \
        HB[(size_t)(CIDX) * 4096 + (size_t)(16 * mt + 4 * lg + r) * 64 + col0 + lr] = st[mt][r]; \
    bf16x8 bH[2], bL[2];                                                         \
    _Pragma("unroll") for (int ks = 0; ks < 2; ++ks) {                           \
      _Pragma("unroll") for (int e = 0; e < 8; ++e) {                            \
        int src_ = (2 * (lg & 1) + (e >> 2)) * 16 + lr;                          \
        float va_ = __shfl(st[2 * ks][e & 3], src_);                             \
        float vb_ = __shfl(st[2 * ks + 1][e & 3], src_);                         \
        float bv_ = (lg & 2) ? vb_ : va_;                                        \
        float rem_;                                                              \
        bH[ks][e] = bf_hi(bv_, rem_);                                            \
        bL[ks][e] = bf_of(rem_);                                                 \
      }                                                                          \
    }                                                                            \
    f32x4 stn[4];                                                                \
    _Pragma("unroll") for (int mt = 0; mt < 4; ++mt) {                           \
      f32x4 a_ = u[SET][mt];                                                     \
      _Pragma("unroll") for (int ks = 0; ks < 2; ++ks) {                         \
        a_ = __builtin_amdgcn_mfma_f32_16x16x32_bf16(aH[SET][mt][ks], bH[ks], a_, 0, 0, 0); \
        a_ = __builtin_amdgcn_mfma_f32_16x16x32_bf16(aH[SET][mt][ks], bL[ks], a_, 0, 0, 0); \
        a_ = __builtin_amdgcn_mfma_f32_16x16x32_bf16(aL[SET][mt][ks], bH[ks], a_, 0, 0, 0); \
      }                                                                          \
      stn[mt] = a_;                                                              \
    }                                                                            \
    _Pragma("unroll") for (int mt = 0; mt < 4; ++mt) st[mt] = stn[mt];           \
  }

__global__ __launch_bounds__(64, 1) void k_chain3(
    const bf16* __restrict__ PtHi, const bf16* __restrict__ PtLo,
    const float* __restrict__ Ut, const float* __restrict__ carry,
    float* __restrict__ Hbuf, float* __restrict__ out_hs) {
  const int bh = blockIdx.x >> 2, cb = blockIdx.x & 3, col0 = cb * 16;
  const int lane = threadIdx.x & 63, lr = lane & 15, lg = lane >> 4;
  const short* PH = (const short*)PtHi + (size_t)bh * CHUNKS_ * 4096;
  const short* PL = (const short*)PtLo + (size_t)bh * CHUNKS_ * 4096;
  const float* UB = Ut + (size_t)bh * CHUNKS_ * 4096;
  float* HB = Hbuf + (size_t)bh * CHUNKS_ * 4096;

  f32x4 st[4];
#pragma unroll
  for (int mt = 0; mt < 4; ++mt)
    st[mt] = *(const f32x4*)(carry + ((size_t)bh * 64 + col0 + lr) * 64 + 16 * mt + 4 * lg);

  bf16x8 aH[2][4][2], aL[2][4][2];
  f32x4 u[2][4];
  PREFETCH_(0, 0);
  for (int c = 0; c < CHUNKS_; c += 2) {
    CHAINSTEP_(0, 1, c);
    CHAINSTEP_(1, 0, c + 1);
  }
#pragma unroll
  for (int mt = 0; mt < 4; ++mt)
    *(f32x4*)(out_hs + ((size_t)bh * 64 + col0 + lr) * 64 + 16 * mt + 4 * lg) = st[mt];
}

// ---- phase 3: Attn[64x32] = H0 @ Qt^T + Vt per (bh, c), via hi/lo MFMA ----
// Hbuf layout: HB[c][j*64 + i] = hs[i][j] (j = H0 col index l). Qt[s][l], Vt[s][i].
__global__ __launch_bounds__(256) void k_attn_gemm(
    const float* __restrict__ Hbuf, const float* __restrict__ Qtb,
    const float* __restrict__ Vtb, float* __restrict__ attn) {
  const int blk = blockIdx.x, bh = blk >> 5, c = blk & (CHUNKS_ - 1);
  const int b = bh >> 3, h = bh & 7;
  const int tid = threadIdx.x, wave = tid >> 6, lane = tid & 63;
  const int lr = lane & 15, lg = lane >> 4;
  const float* H0 = Hbuf + ((size_t)bh * CHUNKS_ + c) * 4096;
  const float* QT = Qtb + ((size_t)bh * CHUNKS_ + c) * (CLEN_ * 64);
  const float* VT = Vtb + ((size_t)bh * CHUNKS_ + c) * (CLEN_ * 64);

  // A-frag: rows i = wave*16 + lr, k = l = ks*32 + lg*8 + e; H0[i][l] at H0[l*64+i]
  bf16x8 aH[2], aL[2];
#pragma unroll
  for (int ks = 0; ks < 2; ++ks) {
#pragma unroll
    for (int e = 0; e < 8; ++e) {
      float v = H0[(size_t)(ks * 32 + lg * 8 + e) * 64 + wave * 16 + lr];
      float rem;
      aH[ks][e] = bf_hi(v, rem);
      aL[ks][e] = bf_of(rem);
    }
  }
  f32x4 acc[2];
#pragma unroll
  for (int nt = 0; nt < 2; ++nt) {
    f32x4 a = (f32x4){0.f, 0.f, 0.f, 0.f};
#pragma unroll
    for (int ks = 0; ks < 2; ++ks) {
      const float* qp = QT + (size_t)(nt * 16 + lr) * 64 + ks * 32 + lg * 8;
      bf16x8 bH, bL;
#pragma unroll
      for (int e = 0; e < 8; ++e) {
        float rem;
        bH[e] = bf_hi(qp[e], rem);
        bL[e] = bf_of(rem);
      }
      a = __builtin_amdgcn_mfma_f32_16x16x32_bf16(aH[ks], bH, a, 0, 0, 0);
      a = __builtin_amdgcn_mfma_f32_16x16x32_bf16(aH[ks], bL, a, 0, 0, 0);
      a = __builtin_amdgcn_mfma_f32_16x16x32_bf16(aL[ks], bH, a, 0, 0, 0);
    }
    acc[nt] = a;
  }
  const int m0 = b * S_ + c * CLEN_;
#pragma unroll
  for (int nt = 0; nt < 2; ++nt) {
    int s = nt * 16 + lr;
    f32x4 vt = *(const f32x4*)(VT + (size_t)s * 64 + wave * 16 + lg * 4);
    f32x4 o = acc[nt];
#pragma unroll
    for (int r = 0; r < 4; ++r) o[r] += vt[r];
    *(f32x4*)(attn + (size_t)(m0 + s) * 512 + h * 64 + wave * 16 + lg * 4) = o;
  }
}

// ---------------- host ----------------
extern "C" void kernel_launch(void* const* d_in, const int* in_sizes, int n_in,
                              void* d_out, int out_size, void* d_ws, size_t ws_size,
                              hipStream_t stream) {
  const float* x      = (const float*)d_in[0];
  const int*   action = (const int*)d_in[1];
  const int*   mask   = (const int*)d_in[2];
  const float* carry  = (const float*)d_in[3];
  const float* n1s    = (const float*)d_in[4];
  const float* wq     = (const float*)d_in[5];
  const float* wk     = (const float*)d_in[6];
  const float* wv     = (const float*)d_in[7];
  const float* wbeta  = (const float*)d_in[8];
  const float* embed  = (const float*)d_in[9];
  const float* walpha = (const float*)d_in[10];
  const float* wbu    = (const float*)d_in[11];
  const float* wbv    = (const float*)d_in[12];
  const float* nas    = (const float*)d_in[13];
  const float* wout   = (const float*)d_in[14];
  const float* bout   = (const float*)d_in[15];
  const float* n2s    = (const float*)d_in[16];
  const float* wgate  = (const float*)d_in[17];
  const float* wval   = (const float*)d_in[18];
  const float* wffn   = (const float*)d_in[19];

  float* out_hs  = (float*)d_out;            // [2,8,64,64]
  float* out_ffn = (float*)d_out + 65536;    // [2,1024,512]

  char* p = (char*)d_ws;
  auto alloc = [&](size_t bytes) -> char* {
    char* r = p; p += (bytes + 255) & ~(size_t)255; return r;
  };
  bf16*  wqkvT = (bf16*)alloc((size_t)1536 * 512 * 2);
  bf16*  wbuvT = (bf16*)alloc((size_t)1024 * 512 * 2);
  bf16*  woutT = (bf16*)alloc((size_t)512 * 512 * 2);
  bf16*  wgvT  = (bf16*)alloc((size_t)4096 * 512 * 2);   // gate/val row-interleaved
  bf16*  wffnT = (bf16*)alloc((size_t)512 * 2048 * 2);
  float* qkvF  = (float*)alloc((size_t)M_ * 1536 * 4);
  float* buvF  = (float*)alloc((size_t)M_ * 1024 * 4);
  float* betaF = (float*)alloc((size_t)M_ * 8 * 4);
  float* alphaF= (float*)alloc((size_t)M_ * 8 * 4);
  float* scal8 = (float*)alloc((size_t)M_ * 8 * 8 * 4);
  float* attnF = (float*)alloc((size_t)M_ * 512 * 4);
  bf16*  attnB = (bf16*)alloc((size_t)M_ * 512 * 2);
  float* skipF = (float*)alloc((size_t)M_ * 512 * 4);
  bf16*  h2B   = (bf16*)alloc((size_t)M_ * 512 * 2);
  bf16*  ffnB  = (bf16*)alloc((size_t)M_ * 2048 * 2);
  // 32 MiB shared tail: early-phase hF/hB/aeF/aeB, later the chunk buffers
  // (hF/hB/aeF/aeB are dead before k_scan_chunk writes the chunk buffers).
  char*  tail  = alloc((size_t)32 * 1024 * 1024);
  if ((size_t)(p - (char*)d_ws) > ws_size) return;  // workspace too small

  float* hF  = (float*)tail;                               // 4 MiB
  bf16*  hB  = (bf16*)(tail + ((size_t)4 << 20));          // 2 MiB
  float* aeF = (float*)(tail + ((size_t)6 << 20));         // 4 MiB
  bf16*  aeB = (bf16*)(tail + ((size_t)10 << 20));         // 2 MiB

  bf16*  PtHi = (bf16*)tail;                               // 4 MiB
  bf16*  PtLo = (bf16*)(tail + ((size_t)4 << 20));         // 4 MiB
  float* UtB  = (float*)(tail + ((size_t)8 << 20));        // 8 MiB
  float* Hbuf = (float*)(tail + ((size_t)16 << 20));       // 8 MiB
  float* Qtb  = (float*)(tail + ((size_t)24 << 20));       // 4 MiB
  float* Vtb  = (float*)(tail + ((size_t)28 << 20));       // 4 MiB

  TTab tab;
  tab.j[0] = {wq,    wqkvT,              512,  512,  0,    0};
  tab.j[1] = {wk,    wqkvT + 512 * 512,  512,  512,  256,  0};
  tab.j[2] = {wv,    wqkvT + 1024 * 512, 512,  512,  512,  0};
  tab.j[3] = {wbu,   wbuvT,              512,  512,  768,  0};
  tab.j[4] = {wbv,   wbuvT + 512 * 512,  512,  512,  1024, 0};
  tab.j[5] = {wout,  woutT,              512,  512,  1280, 0};
  tab.j[6] = {wgate, wgvT,               512,  2048, 1536, 1};
  tab.j[7] = {wval,  wgvT,               512,  2048, 2560, 2};
  tab.j[8] = {wffn,  wffnT,              2048, 512,  3584, 0};
  k_transpose_all<<<4608, dim3(32, 8), 0, stream>>>(tab);

  k_rmsnorm<<<M_, 256, 0, stream>>>(x, n1s, hF, hB);
  k_gather<<<M_, 256, 0, stream>>>(action, embed, aeF, aeB);

  k_gemm2<1><<<dim3(1536 / 64, M_ / 64), 256, 0, stream>>>(hB, wqkvT, qkvF, M_, 1536, 512, 1024, nullptr, nullptr);
  k_gemm2<0><<<dim3(1024 / 64, M_ / 64), 256, 0, stream>>>(aeB, wbuvT, buvF, M_, 1024, 512, 0, nullptr, nullptr);
  k_dot8x2<<<M_, 256, 0, stream>>>(hF, aeF, wbeta, walpha, betaF, alphaF);
  k_qknorm_dots<<<M_ * 2, 256, 0, stream>>>(qkvF, buvF, betaF, alphaF, mask, scal8);
  // hF/hB/aeF/aeB dead from here; tail region is reused by the chunk buffers.

  k_scan_chunk<<<16 * CHUNKS_, 512, 0, stream>>>(qkvF, buvF, scal8, PtHi, PtLo, UtB, Qtb, Vtb);
  k_chain3<<<64, 64, 0, stream>>>(PtHi, PtLo, UtB, carry, Hbuf, out_hs);
  k_attn_gemm<<<16 * CHUNKS_, 256, 0, stream>>>(Hbuf, Qtb, Vtb, attnF);

  k_rmsnorm<<<M_, 256, 0, stream>>>(attnF, nas, nullptr, attnB);
  k_gemm2<2><<<dim3(512 / 64, M_ / 64), 256, 0, stream>>>(attnB, woutT, skipF, M_, 512, 512, 0, bout, x);
  k_rmsnorm<<<M_, 256, 0, stream>>>(skipF, n2s, nullptr, h2B);
  k_gemm2<4><<<dim3(4096 / 64, M_ / 64), 256, 0, stream>>>(h2B, wgvT, ffnB, M_, 4096, 512, 0, nullptr, nullptr);
  k_gemm2<3><<<dim3(512 / 64, M_ / 64), 256, 0, stream>>>(ffnB, wffnT, out_ffn, M_, 512, 2048, 0, nullptr, skipF);
}

// Round 8
// 190.130 us; speedup vs baseline: 8.6966x; 1.0003x over previous
//
#include <hip/hip_runtime.h>
#include <hip/hip_bf16.h>
#include <cstdint>
#include <cstddef>

using bf16 = __hip_bfloat16;
typedef __attribute__((ext_vector_type(8))) short bf16x8;  // 8 bf16 (4 VGPRs)
typedef __attribute__((ext_vector_type(4))) float f32x4;

static constexpr int B_ = 2, S_ = 1024, D_ = 512, H_ = 8;
static constexpr int M_ = B_ * S_;     // 2048 rows
static constexpr int CHUNKS_ = 32, CLEN_ = 32;  // S = CHUNKS * CLEN
static constexpr float EPS_ = 1e-6f;

__device__ __forceinline__ float sigmoidf_(float x) { return 1.0f / (1.0f + __expf(-x)); }

__device__ __forceinline__ short bf_hi(float v, float& rem) {
  bf16 h = __float2bfloat16(v);
  rem = v - __bfloat162float(h);
  return *(short*)&h;
}
__device__ __forceinline__ short bf_of(float v) {
  bf16 h = __float2bfloat16(v);
  return *(short*)&h;
}

// -------- fused transpose + cast: W [K][N] f32 -> Wt [dstRow(n)][K] bf16 --------
// xf: 0 linear; 1 gate-interleave (row = (n>>5)*64 + (n&31)); 2 val (+32)
struct TJob { const float* src; bf16* dst; int K, N, base, xf; };
struct TTab { TJob j[9]; };

__global__ __launch_bounds__(256) void k_transpose_all(TTab tab) {
  __shared__ float tile[32][33];
  int blk = blockIdx.x;
  int ji = 0;
#pragma unroll
  for (int t = 1; t < 9; ++t) if (tab.j[t].base <= blk) ji = t;
  const float* W = tab.j[ji].src;
  bf16* Wt = tab.j[ji].dst;
  int K = tab.j[ji].K, N = tab.j[ji].N, xf = tab.j[ji].xf;
  int rel = blk - tab.j[ji].base;
  int nb = N >> 5;
  int n0 = (rel % nb) * 32, k0 = (rel / nb) * 32;
  int tx = threadIdx.x, ty = threadIdx.y;  // 32 x 8
#pragma unroll
  for (int r = ty; r < 32; r += 8) tile[r][tx] = W[(size_t)(k0 + r) * N + n0 + tx];
  __syncthreads();
#pragma unroll
  for (int r = ty; r < 32; r += 8) {
    int n = n0 + r;
    int drow = n;
    if (xf == 1) drow = ((n >> 5) << 6) + (n & 31);
    else if (xf == 2) drow = ((n >> 5) << 6) + (n & 31) + 32;
    Wt[(size_t)drow * K + k0 + tx] = __float2bfloat16(tile[tx][r]);
  }
}

// ---- fused: blocks [0,M) rmsnorm(x)->hF,hB ; blocks [M,2M) gather ae->aeF,aeB ----
__global__ __launch_bounds__(256) void k_pre(const float* __restrict__ x,
                                             const float* __restrict__ scale,
                                             float* __restrict__ hF, bf16* __restrict__ hB,
                                             const int* __restrict__ action,
                                             const float* __restrict__ embed,
                                             float* __restrict__ aeF, bf16* __restrict__ aeB) {
  int tid = threadIdx.x;
  if (blockIdx.x < M_) {
    int m = blockIdx.x;
    const float* row = x + (size_t)m * D_;
    float2 v = *(const float2*)(row + tid * 2);
    float ss = v.x * v.x + v.y * v.y;
#pragma unroll
    for (int o = 1; o < 64; o <<= 1) ss += __shfl_xor(ss, o);
    __shared__ float wsum[4];
    if ((tid & 63) == 0) wsum[tid >> 6] = ss;
    __syncthreads();
    float tot = wsum[0] + wsum[1] + wsum[2] + wsum[3];
    float rs = rsqrtf(tot * (1.0f / (float)D_) + EPS_);
    float2 sc = *(const float2*)(scale + tid * 2);
    float o0 = v.x * rs * sc.x, o1 = v.y * rs * sc.y;
    float2 o; o.x = o0; o.y = o1;
    *(float2*)(hF + (size_t)m * D_ + tid * 2) = o;
    bf16* p = hB + (size_t)m * D_ + tid * 2;
    p[0] = __float2bfloat16(o0); p[1] = __float2bfloat16(o1);
  } else {
    int m = blockIdx.x - M_;
    int a = action[m];
    float2 v = *(const float2*)(embed + (size_t)a * 512 + tid * 2);
    *(float2*)(aeF + (size_t)m * 512 + tid * 2) = v;
    bf16* p = aeB + (size_t)m * 512 + tid * 2;
    p[0] = __float2bfloat16(v.x); p[1] = __float2bfloat16(v.y);
  }
}

// ---------------- rmsnorm over D=512, optional f32 + bf16 outputs ----------------
__global__ __launch_bounds__(256) void k_rmsnorm(const float* __restrict__ x,
                                                 const float* __restrict__ scale,
                                                 float* __restrict__ outf,
                                                 bf16* __restrict__ outb) {
  int m = blockIdx.x, tid = threadIdx.x;
  const float* row = x + (size_t)m * D_;
  float2 v = *(const float2*)(row + tid * 2);
  float ss = v.x * v.x + v.y * v.y;
#pragma unroll
  for (int o = 1; o < 64; o <<= 1) ss += __shfl_xor(ss, o);
  __shared__ float wsum[4];
  if ((tid & 63) == 0) wsum[tid >> 6] = ss;
  __syncthreads();
  float tot = wsum[0] + wsum[1] + wsum[2] + wsum[3];
  float rs = rsqrtf(tot * (1.0f / (float)D_) + EPS_);
  float2 sc = *(const float2*)(scale + tid * 2);
  float o0 = v.x * rs * sc.x, o1 = v.y * rs * sc.y;
  if (outf) {
    float2 o; o.x = o0; o.y = o1;
    *(float2*)(outf + (size_t)m * D_ + tid * 2) = o;
  }
  if (outb) {
    bf16* p = outb + (size_t)m * D_ + tid * 2;
    p[0] = __float2bfloat16(o0); p[1] = __float2bfloat16(o1);
  }
}

// ---- beta = sigmoid(hF@wbeta), alpha = sigmoid(aeF@walpha) in one dispatch ----
__global__ __launch_bounds__(256) void k_dot8x2(const float* __restrict__ hF,
                                                const float* __restrict__ aeF,
                                                const float* __restrict__ W1,
                                                const float* __restrict__ W2,
                                                float* __restrict__ o1,
                                                float* __restrict__ o2) {
  int m = blockIdx.x, tid = threadIdx.x;
  float x0 = hF[(size_t)m * D_ + tid], x1 = hF[(size_t)m * D_ + 256 + tid];
  float y0 = aeF[(size_t)m * D_ + tid], y1 = aeF[(size_t)m * D_ + 256 + tid];
  float p[8], q[8];
#pragma unroll
  for (int j = 0; j < 8; ++j) {
    p[j] = x0 * W1[tid * 8 + j] + x1 * W1[(tid + 256) * 8 + j];
    q[j] = y0 * W2[tid * 8 + j] + y1 * W2[(tid + 256) * 8 + j];
  }
#pragma unroll
  for (int j = 0; j < 8; ++j) {
#pragma unroll
    for (int o = 1; o < 64; o <<= 1) {
      p[j] += __shfl_xor(p[j], o);
      q[j] += __shfl_xor(q[j], o);
    }
  }
  __shared__ float sacc[4][16];
  if ((tid & 63) == 0) {
#pragma unroll
    for (int j = 0; j < 8; ++j) { sacc[tid >> 6][j] = p[j]; sacc[tid >> 6][8 + j] = q[j]; }
  }
  __syncthreads();
  if (tid < 8) {
    float s = sacc[0][tid] + sacc[1][tid] + sacc[2][tid] + sacc[3][tid];
    o1[(size_t)m * 8 + tid] = sigmoidf_(s);
  } else if (tid < 16) {
    int j = tid - 8;
    float s = sacc[0][8 + j] + sacc[1][8 + j] + sacc[2][8 + j] + sacc[3][8 + j];
    o2[(size_t)m * 8 + j] = sigmoidf_(s);
  }
}

// ---- per (m,h): L2-normalize q,k in place; pack scal8 = {beta, g, kq, kbv, bvq} ----
__global__ __launch_bounds__(256) void k_qknorm_dots(float* __restrict__ qkv,
                                                     const float* __restrict__ buv,
                                                     const float* __restrict__ betaF,
                                                     const float* __restrict__ alphaF,
                                                     const int* __restrict__ mask,
                                                     float* __restrict__ scal8) {
  int blk = blockIdx.x * 4 + (threadIdx.x >> 6);
  int m = blk >> 3, h = blk & 7, t = threadIdx.x & 63;
  size_t qi = (size_t)m * 1536 + h * 64 + t;
  float q = qkv[qi], k = qkv[qi + 512];
  float bv = buv[(size_t)m * 1024 + 512 + h * 64 + t];
  float qs = q * q, ks = k * k;
#pragma unroll
  for (int o = 1; o < 64; o <<= 1) { qs += __shfl_xor(qs, o); ks += __shfl_xor(ks, o); }
  float qn = q / (sqrtf(qs) + EPS_);
  float kn = k / (sqrtf(ks) + EPS_);
  qkv[qi] = qn; qkv[qi + 512] = kn;
  float d0 = kn * qn, d1 = kn * bv, d2 = bv * qn;
#pragma unroll
  for (int o = 1; o < 64; o <<= 1) {
    d0 += __shfl_xor(d0, o); d1 += __shfl_xor(d1, o); d2 += __shfl_xor(d2, o);
  }
  if (t == 0) {
    int mh = m * 8 + h;
    float4 s4;
    s4.x = betaF[mh];
    s4.y = alphaF[mh] * (1.0f - (float)mask[m]);
    s4.z = d0; s4.w = d1;
    *(float4*)(scal8 + (size_t)mh * 8) = s4;
    scal8[(size_t)mh * 8 + 4] = d2;
  }
}

// ======== pipelined bf16 MFMA GEMM: C = epi(A[M,K] @ Bt[N,K]^T), 64x64 tile ========
template <int EPI>
__global__ __launch_bounds__(256) void k_gemm2(const bf16* __restrict__ A,
                                               const bf16* __restrict__ Bt,
                                               void* __restrict__ Cv, int M, int N, int K,
                                               int actSplit, const float* __restrict__ bias,
                                               const float* __restrict__ res) {
  __shared__ bf16 As[2][64 * 32];
  __shared__ bf16 Bs[2][64 * 32];
  const int tid = threadIdx.x;
  const int wave = tid >> 6, lane = tid & 63;
  const int wm = wave >> 1, wn = wave & 1;
  const int m0 = blockIdx.y * 64, n0 = blockIdx.x * 64;
  const int lr = lane & 15, lg = lane >> 4;
  const int srow = (wave << 4) | (lane >> 2);
  const int skb = (lane & 3) << 3;
  const bf16* ga = A + (size_t)(m0 + srow) * K + skb;
  const bf16* gb = Bt + (size_t)(n0 + srow) * K + skb;

  f32x4 acc[2][2];
#pragma unroll
  for (int i = 0; i < 2; ++i)
#pragma unroll
    for (int j = 0; j < 2; ++j) acc[i][j] = (f32x4){0.f, 0.f, 0.f, 0.f};

  const int nk = K >> 5;
  int4 ar = *(const int4*)ga;
  int4 br = *(const int4*)gb;
  for (int t = 0; t < nk; ++t) {
    bf16* asb = &As[t & 1][0];
    bf16* bsb = &Bs[t & 1][0];
    *(int4*)(asb + tid * 8) = ar;
    *(int4*)(bsb + tid * 8) = br;
    __syncthreads();
    if (t + 1 < nk) {
      ar = *(const int4*)(ga + ((size_t)(t + 1) << 5));
      br = *(const int4*)(gb + ((size_t)(t + 1) << 5));
    }
    bf16x8 af[2], bfr[2];
#pragma unroll
    for (int mm = 0; mm < 2; ++mm)
      af[mm] = *(const bf16x8*)(asb + (wm * 32 + mm * 16 + lr) * 32 + lg * 8);
#pragma unroll
    for (int nn = 0; nn < 2; ++nn)
      bfr[nn] = *(const bf16x8*)(bsb + (wn * 32 + nn * 16 + lr) * 32 + lg * 8);
#pragma unroll
    for (int mm = 0; mm < 2; ++mm)
#pragma unroll
      for (int nn = 0; nn < 2; ++nn)
        acc[mm][nn] = __builtin_amdgcn_mfma_f32_16x16x32_bf16(af[mm], bfr[nn], acc[mm][nn], 0, 0, 0);
  }

  if constexpr (EPI == 4) {
    __syncthreads();
    float* gateL = (float*)&As[0][0];
    float* valL = (float*)&Bs[0][0];
    float* dstL = wn ? valL : gateL;
#pragma unroll
    for (int mm = 0; mm < 2; ++mm)
#pragma unroll
      for (int nn = 0; nn < 2; ++nn)
#pragma unroll
        for (int r = 0; r < 4; ++r)
          dstL[(wm * 32 + mm * 16 + lg * 4 + r) * 32 + nn * 16 + lr] = acc[mm][nn][r];
    __syncthreads();
    bf16* Cb = (bf16*)Cv;
    int row = tid >> 2, c0 = (tid & 3) * 8;
    bf16x8 o;
#pragma unroll
    for (int e = 0; e < 8; ++e) {
      float g = gateL[row * 32 + c0 + e];
      float v = valL[row * 32 + c0 + e];
      o[e] = bf_of(g * sigmoidf_(g) * v);
    }
    *(int4*)(Cb + (size_t)(m0 + row) * 2048 + blockIdx.x * 32 + c0) = *(int4*)&o;
  } else {
    float* C = (float*)Cv;
#pragma unroll
    for (int mm = 0; mm < 2; ++mm) {
#pragma unroll
      for (int nn = 0; nn < 2; ++nn) {
#pragma unroll
        for (int r = 0; r < 4; ++r) {
          int row = m0 + wm * 32 + mm * 16 + lg * 4 + r;
          int col = n0 + wn * 32 + nn * 16 + lr;
          float v = acc[mm][nn][r];
          if constexpr (EPI == 1) {
            if (col < actSplit) v = v * sigmoidf_(v);
          }
          if constexpr (EPI == 2) v += bias[col] + res[(size_t)row * N + col];
          if constexpr (EPI == 3) v += res[(size_t)row * N + col];
          C[(size_t)row * N + col] = v;
        }
      }
    }
  }
}

// ================= chunked recurrence =================
// Per-step transition: hs' = hs @ A_t + U_t,  A_t = g (I - beta k k^T),
// U_t[i][j] = beta v_i k_j + bu_i (bv_j - beta*kbv*k_j).
// Scan thread layout: tid = 8*i + q8; thread owns cols [q8*8, q8*8+8) of row i.

// ---- phase 1: per-chunk transition (P^T bf16 hi/lo + U^T f32) + qtilde/utilde ----
// LDS-staged step data; qtilde/utilde computed from PRE-update dots:
//   P_new.q = g*(P.q) - cP*(k.q);  U_new.q = g*(U.q) + Ai*(k.q) + bu_i*(bv.q)
// with k.q (kq) and bv.q (bvq) precomputed in scal8.
__global__ __launch_bounds__(512) void k_scan_chunk(
    const float* __restrict__ qkv, const float* __restrict__ buv,
    const float* __restrict__ scal8, bf16* __restrict__ PtHi,
    bf16* __restrict__ PtLo, float* __restrict__ Ut,
    float* __restrict__ Qtb, float* __restrict__ Vtb) {
  __shared__ float kL[CLEN_][64], qL[CLEN_][64], bvL[CLEN_][64];
  __shared__ float vL[CLEN_][64], buL[CLEN_][64];
  __shared__ float scL[CLEN_][8];
  const int blk = blockIdx.x, bh = blk >> 5, c = blk & (CHUNKS_ - 1);
  const int b = bh >> 3, h = bh & 7;
  const int tid = threadIdx.x, i = tid >> 3, q8 = tid & 7, j0 = q8 * 8;
  const bool writer = (q8 == 0);
  const int m0 = b * S_ + c * CLEN_;

  // cooperative stage: thread -> (s = tid>>4, quad = (tid&15)*4); fully coalesced
  {
    int s = tid >> 4, fo = (tid & 15) * 4;
    const float* qb = qkv + (size_t)(m0 + s) * 1536 + h * 64;
    const float* bb = buv + (size_t)(m0 + s) * 1024 + h * 64;
    *(float4*)&qL[s][fo]  = *(const float4*)(qb + fo);
    *(float4*)&kL[s][fo]  = *(const float4*)(qb + 512 + fo);
    *(float4*)&vL[s][fo]  = *(const float4*)(qb + 1024 + fo);
    *(float4*)&buL[s][fo] = *(const float4*)(bb + fo);
    *(float4*)&bvL[s][fo] = *(const float4*)(bb + 512 + fo);
    if ((tid & 15) < 2)
      *(float4*)&scL[s][(tid & 1) * 4] =
          *(const float4*)(scal8 + (size_t)((m0 + s) * 8 + h) * 8 + (tid & 1) * 4);
  }
  __syncthreads();

  alignas(16) float P[8], U[8];
#pragma unroll
  for (int jj = 0; jj < 8; ++jj) { P[jj] = (j0 + jj == i) ? 1.f : 0.f; U[jj] = 0.f; }
  float* QT = Qtb + ((size_t)bh * CHUNKS_ + c) * (CLEN_ * 64);
  float* VT = Vtb + ((size_t)bh * CHUNKS_ + c) * (CLEN_ * 64);

  struct Step8 { float k[8], q[8], bv[8]; float v_i, bu_i, beta, g, kq, kbv, bvq; };
  auto LOAD = [&](Step8& sd, int s) {
    *(float4*)&sd.k[0]  = *(const float4*)&kL[s][j0];
    *(float4*)&sd.k[4]  = *(const float4*)&kL[s][j0 + 4];
    *(float4*)&sd.q[0]  = *(const float4*)&qL[s][j0];
    *(float4*)&sd.q[4]  = *(const float4*)&qL[s][j0 + 4];
    *(float4*)&sd.bv[0] = *(const float4*)&bvL[s][j0];
    *(float4*)&sd.bv[4] = *(const float4*)&bvL[s][j0 + 4];
    sd.v_i = vL[s][i];
    sd.bu_i = buL[s][i];
    float4 s4 = *(const float4*)&scL[s][0];
    sd.beta = s4.x; sd.g = s4.y; sd.kq = s4.z; sd.kbv = s4.w;
    sd.bvq = scL[s][4];
  };
  auto STEP = [&](const Step8& sd, int s) {
    float Pk = 0.f, Uk = 0.f, Pq = 0.f, Uq = 0.f;
#pragma unroll
    for (int jj = 0; jj < 8; ++jj) {
      Pk += P[jj] * sd.k[jj]; Uk += U[jj] * sd.k[jj];
      Pq += P[jj] * sd.q[jj]; Uq += U[jj] * sd.q[jj];
    }
    Pk += __shfl_xor(Pk, 1); Pk += __shfl_xor(Pk, 2); Pk += __shfl_xor(Pk, 4);
    Uk += __shfl_xor(Uk, 1); Uk += __shfl_xor(Uk, 2); Uk += __shfl_xor(Uk, 4);
    Pq += __shfl_xor(Pq, 1); Pq += __shfl_xor(Pq, 2); Pq += __shfl_xor(Pq, 4);
    Uq += __shfl_xor(Uq, 1); Uq += __shfl_xor(Uq, 2); Uq += __shfl_xor(Uq, 4);
    float gb = sd.g * sd.beta;
    float cP = gb * Pk;
    float Ai = sd.beta * sd.v_i - gb * Uk - sd.bu_i * sd.beta * sd.kbv;
    if (writer) {
      QT[s * 64 + i] = sd.g * Pq - cP * sd.kq;
      VT[s * 64 + i] = sd.g * Uq + Ai * sd.kq + sd.bu_i * sd.bvq;
    }
#pragma unroll
    for (int jj = 0; jj < 8; ++jj) {
      P[jj] = sd.g * P[jj] - cP * sd.k[jj];
      U[jj] = sd.g * U[jj] + Ai * sd.k[jj] + sd.bu_i * sd.bv[jj];
    }
  };

  Step8 A, Bs;
  LOAD(A, 0);
  LOAD(Bs, 1);
  for (int s = 0; s < CLEN_; s += 2) {
    STEP(A, s);
    if (s + 2 < CLEN_) LOAD(A, s + 2);
    STEP(Bs, s + 1);
    if (s + 3 < CLEN_) LOAD(Bs, s + 3);
  }

  const size_t base = ((size_t)bh * CHUNKS_ + c) * 4096;
#pragma unroll
  for (int jj = 0; jj < 8; ++jj) {
    int j = j0 + jj;
    float pv = P[jj];
    float rem;
    short ph = bf_hi(pv, rem);
    short pl = bf_of(rem);
    ((short*)PtHi)[base + (size_t)j * 64 + i] = ph;
    ((short*)PtLo)[base + (size_t)j * 64 + i] = pl;
    Ut[base + (size_t)j * 64 + i] = U[jj];
  }
}

// ---- phase 2: barrier-free register-resident MFMA chain ----
// One WAVE per (bh, 16-column strip of hs^T). State lives in D-fragments:
// st[mt][r] = hs^T[16mt+4lg+r][col0+lr]. Next B-frag rebuilt via lane shuffles.
#define PREFETCH_(SET, CIDX)                                                     \
  {                                                                              \
    const size_t cbo_ = (size_t)(CIDX) * 4096;                                   \
    _Pragma("unroll") for (int mt = 0; mt < 4; ++mt) {                           \
      _Pragma("unroll") for (int ks = 0; ks < 2; ++ks) {                         \
        size_t off_ = cbo_ + (size_t)(16 * mt + lr) * 64 + ks * 32 + lg * 8;     \
        aH[SET][mt][ks] = *(const bf16x8*)(PH + off_);                           \
        aL[SET][mt][ks] = *(const bf16x8*)(PL + off_);                           \
      }                                                                          \
      _Pragma("unroll") for (int r = 0; r < 4; ++r)                              \
        u[SET][mt][r] = UB[cbo_ + (size_t)(16 * mt + 4 * lg + r) * 64 + col0 + lr]; \
    }                                                                            \
  }

#define CHAINSTEP_(SET, NSET, CIDX)                                              \
  {                                                                              \
    if ((CIDX) + 1 < CHUNKS_) PREFETCH_(NSET, (CIDX) + 1);                       \
    _Pragma("unroll") for (int mt = 0; mt < 4; ++mt)                             \
      _Pragma("unroll") for (int r = 0; r < 4; ++r)                              \
        HB[(size_t)(CIDX) * 4096 + (size_t)(16 * mt + 4 * lg + r) * 64 + col0 + lr] = st[mt][r]; \
    bf16x8 bH[2], bL[2];                                                         \
    _Pragma("unroll") for (int ks = 0; ks < 2; ++ks) {                           \
      _Pragma("unroll") for (int e = 0; e < 8; ++e) {                            \
        int src_ = (2 * (lg & 1) + (e >> 2)) * 16 + lr;                          \
        float va_ = __shfl(st[2 * ks][e & 3], src_);                             \
        float vb_ = __shfl(st[2 * ks + 1][e & 3], src_);                         \
        float bv_ = (lg & 2) ? vb_ : va_;                                        \
        float rem_;                                                              \
        bH[ks][e] = bf_hi(bv_, rem_);                                            \
        bL[ks][e] = bf_of(rem_);                                                 \
      }                                                                          \
    }                                                                            \
    f32x4 stn[4];                                                                \
    _Pragma("unroll") for (int mt = 0; mt < 4; ++mt) {                           \
      f32x4 a_ = u[SET][mt];                                                     \
      _Pragma("unroll") for (int ks = 0; ks < 2; ++ks) {                         \
        a_ = __builtin_amdgcn_mfma_f32_16x16x32_bf16(aH[SET][mt][ks], bH[ks], a_, 0, 0, 0); \
        a_ = __builtin_amdgcn_mfma_f32_16x16x32_bf16(aH[SET][mt][ks], bL[ks], a_, 0, 0, 0); \
        a_ = __builtin_amdgcn_mfma_f32_16x16x32_bf16(aL[SET][mt][ks], bH[ks], a_, 0, 0, 0); \
      }                                                                          \
      stn[mt] = a_;                                                              \
    }                                                                            \
    _Pragma("unroll") for (int mt = 0; mt < 4; ++mt) st[mt] = stn[mt];           \
  }

__global__ __launch_bounds__(64, 1) void k_chain3(
    const bf16* __restrict__ PtHi, const bf16* __restrict__ PtLo,
    const float* __restrict__ Ut, const float* __restrict__ carry,
    float* __restrict__ Hbuf, float* __restrict__ out_hs) {
  const int bh = blockIdx.x >> 2, cb = blockIdx.x & 3, col0 = cb * 16;
  const int lane = threadIdx.x & 63, lr = lane & 15, lg = lane >> 4;
  const short* PH = (const short*)PtHi + (size_t)bh * CHUNKS_ * 4096;
  const short* PL = (const short*)PtLo + (size_t)bh * CHUNKS_ * 4096;
  const float* UB = Ut + (size_t)bh * CHUNKS_ * 4096;
  float* HB = Hbuf + (size_t)bh * CHUNKS_ * 4096;

  f32x4 st[4];
#pragma unroll
  for (int mt = 0; mt < 4; ++mt)
    st[mt] = *(const f32x4*)(carry + ((size_t)bh * 64 + col0 + lr) * 64 + 16 * mt + 4 * lg);

  bf16x8 aH[2][4][2], aL[2][4][2];
  f32x4 u[2][4];
  PREFETCH_(0, 0);
  for (int c = 0; c < CHUNKS_; c += 2) {
    CHAINSTEP_(0, 1, c);
    CHAINSTEP_(1, 0, c + 1);
  }
#pragma unroll
  for (int mt = 0; mt < 4; ++mt)
    *(f32x4*)(out_hs + ((size_t)bh * 64 + col0 + lr) * 64 + 16 * mt + 4 * lg) = st[mt];
}

// ---- phase 3: Attn[64x32] = H0 @ Qt^T + Vt per (bh, c), via hi/lo MFMA ----
// Hbuf layout: HB[c][j*64 + i] = hs[i][j] (j = H0 col index l). Qt[s][l], Vt[s][i].
__global__ __launch_bounds__(256) void k_attn_gemm(
    const float* __restrict__ Hbuf, const float* __restrict__ Qtb,
    const float* __restrict__ Vtb, float* __restrict__ attn) {
  const int blk = blockIdx.x, bh = blk >> 5, c = blk & (CHUNKS_ - 1);
  const int b = bh >> 3, h = bh & 7;
  const int tid = threadIdx.x, wave = tid >> 6, lane = tid & 63;
  const int lr = lane & 15, lg = lane >> 4;
  const float* H0 = Hbuf + ((size_t)bh * CHUNKS_ + c) * 4096;
  const float* QT = Qtb + ((size_t)bh * CHUNKS_ + c) * (CLEN_ * 64);
  const float* VT = Vtb + ((size_t)bh * CHUNKS_ + c) * (CLEN_ * 64);

  // A-frag: rows i = wave*16 + lr, k = l = ks*32 + lg*8 + e; H0[i][l] at H0[l*64+i]
  bf16x8 aH[2], aL[2];
#pragma unroll
  for (int ks = 0; ks < 2; ++ks) {
#pragma unroll
    for (int e = 0; e < 8; ++e) {
      float v = H0[(size_t)(ks * 32 + lg * 8 + e) * 64 + wave * 16 + lr];
      float rem;
      aH[ks][e] = bf_hi(v, rem);
      aL[ks][e] = bf_of(rem);
    }
  }
  f32x4 acc[2];
#pragma unroll
  for (int nt = 0; nt < 2; ++nt) {
    f32x4 a = (f32x4){0.f, 0.f, 0.f, 0.f};
#pragma unroll
    for (int ks = 0; ks < 2; ++ks) {
      const float* qp = QT + (size_t)(nt * 16 + lr) * 64 + ks * 32 + lg * 8;
      bf16x8 bH, bL;
#pragma unroll
      for (int e = 0; e < 8; ++e) {
        float rem;
        bH[e] = bf_hi(qp[e], rem);
        bL[e] = bf_of(rem);
      }
      a = __builtin_amdgcn_mfma_f32_16x16x32_bf16(aH[ks], bH, a, 0, 0, 0);
      a = __builtin_amdgcn_mfma_f32_16x16x32_bf16(aH[ks], bL, a, 0, 0, 0);
      a = __builtin_amdgcn_mfma_f32_16x16x32_bf16(aL[ks], bH, a, 0, 0, 0);
    }
    acc[nt] = a;
  }
  const int m0 = b * S_ + c * CLEN_;
#pragma unroll
  for (int nt = 0; nt < 2; ++nt) {
    int s = nt * 16 + lr;
    f32x4 vt = *(const f32x4*)(VT + (size_t)s * 64 + wave * 16 + lg * 4);
    f32x4 o = acc[nt];
#pragma unroll
    for (int r = 0; r < 4; ++r) o[r] += vt[r];
    *(f32x4*)(attn + (size_t)(m0 + s) * 512 + h * 64 + wave * 16 + lg * 4) = o;
  }
}

// ---------------- host ----------------
extern "C" void kernel_launch(void* const* d_in, const int* in_sizes, int n_in,
                              void* d_out, int out_size, void* d_ws, size_t ws_size,
                              hipStream_t stream) {
  const float* x      = (const float*)d_in[0];
  const int*   action = (const int*)d_in[1];
  const int*   mask   = (const int*)d_in[2];
  const float* carry  = (const float*)d_in[3];
  const float* n1s    = (const float*)d_in[4];
  const float* wq     = (const float*)d_in[5];
  const float* wk     = (const float*)d_in[6];
  const float* wv     = (const float*)d_in[7];
  const float* wbeta  = (const float*)d_in[8];
  const float* embed  = (const float*)d_in[9];
  const float* walpha = (const float*)d_in[10];
  const float* wbu    = (const float*)d_in[11];
  const float* wbv    = (const float*)d_in[12];
  const float* nas    = (const float*)d_in[13];
  const float* wout   = (const float*)d_in[14];
  const float* bout   = (const float*)d_in[15];
  const float* n2s    = (const float*)d_in[16];
  const float* wgate  = (const float*)d_in[17];
  const float* wval   = (const float*)d_in[18];
  const float* wffn   = (const float*)d_in[19];

  float* out_hs  = (float*)d_out;            // [2,8,64,64]
  float* out_ffn = (float*)d_out + 65536;    // [2,1024,512]

  char* p = (char*)d_ws;
  auto alloc = [&](size_t bytes) -> char* {
    char* r = p; p += (bytes + 255) & ~(size_t)255; return r;
  };
  bf16*  wqkvT = (bf16*)alloc((size_t)1536 * 512 * 2);
  bf16*  wbuvT = (bf16*)alloc((size_t)1024 * 512 * 2);
  bf16*  woutT = (bf16*)alloc((size_t)512 * 512 * 2);
  bf16*  wgvT  = (bf16*)alloc((size_t)4096 * 512 * 2);   // gate/val row-interleaved
  bf16*  wffnT = (bf16*)alloc((size_t)512 * 2048 * 2);
  float* qkvF  = (float*)alloc((size_t)M_ * 1536 * 4);
  float* buvF  = (float*)alloc((size_t)M_ * 1024 * 4);
  float* betaF = (float*)alloc((size_t)M_ * 8 * 4);
  float* alphaF= (float*)alloc((size_t)M_ * 8 * 4);
  float* scal8 = (float*)alloc((size_t)M_ * 8 * 8 * 4);
  float* attnF = (float*)alloc((size_t)M_ * 512 * 4);
  bf16*  attnB = (bf16*)alloc((size_t)M_ * 512 * 2);
  float* skipF = (float*)alloc((size_t)M_ * 512 * 4);
  bf16*  h2B   = (bf16*)alloc((size_t)M_ * 512 * 2);
  bf16*  ffnB  = (bf16*)alloc((size_t)M_ * 2048 * 2);
  // 32 MiB shared tail: early-phase hF/hB/aeF/aeB, later the chunk buffers
  // (hF/hB/aeF/aeB are dead before k_scan_chunk writes the chunk buffers).
  char*  tail  = alloc((size_t)32 * 1024 * 1024);
  if ((size_t)(p - (char*)d_ws) > ws_size) return;  // workspace too small

  float* hF  = (float*)tail;                               // 4 MiB
  bf16*  hB  = (bf16*)(tail + ((size_t)4 << 20));          // 2 MiB
  float* aeF = (float*)(tail + ((size_t)6 << 20));         // 4 MiB
  bf16*  aeB = (bf16*)(tail + ((size_t)10 << 20));         // 2 MiB

  bf16*  PtHi = (bf16*)tail;                               // 4 MiB
  bf16*  PtLo = (bf16*)(tail + ((size_t)4 << 20));         // 4 MiB
  float* UtB  = (float*)(tail + ((size_t)8 << 20));        // 8 MiB
  float* Hbuf = (float*)(tail + ((size_t)16 << 20));       // 8 MiB
  float* Qtb  = (float*)(tail + ((size_t)24 << 20));       // 4 MiB
  float* Vtb  = (float*)(tail + ((size_t)28 << 20));       // 4 MiB

  TTab tab;
  tab.j[0] = {wq,    wqkvT,              512,  512,  0,    0};
  tab.j[1] = {wk,    wqkvT + 512 * 512,  512,  512,  256,  0};
  tab.j[2] = {wv,    wqkvT + 1024 * 512, 512,  512,  512,  0};
  tab.j[3] = {wbu,   wbuvT,              512,  512,  768,  0};
  tab.j[4] = {wbv,   wbuvT + 512 * 512,  512,  512,  1024, 0};
  tab.j[5] = {wout,  woutT,              512,  512,  1280, 0};
  tab.j[6] = {wgate, wgvT,               512,  2048, 1536, 1};
  tab.j[7] = {wval,  wgvT,               512,  2048, 2560, 2};
  tab.j[8] = {wffn,  wffnT,              2048, 512,  3584, 0};
  k_transpose_all<<<4608, dim3(32, 8), 0, stream>>>(tab);

  k_pre<<<M_ * 2, 256, 0, stream>>>(x, n1s, hF, hB, action, embed, aeF, aeB);

  k_gemm2<1><<<dim3(1536 / 64, M_ / 64), 256, 0, stream>>>(hB, wqkvT, qkvF, M_, 1536, 512, 1024, nullptr, nullptr);
  k_gemm2<0><<<dim3(1024 / 64, M_ / 64), 256, 0, stream>>>(aeB, wbuvT, buvF, M_, 1024, 512, 0, nullptr, nullptr);
  k_dot8x2<<<M_, 256, 0, stream>>>(hF, aeF, wbeta, walpha, betaF, alphaF);
  k_qknorm_dots<<<M_ * 2, 256, 0, stream>>>(qkvF, buvF, betaF, alphaF, mask, scal8);
  // hF/hB/aeF/aeB dead from here; tail region is reused by the chunk buffers.

  k_scan_chunk<<<16 * CHUNKS_, 512, 0, stream>>>(qkvF, buvF, scal8, PtHi, PtLo, UtB, Qtb, Vtb);
  k_chain3<<<64, 64, 0, stream>>>(PtHi, PtLo, UtB, carry, Hbuf, out_hs);
  k_attn_gemm<<<16 * CHUNKS_, 256, 0, stream>>>(Hbuf, Qtb, Vtb, attnF);

  k_rmsnorm<<<M_, 256, 0, stream>>>(attnF, nas, nullptr, attnB);
  k_gemm2<2><<<dim3(512 / 64, M_ / 64), 256, 0, stream>>>(attnB, woutT, skipF, M_, 512, 512, 0, bout, x);
  k_rmsnorm<<<M_, 256, 0, stream>>>(skipF, n2s, nullptr, h2B);
  k_gemm2<4><<<dim3(4096 / 64, M_ / 64), 256, 0, stream>>>(h2B, wgvT, ffnB, M_, 4096, 512, 0, nullptr, nullptr);
  k_gemm2<3><<<dim3(512 / 64, M_ / 64), 256, 0, stream>>>(ffnB, wffnT, out_ffn, M_, 512, 2048, 0, nullptr, skipF);
}